// Round 9
// baseline (773.733 us; speedup 1.0000x reference)
//
#include <hip/hip_runtime.h>

#define NGRAPH  1024
#define E_EDGES 2097152
#define ECAP    2944
#define MAXZ    1000
#define WD_ELEMS 12352   // 3*64*64 + 64 (W0..W2, W3 as f64)

// XOR swizzle for f64 X tile [128][64] (validated r3: conflict-acceptable, absmax 0.0)
__device__ __forceinline__ int xd_idx(int r, int c) {
    return (r << 6) | (c ^ ((r & 7) << 1) ^ ((c & 48) >> 3));
}

// branchless double tanh via e^{2p}; abs error ~2e-13
__device__ __forceinline__ double tanh_fast(double p) {
    double q = 2.0 * p;
    q = fmin(40.0, fmax(-40.0, q));
    double nf = rint(q * 1.4426950408889634074);
    double r  = fma(nf, -6.93147180369123816490e-01, q);
    r = fma(nf, -1.90821492927058770002e-10, r);
    double er =     2.755731922398589e-07;
    er = fma(er, r, 2.755731922398589e-06);
    er = fma(er, r, 2.4801587301587302e-05);
    er = fma(er, r, 1.984126984126984e-04);
    er = fma(er, r, 1.3888888888888889e-03);
    er = fma(er, r, 8.333333333333333e-03);
    er = fma(er, r, 4.1666666666666664e-02);
    er = fma(er, r, 1.6666666666666666e-01);
    er = fma(er, r, 0.5);
    er = fma(er, r, 1.0);
    er = fma(er, r, 1.0);                        // e^r
    double E = er * __longlong_as_double((long long)(1023 + (int)nf) << 52);
    return 1.0 - 2.0 / (E + 1.0);
}

__global__ void markWS_kernel(float* out) {
    int i = blockIdx.x * 256 + threadIdx.x;
    if (i < NGRAPH) out[i] = 2.0f;
}

// packed adjacency counts: adjG[g][d][s/4] byte-lane (s&3); commutative atomics
__global__ void adjscatter_kernel(const int* __restrict__ ei,
                                  unsigned* __restrict__ adjG) {
    int e = blockIdx.x * 256 + threadIdx.x;
    if (e >= E_EDGES) return;
    int s = ei[e];
    int d = ei[E_EDGES + e];
    int g = s >> 7;
    int sl = s & 127, dl = d & 127;
    atomicAdd(&adjG[((size_t)g << 12) + (dl << 5) + (sl >> 2)], 1u << ((sl & 3) << 3));
}

// one-time W -> f64 ((double)w exact)
__global__ void wprep_kernel(const float* __restrict__ W0, const float* __restrict__ W1,
                             const float* __restrict__ W2, const float* __restrict__ W3,
                             double* __restrict__ Wd) {
    int i = blockIdx.x * 256 + threadIdx.x;
    if (i < 4096)       Wd[i] = (double)W0[i];
    else if (i < 8192)  Wd[i] = (double)W1[i - 4096];
    else if (i < 12288) Wd[i] = (double)W2[i - 8192];
    else if (i < WD_ELEMS) Wd[i] = (double)W3[i - 12288];
}

// ============ primary: 1024 threads = 2 graphs/block, f64 LDS numerics ============
// Structure = r6/r8 (16 waves/CU, VGPR cap 64); numerics = r3 (pure f64 X/H in LDS,
// f64-only FMA stream — PASSED with absmax 0.0 in r3). Removes the f32 lo shadow
// path + all bf16 pack/unpack (~40% of the GCN-layer VALU stream).
__global__ __launch_bounds__(1024, 1) void gnnf64_kernel(
    const int* __restrict__ z,
    const unsigned* __restrict__ adjG,
    const float* __restrict__ zt,
    const double* __restrict__ Wd,
    const float* __restrict__ b0, const float* __restrict__ b1,
    const float* __restrict__ b2, const float* __restrict__ b3,
    const float* __restrict__ c1w, const float* __restrict__ c1b,
    const float* __restrict__ c2w, const float* __restrict__ c2b,
    const float* __restrict__ l1w, const float* __restrict__ l1b,
    const float* __restrict__ l2w, const float* __restrict__ l2b,
    float* __restrict__ xdump,
    float* __restrict__ out)
{
    __shared__ __align__(16) double Xd[2][8192];      // 131072 B (adjM overlay at setup)
    __shared__ __align__(16) double h4sD[2][128];     //   2048 B
    __shared__ __align__(16) double keydD[2][128];    //   2048 B
    __shared__ __align__(16) float  hscr[2][1200];    //   9600 B (head scratch)
    __shared__ unsigned char  csr[2][ECAP];           //   5888 B
    __shared__ unsigned short rp16[2][132];
    __shared__ int            aux[2][128];
    __shared__ int            inv[2][30];
    __shared__ float          kd30f[2][30];
    __shared__ int            w0tot[2];
    // ~153 KB -> one 16-wave block/CU

    const int half = threadIdx.x >> 9;                // 0/1: waves 0-7 / 8-15
    const int tt   = threadIdx.x & 511;
    const int g    = (blockIdx.x << 1) | half;
    const int r0 = tt >> 3;
    const int r1 = r0 + 64;
    const int c0 = (tt & 7) << 3;

    double*         XD = Xd[half];
    unsigned char*  CS = csr[half];
    unsigned short* RP = rp16[half];
    int*            AX = aux[half];

    unsigned* adjM = (unsigned*)XD;   // [128][32] packed byte counts (16 KB)

    // load this graph's adjacency-count slab (coalesced)
    {
        const uint4* src = (const uint4*)(adjG + ((size_t)g << 12));
        uint4* dst = (uint4*)adjM;
        for (int i = tt; i < 1024; i += 512) dst[i] = src[i];
    }
    if (tt < 30) { inv[half][tt] = tt; kd30f[half][tt] = 0.f; }
    __syncthreads();

    // per-node in-degree
    int degv = 0;
    if (tt < 128) {
        for (int w = 0; w < 32; ++w) {
            unsigned u = adjM[(tt << 5) + w];
            degv += (int)((u & 255u) + ((u >> 8) & 255u) + ((u >> 16) & 255u) + (u >> 24));
        }
        AX[tt] = degv;
    }
    // exclusive scan (two waves per half)
    if (tt < 128) {
        int v = degv;
        for (int o = 1; o < 64; o <<= 1) {
            int u = __shfl_up(v, o, 64);
            if ((tt & 63) >= o) v += u;
        }
        if (tt == 63) w0tot[half] = v;
        RP[tt + 1] = (unsigned short)v;
    }
    __syncthreads();
    if (tt >= 64 && tt < 128) RP[tt + 1] = (unsigned short)(RP[tt + 1] + w0tot[half]);
    if (tt == 0) RP[0] = 0;
    __syncthreads();

    const int mydeg = (tt < 128) ? AX[tt] : 0;
    const double dv0 = 1.0 / sqrt((double)(AX[r0] + 1));
    const double dv1 = 1.0 / sqrt((double)(AX[r1] + 1));
    const double dvm = 1.0 / sqrt((double)(mydeg + 1));

    // deterministic CSR emit
    if (tt < 128) {
        unsigned pos = RP[tt];
        for (int w = 0; w < 32; ++w) {
            unsigned u = adjM[(tt << 5) + w];
            while (u) {
                int b2 = (u & 0xFFu) ? 0 : (u & 0xFF00u) ? 1 : (u & 0xFF0000u) ? 2 : 3;
                int m = (int)((u >> (b2 << 3)) & 255u);
                unsigned char sv = (unsigned char)((w << 2) + b2);
                for (int q = 0; q < m; ++q) { if (pos < ECAP) CS[pos] = sv; ++pos; }
                u &= ~(0xFFu << (b2 << 3));
            }
        }
    }
    __syncthreads();                 // adjM reads done; XD free

    // X0 = (double)z_table[z] — exact
    for (int idx = tt; idx < 8192; idx += 512) {
        int n = idx >> 6, c = idx & 63;
        int zv = z[(g << 7) + n];
        zv = (zv < 0) ? 0 : ((zv >= MAXZ) ? MAXZ - 1 : zv);
        XD[xd_idx(n, c)] = (double)zt[zv * 64 + c];
    }
    __syncthreads();

    // ---- three GCN layers, straight f64 (r3 numerics) ----
    for (int layer = 0; layer < 3; ++layer) {
        const double* Wg = Wd + (layer << 12);
        const float*  bg = (layer == 0) ? b0 : (layer == 1) ? b1 : b2;

        // phase 1: acc = (X @ W)[r0,r1][c0..c0+7]
        double acc0[8], acc1[8];
#pragma unroll
        for (int j = 0; j < 8; ++j) { acc0[j] = 0.0; acc1[j] = 0.0; }

        for (int k = 0; k < 64; k += 4) {
            int b0i = (r0 << 6) | (k ^ ((r0 & 7) << 1) ^ ((k & 48) >> 3));
            int b1i = b0i + 4096;                        // r1 = r0+64, same swizzle bits
            double2 xa = *(const double2*)&XD[b0i];
            double2 xb = *(const double2*)&XD[b0i ^ 2];
            double2 ya = *(const double2*)&XD[b1i];
            double2 yb = *(const double2*)&XD[b1i ^ 2];
            double x0[4] = {xa.x, xa.y, xb.x, xb.y};
            double x1[4] = {ya.x, ya.y, yb.x, yb.y};
#pragma unroll
            for (int kk = 0; kk < 4; ++kk) {
                const double* wr = Wg + ((k + kk) << 6) + c0;
                double2 w0v = *(const double2*)wr;
                double2 w1v = *(const double2*)(wr + 2);
                double2 w2v = *(const double2*)(wr + 4);
                double2 w3v = *(const double2*)(wr + 6);
                double wv[8] = {w0v.x, w0v.y, w1v.x, w1v.y, w2v.x, w2v.y, w3v.x, w3v.y};
#pragma unroll
                for (int j = 0; j < 8; ++j) {
                    acc0[j] = fma(x0[kk], wv[j], acc0[j]);
                    acc1[j] = fma(x1[kk], wv[j], acc1[j]);
                }
            }
        }
        __syncthreads();                                   // all X reads complete

        // H = dinv * acc; store f64
        {
            int bi = xd_idx(r0, c0);
            *(double2*)&Xd[half][bi]     = make_double2(dv0 * acc0[0], dv0 * acc0[1]);
            *(double2*)&Xd[half][bi ^ 2] = make_double2(dv0 * acc0[2], dv0 * acc0[3]);
            *(double2*)&Xd[half][bi ^ 4] = make_double2(dv0 * acc0[4], dv0 * acc0[5]);
            *(double2*)&Xd[half][bi ^ 6] = make_double2(dv0 * acc0[6], dv0 * acc0[7]);
            int bj = xd_idx(r1, c0);
            *(double2*)&Xd[half][bj]     = make_double2(dv1 * acc1[0], dv1 * acc1[1]);
            *(double2*)&Xd[half][bj ^ 2] = make_double2(dv1 * acc1[2], dv1 * acc1[3]);
            *(double2*)&Xd[half][bj ^ 4] = make_double2(dv1 * acc1[4], dv1 * acc1[5]);
            *(double2*)&Xd[half][bj ^ 6] = make_double2(dv1 * acc1[6], dv1 * acc1[7]);
        }
        __syncthreads();                                   // H fully written

        // phase 2 + tanh, row-split; results staged in regs, stored after barrier
        double tv[2][8];
#pragma unroll
        for (int rw = 0; rw < 2; ++rw) {
            int rr = rw ? r1 : r0;
            double dv = rw ? dv1 : dv0;
            int bio = xd_idx(rr, c0);
            double2 p0 = *(const double2*)&XD[bio];
            double2 p1 = *(const double2*)&XD[bio ^ 2];
            double2 p2 = *(const double2*)&XD[bio ^ 4];
            double2 p3 = *(const double2*)&XD[bio ^ 6];
            double ad[8];
            ad[0] = p0.x; ad[1] = p0.y; ad[2] = p1.x; ad[3] = p1.y;
            ad[4] = p2.x; ad[5] = p2.y; ad[6] = p3.x; ad[7] = p3.y;

            for (unsigned e = RP[rr]; e < RP[rr + 1]; ++e) {
                int s = CS[e];
                int bi = (s << 6) | (c0 ^ ((s & 7) << 1) ^ ((c0 & 48) >> 3));
                double2 q0 = *(const double2*)&XD[bi];
                double2 q1 = *(const double2*)&XD[bi ^ 2];
                double2 q2 = *(const double2*)&XD[bi ^ 4];
                double2 q3 = *(const double2*)&XD[bi ^ 6];
                ad[0] += q0.x; ad[1] += q0.y;
                ad[2] += q1.x; ad[3] += q1.y;
                ad[4] += q2.x; ad[5] += q2.y;
                ad[6] += q3.x; ad[7] += q3.y;
            }
#pragma unroll
            for (int j = 0; j < 8; ++j)
                tv[rw][j] = tanh_fast(dv * ad[j] + (double)bg[c0 + j]);
        }
        __syncthreads();                                   // all H reads complete

        // store X = tanh outputs (f64); dump layer-0/1 as f32 for head-side conv1
#pragma unroll
        for (int rw = 0; rw < 2; ++rw) {
            int rr = rw ? r1 : r0;
            int bi = xd_idx(rr, c0);
            *(double2*)&XD[bi]     = make_double2(tv[rw][0], tv[rw][1]);
            *(double2*)&XD[bi ^ 2] = make_double2(tv[rw][2], tv[rw][3]);
            *(double2*)&XD[bi ^ 4] = make_double2(tv[rw][4], tv[rw][5]);
            *(double2*)&XD[bi ^ 6] = make_double2(tv[rw][6], tv[rw][7]);

            if (layer < 2) {
                float* xd = xdump + (((size_t)g * 2 + layer) << 13) + (rr << 6) + c0;
                *(float4*)xd       = make_float4((float)tv[rw][0], (float)tv[rw][1],
                                                 (float)tv[rw][2], (float)tv[rw][3]);
                *(float4*)(xd + 4) = make_float4((float)tv[rw][4], (float)tv[rw][5],
                                                 (float)tv[rw][6], (float)tv[rw][7]);
            }
        }
        __syncthreads();
    }

    // ---- layer 4 (64->1): key path (r3 chain order; passed absmax 0.0) ----
    double sdreg = 0.0;
    if (tt < 128) {
        const double* W3d = Wd + 12288;
        double sd = 0.0;
        for (int k = 0; k < 64; k += 2) {
            int bi = (tt << 6) | (k ^ ((tt & 7) << 1) ^ ((k & 48) >> 3));
            double2 a = *(const double2*)&XD[bi];
            double2 w = *(const double2*)&W3d[k];
            sd = fma(a.x, w.x, sd);
            sd = fma(a.y, w.y, sd);
        }
        sdreg = sd;
    }
    if (tt < 128) h4sD[half][tt] = dvm * sdreg;
    __syncthreads();
    double keyreg = 0.0;
    if (tt < 128) {
        double a = h4sD[half][tt];
        for (unsigned e = RP[tt]; e < RP[tt + 1]; ++e) a += h4sD[half][CS[e]];
        keyreg = tanh_fast(dvm * a + (double)b3[0]);
        keydD[half][tt] = keyreg;
    }
    __syncthreads();

    // stable descending rank
    if (tt < 128) {
        int rk = 0;
        for (int j = 0; j < 128; ++j) {
            double kj = keydD[half][j];
            if (kj > keyreg || (kj == keyreg && j < tt)) ++rk;
        }
        if (rk < 30) { inv[half][rk] = tt; kd30f[half][rk] = (float)keyreg; }
    }
    __syncthreads();                         // publish inv/kd30f

    // ---- head (per half, own scratch) ----
    float* h1v = hscr[half];          // 480
    float* ppv = hscr[half] + 480;    // 240
    float* flv = hscr[half] + 720;    // 352
    float* hmv = hscr[half] + 1072;   // 128

    if (tt < 480) {
        int c = tt & 15, k = tt >> 4;
        int node = inv[half][k];
        // conv1 partials, bit-identical chain+tree (L0 j0..7, L1 j0..7, L2 j0..7; xor tree)
        const float* wrow = c1w + c * 193;
        const float* xg0 = xdump + ((size_t)g * 2) * 8192 + node * 64;
        const float* xg1 = xg0 + 8192;
        float s8[8];
#pragma unroll
        for (int cg = 0; cg < 8; ++cg) {
            float acc = 0.f;
            float4 xa = *(const float4*)&xg0[cg * 8];
            float4 xb = *(const float4*)&xg0[cg * 8 + 4];
            const float* w0p = wrow + cg * 8;
            acc = fmaf(xa.x, w0p[0], acc); acc = fmaf(xa.y, w0p[1], acc);
            acc = fmaf(xa.z, w0p[2], acc); acc = fmaf(xa.w, w0p[3], acc);
            acc = fmaf(xb.x, w0p[4], acc); acc = fmaf(xb.y, w0p[5], acc);
            acc = fmaf(xb.z, w0p[6], acc); acc = fmaf(xb.w, w0p[7], acc);
            float4 ya = *(const float4*)&xg1[cg * 8];
            float4 yb = *(const float4*)&xg1[cg * 8 + 4];
            const float* w1p = wrow + 64 + cg * 8;
            acc = fmaf(ya.x, w1p[0], acc); acc = fmaf(ya.y, w1p[1], acc);
            acc = fmaf(ya.z, w1p[2], acc); acc = fmaf(ya.w, w1p[3], acc);
            acc = fmaf(yb.x, w1p[4], acc); acc = fmaf(yb.y, w1p[5], acc);
            acc = fmaf(yb.z, w1p[6], acc); acc = fmaf(yb.w, w1p[7], acc);
            const float* w2p = wrow + 128 + cg * 8;
#pragma unroll
            for (int j = 0; j < 8; ++j)
                acc = fmaf((float)XD[xd_idx(node, cg * 8 + j)], w2p[j], acc);
            s8[cg] = acc;
        }
        float A0 = s8[0] + s8[1], A1 = s8[2] + s8[3];
        float A2 = s8[4] + s8[5], A3 = s8[6] + s8[7];
        float G = (A0 + A1) + (A2 + A3);
        float s = G + c1w[c * 193 + 192] * kd30f[half][k] + c1b[c];
        h1v[c * 30 + k] = s > 0.f ? s : 0.f;
    }
    __syncthreads();
    if (tt < 240) {
        int c = tt & 15, i = tt >> 4;
        float a = h1v[c * 30 + 2 * i], b = h1v[c * 30 + 2 * i + 1];
        ppv[c * 15 + i] = a > b ? a : b;
    }
    __syncthreads();
    if (tt < 352) {
        int o = tt / 11, j = tt % 11;
        float s = c2b[o];
        for (int i = 0; i < 16; ++i)
#pragma unroll
            for (int u = 0; u < 5; ++u)
                s = fmaf(ppv[i * 15 + j + u], c2w[o * 80 + i * 5 + u], s);
        flv[tt] = s > 0.f ? s : 0.f;
    }
    __syncthreads();
    if (tt < 128) {
        float s = l1b[tt];
        for (int i = 0; i < 352; ++i) s = fmaf(flv[i], l1w[i * 128 + tt], s);
        hmv[tt] = s > 0.f ? s : 0.f;
    }
    __syncthreads();
    if (tt < 64) {
        float v = fmaf(hmv[tt], l2w[tt], hmv[tt + 64] * l2w[tt + 64]);
#pragma unroll
        for (int o = 32; o > 0; o >>= 1) v += __shfl_down(v, o, 64);
        if (tt == 0) out[g] = v + l2b[0];
    }
}

// ============ fallback kernel: r2 fused variant (512 threads, 1 graph) ============
__global__ __launch_bounds__(512, 2) void gnn_kernel(
    const int* __restrict__ z,
    const unsigned* __restrict__ adjG,
    const float* __restrict__ zt,
    const float* __restrict__ W0, const float* __restrict__ b0,
    const float* __restrict__ W1, const float* __restrict__ b1,
    const float* __restrict__ W2, const float* __restrict__ b2,
    const float* __restrict__ W3, const float* __restrict__ b3,
    const float* __restrict__ c1w, const float* __restrict__ c1b,
    const float* __restrict__ c2w, const float* __restrict__ c2b,
    const float* __restrict__ l1w, const float* __restrict__ l1b,
    const float* __restrict__ l2w, const float* __restrict__ l2b,
    float* __restrict__ out)
{
    __shared__ __align__(16) float    Xhi[8192];
    __shared__ __align__(16) unsigned Xlo[4096];
    __shared__ unsigned char  csr[ECAP];
    __shared__ unsigned short rp16[132];
    __shared__ int            aux[128];
    __shared__ int            inv[30];
    __shared__ float          kd30f[30];
    __shared__ int            w0tot;

    const int g  = blockIdx.x;
    const int t  = threadIdx.x;
    const int r0 = t >> 3;
    const int r1 = r0 + 64;
    const int c0 = (t & 7) << 3;

    auto bfu_lo = [](unsigned u) { return __uint_as_float(u << 16); };
    auto bfu_hi = [](unsigned u) { return __uint_as_float(u & 0xFFFF0000u); };
    auto packlo = [](float f0, float f1) {
        return (__float_as_uint(f0) >> 16) | (__float_as_uint(f1) & 0xFFFF0000u);
    };
    auto xh_idx = [](int r, int k)  { return (r << 6) | (k  ^ ((r & 7) << 3)); };
    auto xl_idx = [](int r, int k2) { return (r << 5) | (k2 ^ ((r & 7) << 2)); };

    unsigned* adjM = (unsigned*)Xhi;

    {
        const uint4* src = (const uint4*)(adjG + ((size_t)g << 12));
        uint4* dst = (uint4*)adjM;
        for (int i = t; i < 1024; i += 512) dst[i] = src[i];
    }
    if (t < 30) { inv[t] = t; kd30f[t] = 0.f; }
    __syncthreads();

    int degv = 0;
    if (t < 128) {
        for (int w = 0; w < 32; ++w) {
            unsigned u = adjM[(t << 5) + w];
            degv += (int)((u & 255u) + ((u >> 8) & 255u) + ((u >> 16) & 255u) + (u >> 24));
        }
        aux[t] = degv;
    }
    if (t < 128) {
        int v = degv;
        for (int o = 1; o < 64; o <<= 1) {
            int u = __shfl_up(v, o, 64);
            if ((t & 63) >= o) v += u;
        }
        if (t == 63) w0tot = v;
        rp16[t + 1] = (unsigned short)v;
    }
    __syncthreads();
    if (t >= 64 && t < 128) rp16[t + 1] = (unsigned short)(rp16[t + 1] + w0tot);
    if (t == 0) rp16[0] = 0;
    __syncthreads();

    const int mydeg = (t < 128) ? aux[t] : 0;
    const double dv0 = 1.0 / sqrt((double)(aux[r0] + 1));
    const double dv1 = 1.0 / sqrt((double)(aux[r1] + 1));
    const double dvm = 1.0 / sqrt((double)(mydeg + 1));

    if (t < 128) {
        unsigned pos = rp16[t];
        for (int w = 0; w < 32; ++w) {
            unsigned u = adjM[(t << 5) + w];
            while (u) {
                int b2 = (u & 0xFFu) ? 0 : (u & 0xFF00u) ? 1 : (u & 0xFF0000u) ? 2 : 3;
                int m = (int)((u >> (b2 << 3)) & 255u);
                unsigned char sv = (unsigned char)((w << 2) + b2);
                for (int q = 0; q < m; ++q) { if (pos < ECAP) csr[pos] = sv; ++pos; }
                u &= ~(0xFFu << (b2 << 3));
            }
        }
    }
    __syncthreads();

    for (int idx = t; idx < 8192; idx += 512) {
        int n = idx >> 6, c = idx & 63;
        int zv = z[(g << 7) + n];
        zv = (zv < 0) ? 0 : ((zv >= MAXZ) ? MAXZ - 1 : zv);
        Xhi[xh_idx(n, c)] = zt[zv * 64 + c];
    }
    __syncthreads();

    float g1p[2][16];
#pragma unroll
    for (int rw = 0; rw < 2; ++rw)
#pragma unroll
        for (int c = 0; c < 16; ++c) g1p[rw][c] = 0.f;

    for (int layer = 0; layer < 3; ++layer) {
        const float* Wg = (layer == 0) ? W0 : (layer == 1) ? W1 : W2;
        const float* bg = (layer == 0) ? b0 : (layer == 1) ? b1 : b2;
        const bool haslo = (layer != 0);

        double accd0[8], accd1[8]; float accf0[8], accf1[8];
#pragma unroll
        for (int j = 0; j < 8; ++j) { accd0[j] = 0.0; accd1[j] = 0.0; accf0[j] = 0.f; accf1[j] = 0.f; }

        for (int k = 0; k < 64; k += 4) {
            float4 a0 = *(const float4*)&Xhi[xh_idx(r0, k)];
            float4 a1 = *(const float4*)&Xhi[xh_idx(r1, k)];
            float x0[4] = {a0.x, a0.y, a0.z, a0.w};
            float x1[4] = {a1.x, a1.y, a1.z, a1.w};
            float l0[4], l1[4];
            if (haslo) {
                uint2 u0 = *(const uint2*)&Xlo[xl_idx(r0, k >> 1)];
                uint2 u1 = *(const uint2*)&Xlo[xl_idx(r1, k >> 1)];
                l0[0] = bfu_lo(u0.x); l0[1] = bfu_hi(u0.x); l0[2] = bfu_lo(u0.y); l0[3] = bfu_hi(u0.y);
                l1[0] = bfu_lo(u1.x); l1[1] = bfu_hi(u1.x); l1[2] = bfu_lo(u1.y); l1[3] = bfu_hi(u1.y);
            }
#pragma unroll
            for (int kk = 0; kk < 4; ++kk) {
                const float* wr = Wg + ((k + kk) << 6) + c0;
                float4 wa = *(const float4*)wr;
                float4 wb = *(const float4*)(wr + 4);
                float wf[8] = {wa.x, wa.y, wa.z, wa.w, wb.x, wb.y, wb.z, wb.w};
                double xd0 = (double)x0[kk], xd1 = (double)x1[kk];
#pragma unroll
                for (int j = 0; j < 8; ++j) {
                    double wd = (double)wf[j];
                    accd0[j] = fma(xd0, wd, accd0[j]);
                    accd1[j] = fma(xd1, wd, accd1[j]);
                }
                if (haslo) {
#pragma unroll
                    for (int j = 0; j < 8; ++j) {
                        accf0[j] = fmaf(l0[kk], wf[j], accf0[j]);
                        accf1[j] = fmaf(l1[kk], wf[j], accf1[j]);
                    }
                }
            }
        }
        __syncthreads();

        float hfv[2][8], rsv[2][8];
#pragma unroll
        for (int rw = 0; rw < 2; ++rw) {
            int rr = rw ? r1 : r0;
            double dv = rw ? dv1 : dv0;
#pragma unroll
            for (int j = 0; j < 8; ++j) {
                double acc = rw ? (accd1[j] + (double)accf1[j]) : (accd0[j] + (double)accf0[j]);
                double h = dv * acc;
                float hf = (float)h;
                hfv[rw][j] = hf;
                rsv[rw][j] = (float)(h - (double)hf);
            }
            int bi = xh_idx(rr, c0);
            *(float4*)&Xhi[bi]     = make_float4(hfv[rw][0], hfv[rw][1], hfv[rw][2], hfv[rw][3]);
            *(float4*)&Xhi[bi + 4] = make_float4(hfv[rw][4], hfv[rw][5], hfv[rw][6], hfv[rw][7]);
            uint4 lv;
            lv.x = packlo(rsv[rw][0], rsv[rw][1]);
            lv.y = packlo(rsv[rw][2], rsv[rw][3]);
            lv.z = packlo(rsv[rw][4], rsv[rw][5]);
            lv.w = packlo(rsv[rw][6], rsv[rw][7]);
            *(uint4*)&Xlo[xl_idx(rr, c0 >> 1)] = lv;
        }
        __syncthreads();

        double ad[2][8]; float af[2][8];
#pragma unroll
        for (int rw = 0; rw < 2; ++rw)
#pragma unroll
            for (int j = 0; j < 8; ++j) { ad[rw][j] = (double)hfv[rw][j]; af[rw][j] = rsv[rw][j]; }

#pragma unroll
        for (int rw = 0; rw < 2; ++rw) {
            int rr = rw ? r1 : r0;
            for (unsigned e = rp16[rr]; e < rp16[rr + 1]; ++e) {
                int s = csr[e];
                int bi = (s << 6) | (c0 ^ ((s & 7) << 3));
                float4 a = *(const float4*)&Xhi[bi];
                float4 b = *(const float4*)&Xhi[bi + 4];
                uint4 lu = *(const uint4*)&Xlo[(s << 5) | ((c0 >> 1) ^ ((s & 7) << 2))];
                ad[rw][0] += (double)a.x; ad[rw][1] += (double)a.y;
                ad[rw][2] += (double)a.z; ad[rw][3] += (double)a.w;
                ad[rw][4] += (double)b.x; ad[rw][5] += (double)b.y;
                ad[rw][6] += (double)b.z; ad[rw][7] += (double)b.w;
                af[rw][0] += bfu_lo(lu.x); af[rw][1] += bfu_hi(lu.x);
                af[rw][2] += bfu_lo(lu.y); af[rw][3] += bfu_hi(lu.y);
                af[rw][4] += bfu_lo(lu.z); af[rw][5] += bfu_hi(lu.z);
                af[rw][6] += bfu_lo(lu.w); af[rw][7] += bfu_hi(lu.w);
            }
        }
        __syncthreads();

#pragma unroll
        for (int rw = 0; rw < 2; ++rw) {
            int rr = rw ? r1 : r0;
            double dv = rw ? dv1 : dv0;
            float vf[8], rs[8];
#pragma unroll
            for (int j = 0; j < 8; ++j) {
                double v = tanh_fast(dv * (ad[rw][j] + (double)af[rw][j]) + (double)bg[c0 + j]);
                float vfl = (float)v;
                vf[j] = vfl;
                rs[j] = (float)(v - (double)vfl);
            }
            int bi = xh_idx(rr, c0);
            *(float4*)&Xhi[bi]     = make_float4(vf[0], vf[1], vf[2], vf[3]);
            *(float4*)&Xhi[bi + 4] = make_float4(vf[4], vf[5], vf[6], vf[7]);
            uint4 lv;
            lv.x = packlo(rs[0], rs[1]);
            lv.y = packlo(rs[2], rs[3]);
            lv.z = packlo(rs[4], rs[5]);
            lv.w = packlo(rs[6], rs[7]);
            *(uint4*)&Xlo[xl_idx(rr, c0 >> 1)] = lv;

            const float* w1base = c1w + layer * 64 + c0;
            for (int c = 0; c < 16; ++c) {
                const float* wr = w1base + c * 193;
#pragma unroll
                for (int j = 0; j < 8; ++j)
                    g1p[rw][c] = fmaf(vf[j], wr[j], g1p[rw][c]);
            }
        }
        __syncthreads();
    }

    double* h4sD  = (double*)Xlo;
    double* keydD = ((double*)Xlo) + 128;

    double sdreg = 0.0;
    if (t < 128) {
        double sd = 0.0; float sf = 0.f;
        for (int k = 0; k < 64; k += 4) {
            float4 a = *(const float4*)&Xhi[xh_idx(t, k)];
            uint2  u = *(const uint2*)&Xlo[xl_idx(t, k >> 1)];
            float4 w = *(const float4*)&W3[k];
            sd = fma((double)a.x, (double)w.x, sd);
            sd = fma((double)a.y, (double)w.y, sd);
            sd = fma((double)a.z, (double)w.z, sd);
            sd = fma((double)a.w, (double)w.w, sd);
            sf = fmaf(bfu_lo(u.x), w.x, sf);
            sf = fmaf(bfu_hi(u.x), w.y, sf);
            sf = fmaf(bfu_lo(u.y), w.z, sf);
            sf = fmaf(bfu_hi(u.y), w.w, sf);
        }
        sdreg = sd + (double)sf;
    }
    __syncthreads();
    if (t < 128) h4sD[t] = dvm * sdreg;
    __syncthreads();
    double keyreg = 0.0;
    if (t < 128) {
        double a = h4sD[t];
        for (unsigned e = rp16[t]; e < rp16[t + 1]; ++e) a += h4sD[csr[e]];
        keyreg = tanh_fast(dvm * a + (double)b3[0]);
        keydD[t] = keyreg;
    }
    __syncthreads();

    if (t < 128) {
        int rk = 0;
        for (int j = 0; j < 128; ++j) {
            double kj = keydD[j];
            if (kj > keyreg || (kj == keyreg && j < t)) ++rk;
        }
        if (rk < 30) { inv[rk] = t; kd30f[rk] = (float)keyreg; }
    }

#pragma unroll
    for (int m = 1; m <= 4; m <<= 1) {
#pragma unroll
        for (int rw = 0; rw < 2; ++rw)
#pragma unroll
            for (int c = 0; c < 16; ++c)
                g1p[rw][c] += __shfl_xor(g1p[rw][c], m, 64);
    }
    __syncthreads();
    float* XloF = (float*)Xlo;
    float* G1   = XloF + 512;
    if ((t & 7) == 0) {
#pragma unroll
        for (int c = 0; c < 16; c += 4) {
            *(float4*)&G1[r0 * 16 + c] = make_float4(g1p[0][c], g1p[0][c + 1], g1p[0][c + 2], g1p[0][c + 3]);
            *(float4*)&G1[r1 * 16 + c] = make_float4(g1p[1][c], g1p[1][c + 1], g1p[1][c + 2], g1p[1][c + 3]);
        }
    }
    __syncthreads();

    float* h1v = XloF + 2560;
    float* ppv = XloF + 3040;
    float* flv = XloF + 3280;
    float* hmv = XloF + 3632;

    if (t < 480) {
        int c = t & 15, k = t >> 4;
        int node = inv[k];
        float s = G1[node * 16 + c] + c1w[c * 193 + 192] * kd30f[k] + c1b[c];
        h1v[c * 30 + k] = s > 0.f ? s : 0.f;
    }
    __syncthreads();
    if (t < 240) {
        int c = t & 15, i = t >> 4;
        float a = h1v[c * 30 + 2 * i], b = h1v[c * 30 + 2 * i + 1];
        ppv[c * 15 + i] = a > b ? a : b;
    }
    __syncthreads();
    if (t < 352) {
        int o = t / 11, j = t % 11;
        float s = c2b[o];
        for (int i = 0; i < 16; ++i)
#pragma unroll
            for (int u = 0; u < 5; ++u)
                s = fmaf(ppv[i * 15 + j + u], c2w[o * 80 + i * 5 + u], s);
        flv[t] = s > 0.f ? s : 0.f;
    }
    __syncthreads();
    if (t < 128) {
        float s = l1b[t];
        for (int i = 0; i < 352; ++i) s = fmaf(flv[i], l1w[i * 128 + t], s);
        hmv[t] = s > 0.f ? s : 0.f;
    }
    __syncthreads();
    if (t < 64) {
        float v = fmaf(hmv[t], l2w[t], hmv[t + 64] * l2w[t + 64]);
#pragma unroll
        for (int o = 32; o > 0; o >>= 1) v += __shfl_down(v, o, 64);
        if (t == 0) out[g] = v + l2b[0];
    }
}

// ---------------- launch ----------------

extern "C" void kernel_launch(void* const* d_in, const int* in_sizes, int n_in,
                              void* d_out, int out_size, void* d_ws, size_t ws_size,
                              hipStream_t stream) {
    const int*   z   = (const int*)d_in[0];
    const int*   ei  = (const int*)d_in[1];
    const float* zt  = (const float*)d_in[3];
    const float* W0  = (const float*)d_in[4];
    const float* b0  = (const float*)d_in[5];
    const float* W1  = (const float*)d_in[6];
    const float* b1  = (const float*)d_in[7];
    const float* W2  = (const float*)d_in[8];
    const float* b2  = (const float*)d_in[9];
    const float* W3  = (const float*)d_in[10];
    const float* b3  = (const float*)d_in[11];
    const float* c1w = (const float*)d_in[12];
    const float* c1b = (const float*)d_in[13];
    const float* c2w = (const float*)d_in[14];
    const float* c2b = (const float*)d_in[15];
    const float* l1w = (const float*)d_in[16];
    const float* l1b = (const float*)d_in[17];
    const float* l2w = (const float*)d_in[18];
    const float* l2b = (const float*)d_in[19];
    float* out = (float*)d_out;

    const size_t ADJ_B = (size_t)NGRAPH * 4096 * 4;            // 16.78 MB
    const size_t XD_B  = (size_t)NGRAPH * 2 * 8192 * 4;        // 67.11 MB (x dumps, layers 0-1)
    const size_t WD_B  = (size_t)WD_ELEMS * 8;                 // 98.8 KB (f64 weights)
    if (ws_size < ADJ_B) {
        markWS_kernel<<<4, 256, 0, stream>>>(out);
        return;
    }

    unsigned* adjG = (unsigned*)d_ws;

    hipMemsetAsync(adjG, 0, ADJ_B, stream);
    adjscatter_kernel<<<(E_EDGES + 255) / 256, 256, 0, stream>>>(ei, adjG);

    if (ws_size >= ADJ_B + XD_B + WD_B) {
        float*  xdump = (float*)((char*)d_ws + ADJ_B);
        double* Wd    = (double*)((char*)d_ws + ADJ_B + XD_B);
        wprep_kernel<<<(WD_ELEMS + 255) / 256, 256, 0, stream>>>(W0, W1, W2, W3, Wd);
        gnnf64_kernel<<<NGRAPH / 2, 1024, 0, stream>>>(z, adjG, zt, Wd,
                                                       b0, b1, b2, b3,
                                                       c1w, c1b, c2w, c2b,
                                                       l1w, l1b, l2w, l2b,
                                                       xdump, out);
    } else {
        gnn_kernel<<<NGRAPH, 512, 0, stream>>>(z, adjG, zt,
                                               W0, b0, W1, b1, W2, b2, W3, b3,
                                               c1w, c1b, c2w, c2b, l1w, l1b, l2w, l2b,
                                               out);
    }
}

// Round 10
// 651.989 us; speedup vs baseline: 1.1867x; 1.1867x over previous
//
#include <hip/hip_runtime.h>

#define NGRAPH  1024
#define E_EDGES 2097152
#define ECAP    2944
#define MAXZ    1000

#if defined(__has_builtin)
#  if __has_builtin(__builtin_amdgcn_mfma_f64_16x16x4f64)
#    define HAVE_MFMA64 1
#  endif
#endif
#ifndef HAVE_MFMA64
#  define HAVE_MFMA64 0
#endif

typedef __attribute__((ext_vector_type(4))) double double4v;

__device__ __forceinline__ float bfu_lo(unsigned u) { return __uint_as_float(u << 16); }
__device__ __forceinline__ float bfu_hi(unsigned u) { return __uint_as_float(u & 0xFFFF0000u); }
__device__ __forceinline__ unsigned packlo(float f0, float f1) {
    return (__float_as_uint(f0) >> 16) | (__float_as_uint(f1) & 0xFFFF0000u);
}
// XOR-swizzled X indices (conflict-free vector access)
__device__ __forceinline__ int xh_idx(int r, int k)  { return (r << 6) | (k  ^ ((r & 7) << 3)); }
__device__ __forceinline__ int xl_idx(int r, int k2) { return (r << 5) | (k2 ^ ((r & 7) << 2)); }

// branchless double tanh via e^{2p}; abs error ~2e-13
__device__ __forceinline__ double tanh_fast(double p) {
    double q = 2.0 * p;
    q = fmin(40.0, fmax(-40.0, q));
    double nf = rint(q * 1.4426950408889634074);
    double r  = fma(nf, -6.93147180369123816490e-01, q);
    r = fma(nf, -1.90821492927058770002e-10, r);
    double er =     2.755731922398589e-07;
    er = fma(er, r, 2.755731922398589e-06);
    er = fma(er, r, 2.4801587301587302e-05);
    er = fma(er, r, 1.984126984126984e-04);
    er = fma(er, r, 1.3888888888888889e-03);
    er = fma(er, r, 8.333333333333333e-03);
    er = fma(er, r, 4.1666666666666664e-02);
    er = fma(er, r, 1.6666666666666666e-01);
    er = fma(er, r, 0.5);
    er = fma(er, r, 1.0);
    er = fma(er, r, 1.0);                        // e^r
    double E = er * __longlong_as_double((long long)(1023 + (int)nf) << 52);
    return 1.0 - 2.0 / (E + 1.0);
}

__global__ void markWS_kernel(float* out) {
    int i = blockIdx.x * 256 + threadIdx.x;
    if (i < NGRAPH) out[i] = 2.0f;
}

// packed adjacency counts: adjG[g][d][s/4] byte-lane (s&3); commutative atomics
__global__ void adjscatter_kernel(const int* __restrict__ ei,
                                  unsigned* __restrict__ adjG) {
    int e = blockIdx.x * 256 + threadIdx.x;
    if (e >= E_EDGES) return;
    int s = ei[e];
    int d = ei[E_EDGES + e];
    int g = s >> 7;
    int sl = s & 127, dl = d & 127;
    atomicAdd(&adjG[((size_t)g << 12) + (dl << 5) + (sl >> 2)], 1u << ((sl & 3) << 3));
}

// HW-verify the f64 MFMA fragment layout with asymmetric exact-integer matrices.
// Assumed mapping (gfx90a-lineage 16x16x4): A[i][k]: i=lane&15, k=lane>>4;
// B[k][j]: j=lane&15, k=lane>>4; D[i][j]: j=lane&15, i=4*(lane>>4)+v.
// All products exact in f64 -> equality check is decisive. flag=0 -> vector fallback.
__global__ void mfmaprobe_kernel(int* flag) {
#if HAVE_MFMA64
    int l = threadIdx.x;
    int i16 = l & 15, kq = l >> 4;
    double A = (double)(i16 * 17 + kq * 3 + 1);
    double B = (double)(kq * 7 + i16 * 29 + 2);
    double4v acc = {0.0, 0.0, 0.0, 0.0};
    acc = __builtin_amdgcn_mfma_f64_16x16x4f64(A, B, acc, 0, 0, 0);
    bool ok = true;
#pragma unroll
    for (int v = 0; v < 4; ++v) {
        int i = (kq << 2) + v;
        int j = i16;
        double ref = 0.0;
#pragma unroll
        for (int k = 0; k < 4; ++k)
            ref += (double)(i * 17 + k * 3 + 1) * (double)(k * 7 + j * 29 + 2);
        ok = ok && (acc[v] == ref);
    }
    unsigned long long m = __ballot(ok);
    if (l == 0) flag[0] = (m == 0xFFFFFFFFFFFFFFFFull) ? 1 : 0;
#else
    if (threadIdx.x == 0) flag[0] = 0;
#endif
}

// ============ primary: 1024 threads = 2 graphs/block (r6 anchor) ============
// 16 waves/CU (VGPR cap 64). Phase 1 branches (block-uniform, probe-verified):
//   MFMA path: v_mfma_f64_16x16x4 — per wave a 16-row block x 4 col-tiles, K=64 in
//     16 steps; x reconstructed exactly as (double)hi + (double)lo; w = (double)f32.
//     Collapses 16 vector f64 FMA -> 1 matrix instr, frees VALU.
//   vector path: r6's proven one-pass k-loop (475us).
// Storage format (f32 hi + bf16 lo in swizzled LDS), phase 2, key, head: r6 verbatim.
__global__ __launch_bounds__(1024, 1) void gnn2_kernel(
    const int* __restrict__ z,
    const unsigned* __restrict__ adjG,
    const float* __restrict__ zt,
    const float* __restrict__ W0, const float* __restrict__ b0,
    const float* __restrict__ W1, const float* __restrict__ b1,
    const float* __restrict__ W2, const float* __restrict__ b2,
    const float* __restrict__ W3, const float* __restrict__ b3,
    const float* __restrict__ c1w, const float* __restrict__ c1b,
    const float* __restrict__ c2w, const float* __restrict__ c2b,
    const float* __restrict__ l1w, const float* __restrict__ l1b,
    const float* __restrict__ l2w, const float* __restrict__ l2b,
    const int* __restrict__ mfmaflag,
    float* __restrict__ xdump,
    float* __restrict__ out)
{
    __shared__ __align__(16) float    Xhi[2][8192];   // 65536 B (adjM overlay during setup)
    __shared__ __align__(16) unsigned Xlo[2][4096];   // 32768 B (h4s/key/head overlays)
    __shared__ unsigned char  csr[2][ECAP];           //  5888 B
    __shared__ unsigned short rp16[2][132];
    __shared__ int            aux[2][128];            // degree
    __shared__ int            inv[2][30];
    __shared__ float          kd30f[2][30];
    __shared__ int            w0tot[2];
    // ~106.4 KB -> one 16-wave block/CU

    const int half = threadIdx.x >> 9;                // 0/1: waves 0-7 / 8-15
    const int tt   = threadIdx.x & 511;
    const int g    = (blockIdx.x << 1) | half;
    const int r0 = tt >> 3;
    const int r1 = r0 + 64;
    const int c0 = (tt & 7) << 3;

    float*          XH = Xhi[half];
    unsigned*       XL = Xlo[half];
    unsigned char*  CS = csr[half];
    unsigned short* RP = rp16[half];
    int*            AX = aux[half];

#if HAVE_MFMA64
    const bool use_mfma = (mfmaflag[0] != 0);
#endif

    unsigned* adjM = (unsigned*)XH;   // [128][32] packed byte counts (16 KB)

    // load this graph's adjacency-count slab (coalesced)
    {
        const uint4* src = (const uint4*)(adjG + ((size_t)g << 12));
        uint4* dst = (uint4*)adjM;
        for (int i = tt; i < 1024; i += 512) dst[i] = src[i];
    }
    if (tt < 30) { inv[half][tt] = tt; kd30f[half][tt] = 0.f; }
    __syncthreads();

    // per-node in-degree
    int degv = 0;
    if (tt < 128) {
        for (int w = 0; w < 32; ++w) {
            unsigned u = adjM[(tt << 5) + w];
            degv += (int)((u & 255u) + ((u >> 8) & 255u) + ((u >> 16) & 255u) + (u >> 24));
        }
        AX[tt] = degv;
    }
    // exclusive scan (two waves per half)
    if (tt < 128) {
        int v = degv;
        for (int o = 1; o < 64; o <<= 1) {
            int u = __shfl_up(v, o, 64);
            if ((tt & 63) >= o) v += u;
        }
        if (tt == 63) w0tot[half] = v;
        RP[tt + 1] = (unsigned short)v;
    }
    __syncthreads();
    if (tt >= 64 && tt < 128) RP[tt + 1] = (unsigned short)(RP[tt + 1] + w0tot[half]);
    if (tt == 0) RP[0] = 0;
    __syncthreads();

    const int mydeg = (tt < 128) ? AX[tt] : 0;
    const double dv0 = 1.0 / sqrt((double)(AX[r0] + 1));
    const double dv1 = 1.0 / sqrt((double)(AX[r1] + 1));
    const double dvm = 1.0 / sqrt((double)(mydeg + 1));

    // deterministic CSR emit (s ascending, multiplicity preserved)
    if (tt < 128) {
        unsigned pos = RP[tt];
        for (int w = 0; w < 32; ++w) {
            unsigned u = adjM[(tt << 5) + w];
            while (u) {
                int b2 = (u & 0xFFu) ? 0 : (u & 0xFF00u) ? 1 : (u & 0xFF0000u) ? 2 : 3;
                int m = (int)((u >> (b2 << 3)) & 255u);
                unsigned char sv = (unsigned char)((w << 2) + b2);
                for (int q = 0; q < m; ++q) { if (pos < ECAP) CS[pos] = sv; ++pos; }
                u &= ~(0xFFu << (b2 << 3));
            }
        }
    }
    __syncthreads();                 // adjM reads done; XH free

    // X0 = z_table[z] (bf16-exact f32; lo path skipped in layer 0)
    for (int idx = tt; idx < 8192; idx += 512) {
        int n = idx >> 6, c = idx & 63;
        int zv = z[(g << 7) + n];
        zv = (zv < 0) ? 0 : ((zv >= MAXZ) ? MAXZ - 1 : zv);
        XH[xh_idx(n, c)] = zt[zv * 64 + c];
    }
    __syncthreads();

    // ---- three GCN layers ----
    for (int layer = 0; layer < 3; ++layer) {
        const float* Wg = (layer == 0) ? W0 : (layer == 1) ? W1 : W2;
        const float* bg = (layer == 0) ? b0 : (layer == 1) ? b1 : b2;
        const bool haslo = (layer != 0);

#if HAVE_MFMA64
        if (use_mfma) {
            // ---------- MFMA phase 1 ----------
            const int lane = tt & 63;
            const int wv   = tt >> 6;          // 0..7 within half
            const int rowbase = wv << 4;       // 16 rows per wave
            const int arow = rowbase + (lane & 15);
            const int kq   = lane >> 4;        // 0..3
            double4v acc0 = {0.0, 0.0, 0.0, 0.0};
            double4v acc1 = {0.0, 0.0, 0.0, 0.0};
            double4v acc2 = {0.0, 0.0, 0.0, 0.0};
            double4v acc3 = {0.0, 0.0, 0.0, 0.0};
            for (int ks = 0; ks < 16; ++ks) {
                int k = (ks << 2) + kq;
                double x = (double)XH[xh_idx(arow, k)];
                if (haslo) {
                    unsigned u = XL[xl_idx(arow, k >> 1)];
                    x += (double)((k & 1) ? bfu_hi(u) : bfu_lo(u));
                }
                const float* wrk = Wg + (k << 6) + (lane & 15);
                acc0 = __builtin_amdgcn_mfma_f64_16x16x4f64(x, (double)wrk[0],  acc0, 0, 0, 0);
                acc1 = __builtin_amdgcn_mfma_f64_16x16x4f64(x, (double)wrk[16], acc1, 0, 0, 0);
                acc2 = __builtin_amdgcn_mfma_f64_16x16x4f64(x, (double)wrk[32], acc2, 0, 0, 0);
                acc3 = __builtin_amdgcn_mfma_f64_16x16x4f64(x, (double)wrk[48], acc3, 0, 0, 0);
            }
            __syncthreads();                   // all X reads complete

            // H = dinv * acc; convert to hi/lo and store (D: row=rowbase+4*kq+v, col=t4*16+(lane&15))
            double dvv[4];
#pragma unroll
            for (int v = 0; v < 4; ++v)
                dvv[v] = 1.0 / sqrt((double)(AX[rowbase + (kq << 2) + v] + 1));

#define STORE_TILE(ACC, T4)                                                       \
            {                                                                     \
                int ocol = ((T4) << 4) + (lane & 15);                             \
                _Pragma("unroll")                                                 \
                for (int v = 0; v < 4; ++v) {                                     \
                    int orow = rowbase + (kq << 2) + v;                           \
                    double h = dvv[v] * (ACC)[v];                                 \
                    float hf = (float)h;                                          \
                    float rs = (float)(h - (double)hf);                           \
                    XH[xh_idx(orow, ocol)] = hf;                                  \
                    float rsp = __shfl_xor(rs, 1, 64);                            \
                    if (!(lane & 1))                                              \
                        XL[xl_idx(orow, ocol >> 1)] = packlo(rs, rsp);            \
                }                                                                 \
            }
            STORE_TILE(acc0, 0)
            STORE_TILE(acc1, 1)
            STORE_TILE(acc2, 2)
            STORE_TILE(acc3, 3)
#undef STORE_TILE
            __syncthreads();                   // H fully written

            // ---------- phase 2 (reload-init; bits identical to reg-init) ----------
            double ad[2][8]; float af[2][8];
#pragma unroll
            for (int rw = 0; rw < 2; ++rw) {
                int rr = rw ? r1 : r0;
                int bio = xh_idx(rr, c0);
                float4 h0 = *(const float4*)&XH[bio];
                float4 h1 = *(const float4*)&XH[bio + 4];
                uint4  lo = *(const uint4*)&XL[xl_idx(rr, c0 >> 1)];
                ad[rw][0] = (double)h0.x; ad[rw][1] = (double)h0.y;
                ad[rw][2] = (double)h0.z; ad[rw][3] = (double)h0.w;
                ad[rw][4] = (double)h1.x; ad[rw][5] = (double)h1.y;
                ad[rw][6] = (double)h1.z; ad[rw][7] = (double)h1.w;
                af[rw][0] = bfu_lo(lo.x); af[rw][1] = bfu_hi(lo.x);
                af[rw][2] = bfu_lo(lo.y); af[rw][3] = bfu_hi(lo.y);
                af[rw][4] = bfu_lo(lo.z); af[rw][5] = bfu_hi(lo.z);
                af[rw][6] = bfu_lo(lo.w); af[rw][7] = bfu_hi(lo.w);
            }
#pragma unroll
            for (int rw = 0; rw < 2; ++rw) {
                int rr = rw ? r1 : r0;
                for (unsigned e = RP[rr]; e < RP[rr + 1]; ++e) {
                    int s = CS[e];
                    int bi = (s << 6) | (c0 ^ ((s & 7) << 3));
                    float4 a = *(const float4*)&XH[bi];
                    float4 b = *(const float4*)&XH[bi + 4];
                    uint4 lu = *(const uint4*)&XL[(s << 5) | ((c0 >> 1) ^ ((s & 7) << 2))];
                    ad[rw][0] += (double)a.x; ad[rw][1] += (double)a.y;
                    ad[rw][2] += (double)a.z; ad[rw][3] += (double)a.w;
                    ad[rw][4] += (double)b.x; ad[rw][5] += (double)b.y;
                    ad[rw][6] += (double)b.z; ad[rw][7] += (double)b.w;
                    af[rw][0] += bfu_lo(lu.x); af[rw][1] += bfu_hi(lu.x);
                    af[rw][2] += bfu_lo(lu.y); af[rw][3] += bfu_hi(lu.y);
                    af[rw][4] += bfu_lo(lu.z); af[rw][5] += bfu_hi(lu.z);
                    af[rw][6] += bfu_lo(lu.w); af[rw][7] += bfu_hi(lu.w);
                }
            }
            __syncthreads();                   // all H reads complete

            // X = tanh(dinv*agg + b); dump layer-0/1 for head-side conv1
#pragma unroll
            for (int rw = 0; rw < 2; ++rw) {
                int rr = rw ? r1 : r0;
                double dv = rw ? dv1 : dv0;
                float vf[8], rs2[8];
#pragma unroll
                for (int j = 0; j < 8; ++j) {
                    double v = tanh_fast(dv * (ad[rw][j] + (double)af[rw][j]) + (double)bg[c0 + j]);
                    float vfl = (float)v;
                    vf[j] = vfl;
                    rs2[j] = (float)(v - (double)vfl);
                }
                int bi = xh_idx(rr, c0);
                *(float4*)&XH[bi]     = make_float4(vf[0], vf[1], vf[2], vf[3]);
                *(float4*)&XH[bi + 4] = make_float4(vf[4], vf[5], vf[6], vf[7]);
                uint4 lv;
                lv.x = packlo(rs2[0], rs2[1]);
                lv.y = packlo(rs2[2], rs2[3]);
                lv.z = packlo(rs2[4], rs2[5]);
                lv.w = packlo(rs2[6], rs2[7]);
                *(uint4*)&XL[xl_idx(rr, c0 >> 1)] = lv;

                if (layer < 2) {
                    float* xd = xdump + (((size_t)g * 2 + layer) << 13) + (rr << 6) + c0;
                    *(float4*)xd       = make_float4(vf[0], vf[1], vf[2], vf[3]);
                    *(float4*)(xd + 4) = make_float4(vf[4], vf[5], vf[6], vf[7]);
                }
            }
        } else
#endif
        {
            // ---------- vector phase 1 (r6 verbatim, 475us-proven) ----------
            double accd0[8], accd1[8]; float accf0[8], accf1[8];
#pragma unroll
            for (int j = 0; j < 8; ++j) { accd0[j] = 0.0; accd1[j] = 0.0; accf0[j] = 0.f; accf1[j] = 0.f; }

            for (int k = 0; k < 64; k += 4) {
                float4 a0 = *(const float4*)&XH[xh_idx(r0, k)];
                float4 a1 = *(const float4*)&XH[xh_idx(r1, k)];
                float x0[4] = {a0.x, a0.y, a0.z, a0.w};
                float x1[4] = {a1.x, a1.y, a1.z, a1.w};
                float l0[4], l1[4];
                if (haslo) {
                    uint2 u0 = *(const uint2*)&XL[xl_idx(r0, k >> 1)];
                    uint2 u1 = *(const uint2*)&XL[xl_idx(r1, k >> 1)];
                    l0[0] = bfu_lo(u0.x); l0[1] = bfu_hi(u0.x); l0[2] = bfu_lo(u0.y); l0[3] = bfu_hi(u0.y);
                    l1[0] = bfu_lo(u1.x); l1[1] = bfu_hi(u1.x); l1[2] = bfu_lo(u1.y); l1[3] = bfu_hi(u1.y);
                }
#pragma unroll
                for (int kk = 0; kk < 4; ++kk) {
                    const float* wr = Wg + ((k + kk) << 6) + c0;
                    float4 wa = *(const float4*)wr;
                    float4 wb = *(const float4*)(wr + 4);
                    float wf[8] = {wa.x, wa.y, wa.z, wa.w, wb.x, wb.y, wb.z, wb.w};
                    double xd0 = (double)x0[kk], xd1 = (double)x1[kk];
#pragma unroll
                    for (int j = 0; j < 8; ++j) {
                        double wd = (double)wf[j];
                        accd0[j] = fma(xd0, wd, accd0[j]);
                        accd1[j] = fma(xd1, wd, accd1[j]);
                    }
                    if (haslo) {
#pragma unroll
                        for (int j = 0; j < 8; ++j) {
                            accf0[j] = fmaf(l0[kk], wf[j], accf0[j]);
                            accf1[j] = fmaf(l1[kk], wf[j], accf1[j]);
                        }
                    }
                }
            }
            __syncthreads();                   // all X reads complete

            float hfv[2][8], rsv[2][8];
#pragma unroll
            for (int rw = 0; rw < 2; ++rw) {
                int rr = rw ? r1 : r0;
                double dv = rw ? dv1 : dv0;
#pragma unroll
                for (int j = 0; j < 8; ++j) {
                    double acc = rw ? (accd1[j] + (double)accf1[j]) : (accd0[j] + (double)accf0[j]);
                    double h = dv * acc;
                    float hf = (float)h;
                    hfv[rw][j] = hf;
                    rsv[rw][j] = (float)(h - (double)hf);
                }
                int bi = xh_idx(rr, c0);
                *(float4*)&XH[bi]     = make_float4(hfv[rw][0], hfv[rw][1], hfv[rw][2], hfv[rw][3]);
                *(float4*)&XH[bi + 4] = make_float4(hfv[rw][4], hfv[rw][5], hfv[rw][6], hfv[rw][7]);
                uint4 lv;
                lv.x = packlo(rsv[rw][0], rsv[rw][1]);
                lv.y = packlo(rsv[rw][2], rsv[rw][3]);
                lv.z = packlo(rsv[rw][4], rsv[rw][5]);
                lv.w = packlo(rsv[rw][6], rsv[rw][7]);
                *(uint4*)&XL[xl_idx(rr, c0 >> 1)] = lv;
            }
            __syncthreads();                   // H fully written

            double ad[2][8]; float af[2][8];
#pragma unroll
            for (int rw = 0; rw < 2; ++rw)
#pragma unroll
                for (int j = 0; j < 8; ++j) { ad[rw][j] = (double)hfv[rw][j]; af[rw][j] = rsv[rw][j]; }

#pragma unroll
            for (int rw = 0; rw < 2; ++rw) {
                int rr = rw ? r1 : r0;
                for (unsigned e = RP[rr]; e < RP[rr + 1]; ++e) {
                    int s = CS[e];
                    int bi = (s << 6) | (c0 ^ ((s & 7) << 3));
                    float4 a = *(const float4*)&XH[bi];
                    float4 b = *(const float4*)&XH[bi + 4];
                    uint4 lu = *(const uint4*)&XL[(s << 5) | ((c0 >> 1) ^ ((s & 7) << 2))];
                    ad[rw][0] += (double)a.x; ad[rw][1] += (double)a.y;
                    ad[rw][2] += (double)a.z; ad[rw][3] += (double)a.w;
                    ad[rw][4] += (double)b.x; ad[rw][5] += (double)b.y;
                    ad[rw][6] += (double)b.z; ad[rw][7] += (double)b.w;
                    af[rw][0] += bfu_lo(lu.x); af[rw][1] += bfu_hi(lu.x);
                    af[rw][2] += bfu_lo(lu.y); af[rw][3] += bfu_hi(lu.y);
                    af[rw][4] += bfu_lo(lu.z); af[rw][5] += bfu_hi(lu.z);
                    af[rw][6] += bfu_lo(lu.w); af[rw][7] += bfu_hi(lu.w);
                }
            }
            __syncthreads();                   // all H reads complete

#pragma unroll
            for (int rw = 0; rw < 2; ++rw) {
                int rr = rw ? r1 : r0;
                double dv = rw ? dv1 : dv0;
                float vf[8], rs[8];
#pragma unroll
                for (int j = 0; j < 8; ++j) {
                    double v = tanh_fast(dv * (ad[rw][j] + (double)af[rw][j]) + (double)bg[c0 + j]);
                    float vfl = (float)v;
                    vf[j] = vfl;
                    rs[j] = (float)(v - (double)vfl);
                }
                int bi = xh_idx(rr, c0);
                *(float4*)&XH[bi]     = make_float4(vf[0], vf[1], vf[2], vf[3]);
                *(float4*)&XH[bi + 4] = make_float4(vf[4], vf[5], vf[6], vf[7]);
                uint4 lv;
                lv.x = packlo(rs[0], rs[1]);
                lv.y = packlo(rs[2], rs[3]);
                lv.z = packlo(rs[4], rs[5]);
                lv.w = packlo(rs[6], rs[7]);
                *(uint4*)&XL[xl_idx(rr, c0 >> 1)] = lv;

                if (layer < 2) {
                    float* xd = xdump + (((size_t)g * 2 + layer) << 13) + (rr << 6) + c0;
                    *(float4*)xd       = make_float4(vf[0], vf[1], vf[2], vf[3]);
                    *(float4*)(xd + 4) = make_float4(vf[4], vf[5], vf[6], vf[7]);
                }
            }
        }
        __syncthreads();
    }

    // ---- layer 4 (64->1): key path; overlays on dead XL ----
    double* h4sD  = (double*)XL;
    double* keydD = ((double*)XL) + 128;

    double sdreg = 0.0;
    if (tt < 128) {
        double sd = 0.0; float sf = 0.f;
        for (int k = 0; k < 64; k += 4) {
            float4 a = *(const float4*)&XH[xh_idx(tt, k)];
            uint2  u = *(const uint2*)&XL[xl_idx(tt, k >> 1)];
            float4 w = *(const float4*)&W3[k];
            sd = fma((double)a.x, (double)w.x, sd);
            sd = fma((double)a.y, (double)w.y, sd);
            sd = fma((double)a.z, (double)w.z, sd);
            sd = fma((double)a.w, (double)w.w, sd);
            sf = fmaf(bfu_lo(u.x), w.x, sf);
            sf = fmaf(bfu_hi(u.x), w.y, sf);
            sf = fmaf(bfu_lo(u.y), w.z, sf);
            sf = fmaf(bfu_hi(u.y), w.w, sf);
        }
        sdreg = sd + (double)sf;
    }
    __syncthreads();                          // XL reads done before overlay write
    if (tt < 128) h4sD[tt] = dvm * sdreg;
    __syncthreads();
    double keyreg = 0.0;
    if (tt < 128) {
        double a = h4sD[tt];
        for (unsigned e = RP[tt]; e < RP[tt + 1]; ++e) a += h4sD[CS[e]];
        keyreg = tanh_fast(dvm * a + (double)b3[0]);
        keydD[tt] = keyreg;
    }
    __syncthreads();

    // stable descending rank
    if (tt < 128) {
        int rk = 0;
        for (int j = 0; j < 128; ++j) {
            double kj = keydD[j];
            if (kj > keyreg || (kj == keyreg && j < tt)) ++rk;
        }
        if (rk < 30) { inv[half][rk] = tt; kd30f[half][rk] = (float)keyreg; }
    }
    __syncthreads();                         // publish inv/kd30f; keyd reads done

    // ---- head (per half, in its own XL slab) ----
    float* XloF = (float*)XL;
    float* h1v = XloF + 2560;   // 480
    float* ppv = XloF + 3040;   // 240
    float* flv = XloF + 3280;   // 352
    float* hmv = XloF + 3632;   // 128

    if (tt < 480) {
        int c = tt & 15, k = tt >> 4;
        int node = inv[half][k];
        // conv1 partials, bit-identical chain+tree (L0 j0..7, L1 j0..7, L2 j0..7; xor tree)
        const float* wrow = c1w + c * 193;
        const float* xg0 = xdump + ((size_t)g * 2) * 8192 + node * 64;
        const float* xg1 = xg0 + 8192;
        float s8[8];
#pragma unroll
        for (int cg = 0; cg < 8; ++cg) {
            float acc = 0.f;
            float4 xa = *(const float4*)&xg0[cg * 8];
            float4 xb = *(const float4*)&xg0[cg * 8 + 4];
            const float* w0p = wrow + cg * 8;
            acc = fmaf(xa.x, w0p[0], acc); acc = fmaf(xa.y, w0p[1], acc);
            acc = fmaf(xa.z, w0p[2], acc); acc = fmaf(xa.w, w0p[3], acc);
            acc = fmaf(xb.x, w0p[4], acc); acc = fmaf(xb.y, w0p[5], acc);
            acc = fmaf(xb.z, w0p[6], acc); acc = fmaf(xb.w, w0p[7], acc);
            float4 ya = *(const float4*)&xg1[cg * 8];
            float4 yb = *(const float4*)&xg1[cg * 8 + 4];
            const float* w1p = wrow + 64 + cg * 8;
            acc = fmaf(ya.x, w1p[0], acc); acc = fmaf(ya.y, w1p[1], acc);
            acc = fmaf(ya.z, w1p[2], acc); acc = fmaf(ya.w, w1p[3], acc);
            acc = fmaf(yb.x, w1p[4], acc); acc = fmaf(yb.y, w1p[5], acc);
            acc = fmaf(yb.z, w1p[6], acc); acc = fmaf(yb.w, w1p[7], acc);
            const float* w2p = wrow + 128 + cg * 8;
#pragma unroll
            for (int j = 0; j < 8; ++j)
                acc = fmaf(XH[xh_idx(node, cg * 8 + j)], w2p[j], acc);
            s8[cg] = acc;
        }
        float A0 = s8[0] + s8[1], A1 = s8[2] + s8[3];
        float A2 = s8[4] + s8[5], A3 = s8[6] + s8[7];
        float G = (A0 + A1) + (A2 + A3);
        float s = G + c1w[c * 193 + 192] * kd30f[half][k] + c1b[c];
        h1v[c * 30 + k] = s > 0.f ? s : 0.f;
    }
    __syncthreads();
    if (tt < 240) {
        int c = tt & 15, i = tt >> 4;
        float a = h1v[c * 30 + 2 * i], b = h1v[c * 30 + 2 * i + 1];
        ppv[c * 15 + i] = a > b ? a : b;
    }
    __syncthreads();
    if (tt < 352) {
        int o = tt / 11, j = tt % 11;
        float s = c2b[o];
        for (int i = 0; i < 16; ++i)
#pragma unroll
            for (int u = 0; u < 5; ++u)
                s = fmaf(ppv[i * 15 + j + u], c2w[o * 80 + i * 5 + u], s);
        flv[tt] = s > 0.f ? s : 0.f;
    }
    __syncthreads();
    if (tt < 128) {
        float s = l1b[tt];
        for (int i = 0; i < 352; ++i) s = fmaf(flv[i], l1w[i * 128 + tt], s);
        hmv[tt] = s > 0.f ? s : 0.f;
    }
    __syncthreads();
    if (tt < 64) {
        float v = fmaf(hmv[tt], l2w[tt], hmv[tt + 64] * l2w[tt + 64]);
#pragma unroll
        for (int o = 32; o > 0; o >>= 1) v += __shfl_down(v, o, 64);
        if (tt == 0) out[g] = v + l2b[0];
    }
}

// ============ fallback kernel: r2 fused variant (512 threads, 1 graph) ============
__global__ __launch_bounds__(512, 2) void gnn_kernel(
    const int* __restrict__ z,
    const unsigned* __restrict__ adjG,
    const float* __restrict__ zt,
    const float* __restrict__ W0, const float* __restrict__ b0,
    const float* __restrict__ W1, const float* __restrict__ b1,
    const float* __restrict__ W2, const float* __restrict__ b2,
    const float* __restrict__ W3, const float* __restrict__ b3,
    const float* __restrict__ c1w, const float* __restrict__ c1b,
    const float* __restrict__ c2w, const float* __restrict__ c2b,
    const float* __restrict__ l1w, const float* __restrict__ l1b,
    const float* __restrict__ l2w, const float* __restrict__ l2b,
    float* __restrict__ out)
{
    __shared__ __align__(16) float    Xhi[8192];
    __shared__ __align__(16) unsigned Xlo[4096];
    __shared__ unsigned char  csr[ECAP];
    __shared__ unsigned short rp16[132];
    __shared__ int            aux[128];
    __shared__ int            inv[30];
    __shared__ float          kd30f[30];
    __shared__ int            w0tot;

    const int g  = blockIdx.x;
    const int t  = threadIdx.x;
    const int r0 = t >> 3;
    const int r1 = r0 + 64;
    const int c0 = (t & 7) << 3;

    unsigned* adjM = (unsigned*)Xhi;

    {
        const uint4* src = (const uint4*)(adjG + ((size_t)g << 12));
        uint4* dst = (uint4*)adjM;
        for (int i = t; i < 1024; i += 512) dst[i] = src[i];
    }
    if (t < 30) { inv[t] = t; kd30f[t] = 0.f; }
    __syncthreads();

    int degv = 0;
    if (t < 128) {
        for (int w = 0; w < 32; ++w) {
            unsigned u = adjM[(t << 5) + w];
            degv += (int)((u & 255u) + ((u >> 8) & 255u) + ((u >> 16) & 255u) + (u >> 24));
        }
        aux[t] = degv;
    }
    if (t < 128) {
        int v = degv;
        for (int o = 1; o < 64; o <<= 1) {
            int u = __shfl_up(v, o, 64);
            if ((t & 63) >= o) v += u;
        }
        if (t == 63) w0tot = v;
        rp16[t + 1] = (unsigned short)v;
    }
    __syncthreads();
    if (t >= 64 && t < 128) rp16[t + 1] = (unsigned short)(rp16[t + 1] + w0tot);
    if (t == 0) rp16[0] = 0;
    __syncthreads();

    const int mydeg = (t < 128) ? aux[t] : 0;
    const double dv0 = 1.0 / sqrt((double)(aux[r0] + 1));
    const double dv1 = 1.0 / sqrt((double)(aux[r1] + 1));
    const double dvm = 1.0 / sqrt((double)(mydeg + 1));

    if (t < 128) {
        unsigned pos = rp16[t];
        for (int w = 0; w < 32; ++w) {
            unsigned u = adjM[(t << 5) + w];
            while (u) {
                int b2 = (u & 0xFFu) ? 0 : (u & 0xFF00u) ? 1 : (u & 0xFF0000u) ? 2 : 3;
                int m = (int)((u >> (b2 << 3)) & 255u);
                unsigned char sv = (unsigned char)((w << 2) + b2);
                for (int q = 0; q < m; ++q) { if (pos < ECAP) csr[pos] = sv; ++pos; }
                u &= ~(0xFFu << (b2 << 3));
            }
        }
    }
    __syncthreads();

    for (int idx = t; idx < 8192; idx += 512) {
        int n = idx >> 6, c = idx & 63;
        int zv = z[(g << 7) + n];
        zv = (zv < 0) ? 0 : ((zv >= MAXZ) ? MAXZ - 1 : zv);
        Xhi[xh_idx(n, c)] = zt[zv * 64 + c];
    }
    __syncthreads();

    float g1p[2][16];
#pragma unroll
    for (int rw = 0; rw < 2; ++rw)
#pragma unroll
        for (int c = 0; c < 16; ++c) g1p[rw][c] = 0.f;

    for (int layer = 0; layer < 3; ++layer) {
        const float* Wg = (layer == 0) ? W0 : (layer == 1) ? W1 : W2;
        const float* bg = (layer == 0) ? b0 : (layer == 1) ? b1 : b2;
        const bool haslo = (layer != 0);

        double accd0[8], accd1[8]; float accf0[8], accf1[8];
#pragma unroll
        for (int j = 0; j < 8; ++j) { accd0[j] = 0.0; accd1[j] = 0.0; accf0[j] = 0.f; accf1[j] = 0.f; }

        for (int k = 0; k < 64; k += 4) {
            float4 a0 = *(const float4*)&Xhi[xh_idx(r0, k)];
            float4 a1 = *(const float4*)&Xhi[xh_idx(r1, k)];
            float x0[4] = {a0.x, a0.y, a0.z, a0.w};
            float x1[4] = {a1.x, a1.y, a1.z, a1.w};
            float l0[4], l1[4];
            if (haslo) {
                uint2 u0 = *(const uint2*)&Xlo[xl_idx(r0, k >> 1)];
                uint2 u1 = *(const uint2*)&Xlo[xl_idx(r1, k >> 1)];
                l0[0] = bfu_lo(u0.x); l0[1] = bfu_hi(u0.x); l0[2] = bfu_lo(u0.y); l0[3] = bfu_hi(u0.y);
                l1[0] = bfu_lo(u1.x); l1[1] = bfu_hi(u1.x); l1[2] = bfu_lo(u1.y); l1[3] = bfu_hi(u1.y);
            }
#pragma unroll
            for (int kk = 0; kk < 4; ++kk) {
                const float* wr = Wg + ((k + kk) << 6) + c0;
                float4 wa = *(const float4*)wr;
                float4 wb = *(const float4*)(wr + 4);
                float wf[8] = {wa.x, wa.y, wa.z, wa.w, wb.x, wb.y, wb.z, wb.w};
                double xd0 = (double)x0[kk], xd1 = (double)x1[kk];
#pragma unroll
                for (int j = 0; j < 8; ++j) {
                    double wd = (double)wf[j];
                    accd0[j] = fma(xd0, wd, accd0[j]);
                    accd1[j] = fma(xd1, wd, accd1[j]);
                }
                if (haslo) {
#pragma unroll
                    for (int j = 0; j < 8; ++j) {
                        accf0[j] = fmaf(l0[kk], wf[j], accf0[j]);
                        accf1[j] = fmaf(l1[kk], wf[j], accf1[j]);
                    }
                }
            }
        }
        __syncthreads();

        float hfv[2][8], rsv[2][8];
#pragma unroll
        for (int rw = 0; rw < 2; ++rw) {
            int rr = rw ? r1 : r0;
            double dv = rw ? dv1 : dv0;
#pragma unroll
            for (int j = 0; j < 8; ++j) {
                double acc = rw ? (accd1[j] + (double)accf1[j]) : (accd0[j] + (double)accf0[j]);
                double h = dv * acc;
                float hf = (float)h;
                hfv[rw][j] = hf;
                rsv[rw][j] = (float)(h - (double)hf);
            }
            int bi = xh_idx(rr, c0);
            *(float4*)&Xhi[bi]     = make_float4(hfv[rw][0], hfv[rw][1], hfv[rw][2], hfv[rw][3]);
            *(float4*)&Xhi[bi + 4] = make_float4(hfv[rw][4], hfv[rw][5], hfv[rw][6], hfv[rw][7]);
            uint4 lv;
            lv.x = packlo(rsv[rw][0], rsv[rw][1]);
            lv.y = packlo(rsv[rw][2], rsv[rw][3]);
            lv.z = packlo(rsv[rw][4], rsv[rw][5]);
            lv.w = packlo(rsv[rw][6], rsv[rw][7]);
            *(uint4*)&Xlo[xl_idx(rr, c0 >> 1)] = lv;
        }
        __syncthreads();

        double ad[2][8]; float af[2][8];
#pragma unroll
        for (int rw = 0; rw < 2; ++rw)
#pragma unroll
            for (int j = 0; j < 8; ++j) { ad[rw][j] = (double)hfv[rw][j]; af[rw][j] = rsv[rw][j]; }

#pragma unroll
        for (int rw = 0; rw < 2; ++rw) {
            int rr = rw ? r1 : r0;
            for (unsigned e = rp16[rr]; e < rp16[rr + 1]; ++e) {
                int s = csr[e];
                int bi = (s << 6) | (c0 ^ ((s & 7) << 3));
                float4 a = *(const float4*)&Xhi[bi];
                float4 b = *(const float4*)&Xhi[bi + 4];
                uint4 lu = *(const uint4*)&Xlo[(s << 5) | ((c0 >> 1) ^ ((s & 7) << 2))];
                ad[rw][0] += (double)a.x; ad[rw][1] += (double)a.y;
                ad[rw][2] += (double)a.z; ad[rw][3] += (double)a.w;
                ad[rw][4] += (double)b.x; ad[rw][5] += (double)b.y;
                ad[rw][6] += (double)b.z; ad[rw][7] += (double)b.w;
                af[rw][0] += bfu_lo(lu.x); af[rw][1] += bfu_hi(lu.x);
                af[rw][2] += bfu_lo(lu.y); af[rw][3] += bfu_hi(lu.y);
                af[rw][4] += bfu_lo(lu.z); af[rw][5] += bfu_hi(lu.z);
                af[rw][6] += bfu_lo(lu.w); af[rw][7] += bfu_hi(lu.w);
            }
        }
        __syncthreads();

#pragma unroll
        for (int rw = 0; rw < 2; ++rw) {
            int rr = rw ? r1 : r0;
            double dv = rw ? dv1 : dv0;
            float vf[8], rs[8];
#pragma unroll
            for (int j = 0; j < 8; ++j) {
                double v = tanh_fast(dv * (ad[rw][j] + (double)af[rw][j]) + (double)bg[c0 + j]);
                float vfl = (float)v;
                vf[j] = vfl;
                rs[j] = (float)(v - (double)vfl);
            }
            int bi = xh_idx(rr, c0);
            *(float4*)&Xhi[bi]     = make_float4(vf[0], vf[1], vf[2], vf[3]);
            *(float4*)&Xhi[bi + 4] = make_float4(vf[4], vf[5], vf[6], vf[7]);
            uint4 lv;
            lv.x = packlo(rs[0], rs[1]);
            lv.y = packlo(rs[2], rs[3]);
            lv.z = packlo(rs[4], rs[5]);
            lv.w = packlo(rs[6], rs[7]);
            *(uint4*)&Xlo[xl_idx(rr, c0 >> 1)] = lv;

            const float* w1base = c1w + layer * 64 + c0;
            for (int c = 0; c < 16; ++c) {
                const float* wr = w1base + c * 193;
#pragma unroll
                for (int j = 0; j < 8; ++j)
                    g1p[rw][c] = fmaf(vf[j], wr[j], g1p[rw][c]);
            }
        }
        __syncthreads();
    }

    double* h4sD  = (double*)Xlo;
    double* keydD = ((double*)Xlo) + 128;

    double sdreg = 0.0;
    if (t < 128) {
        double sd = 0.0; float sf = 0.f;
        for (int k = 0; k < 64; k += 4) {
            float4 a = *(const float4*)&Xhi[xh_idx(t, k)];
            uint2  u = *(const uint2*)&Xlo[xl_idx(t, k >> 1)];
            float4 w = *(const float4*)&W3[k];
            sd = fma((double)a.x, (double)w.x, sd);
            sd = fma((double)a.y, (double)w.y, sd);
            sd = fma((double)a.z, (double)w.z, sd);
            sd = fma((double)a.w, (double)w.w, sd);
            sf = fmaf(bfu_lo(u.x), w.x, sf);
            sf = fmaf(bfu_hi(u.x), w.y, sf);
            sf = fmaf(bfu_lo(u.y), w.z, sf);
            sf = fmaf(bfu_hi(u.y), w.w, sf);
        }
        sdreg = sd + (double)sf;
    }
    __syncthreads();
    if (t < 128) h4sD[t] = dvm * sdreg;
    __syncthreads();
    double keyreg = 0.0;
    if (t < 128) {
        double a = h4sD[t];
        for (unsigned e = rp16[t]; e < rp16[t + 1]; ++e) a += h4sD[csr[e]];
        keyreg = tanh_fast(dvm * a + (double)b3[0]);
        keydD[t] = keyreg;
    }
    __syncthreads();

    if (t < 128) {
        int rk = 0;
        for (int j = 0; j < 128; ++j) {
            double kj = keydD[j];
            if (kj > keyreg || (kj == keyreg && j < t)) ++rk;
        }
        if (rk < 30) { inv[rk] = t; kd30f[rk] = (float)keyreg; }
    }

#pragma unroll
    for (int m = 1; m <= 4; m <<= 1) {
#pragma unroll
        for (int rw = 0; rw < 2; ++rw)
#pragma unroll
            for (int c = 0; c < 16; ++c)
                g1p[rw][c] += __shfl_xor(g1p[rw][c], m, 64);
    }
    __syncthreads();
    float* XloF = (float*)Xlo;
    float* G1   = XloF + 512;
    if ((t & 7) == 0) {
#pragma unroll
        for (int c = 0; c < 16; c += 4) {
            *(float4*)&G1[r0 * 16 + c] = make_float4(g1p[0][c], g1p[0][c + 1], g1p[0][c + 2], g1p[0][c + 3]);
            *(float4*)&G1[r1 * 16 + c] = make_float4(g1p[1][c], g1p[1][c + 1], g1p[1][c + 2], g1p[1][c + 3]);
        }
    }
    __syncthreads();

    float* h1v = XloF + 2560;
    float* ppv = XloF + 3040;
    float* flv = XloF + 3280;
    float* hmv = XloF + 3632;

    if (t < 480) {
        int c = t & 15, k = t >> 4;
        int node = inv[k];
        float s = G1[node * 16 + c] + c1w[c * 193 + 192] * kd30f[k] + c1b[c];
        h1v[c * 30 + k] = s > 0.f ? s : 0.f;
    }
    __syncthreads();
    if (t < 240) {
        int c = t & 15, i = t >> 4;
        float a = h1v[c * 30 + 2 * i], b = h1v[c * 30 + 2 * i + 1];
        ppv[c * 15 + i] = a > b ? a : b;
    }
    __syncthreads();
    if (t < 352) {
        int o = t / 11, j = t % 11;
        float s = c2b[o];
        for (int i = 0; i < 16; ++i)
#pragma unroll
            for (int u = 0; u < 5; ++u)
                s = fmaf(ppv[i * 15 + j + u], c2w[o * 80 + i * 5 + u], s);
        flv[t] = s > 0.f ? s : 0.f;
    }
    __syncthreads();
    if (t < 128) {
        float s = l1b[t];
        for (int i = 0; i < 352; ++i) s = fmaf(flv[i], l1w[i * 128 + t], s);
        hmv[t] = s > 0.f ? s : 0.f;
    }
    __syncthreads();
    if (t < 64) {
        float v = fmaf(hmv[t], l2w[t], hmv[t + 64] * l2w[t + 64]);
#pragma unroll
        for (int o = 32; o > 0; o >>= 1) v += __shfl_down(v, o, 64);
        if (t == 0) out[g] = v + l2b[0];
    }
}

// ---------------- launch ----------------

extern "C" void kernel_launch(void* const* d_in, const int* in_sizes, int n_in,
                              void* d_out, int out_size, void* d_ws, size_t ws_size,
                              hipStream_t stream) {
    const int*   z   = (const int*)d_in[0];
    const int*   ei  = (const int*)d_in[1];
    const float* zt  = (const float*)d_in[3];
    const float* W0  = (const float*)d_in[4];
    const float* b0  = (const float*)d_in[5];
    const float* W1  = (const float*)d_in[6];
    const float* b1  = (const float*)d_in[7];
    const float* W2  = (const float*)d_in[8];
    const float* b2  = (const float*)d_in[9];
    const float* W3  = (const float*)d_in[10];
    const float* b3  = (const float*)d_in[11];
    const float* c1w = (const float*)d_in[12];
    const float* c1b = (const float*)d_in[13];
    const float* c2w = (const float*)d_in[14];
    const float* c2b = (const float*)d_in[15];
    const float* l1w = (const float*)d_in[16];
    const float* l1b = (const float*)d_in[17];
    const float* l2w = (const float*)d_in[18];
    const float* l2b = (const float*)d_in[19];
    float* out = (float*)d_out;

    const size_t ADJ_B = (size_t)NGRAPH * 4096 * 4;            // 16.78 MB
    const size_t XD_B  = (size_t)NGRAPH * 2 * 8192 * 4;        // 67.11 MB (x dumps, layers 0-1)
    const size_t FL_B  = 256;                                  // mfma-probe flag
    if (ws_size < ADJ_B) {
        markWS_kernel<<<4, 256, 0, stream>>>(out);
        return;
    }

    unsigned* adjG = (unsigned*)d_ws;

    hipMemsetAsync(adjG, 0, ADJ_B, stream);
    adjscatter_kernel<<<(E_EDGES + 255) / 256, 256, 0, stream>>>(ei, adjG);

    if (ws_size >= ADJ_B + XD_B + FL_B) {
        float* xdump = (float*)((char*)d_ws + ADJ_B);
        int*   flag  = (int*)((char*)d_ws + ADJ_B + XD_B);
        mfmaprobe_kernel<<<1, 64, 0, stream>>>(flag);
        gnn2_kernel<<<NGRAPH / 2, 1024, 0, stream>>>(z, adjG, zt,
                                                     W0, b0, W1, b1, W2, b2, W3, b3,
                                                     c1w, c1b, c2w, c2b, l1w, l1b, l2w, l2b,
                                                     flag, xdump, out);
    } else {
        gnn_kernel<<<NGRAPH, 512, 0, stream>>>(z, adjG, zt,
                                               W0, b0, W1, b1, W2, b2, W3, b3,
                                               c1w, c1b, c2w, c2b, l1w, l1b, l2w, l2b,
                                               out);
    }
}

// Round 11
// 578.012 us; speedup vs baseline: 1.3386x; 1.1280x over previous
//
#include <hip/hip_runtime.h>

#define NGRAPH  1024
#define E_EDGES 2097152
#define ECAP    2944
#define MAXZ    1000

__device__ __forceinline__ float bfu_lo(unsigned u) { return __uint_as_float(u << 16); }
__device__ __forceinline__ float bfu_hi(unsigned u) { return __uint_as_float(u & 0xFFFF0000u); }
__device__ __forceinline__ unsigned packlo(float f0, float f1) {
    return (__float_as_uint(f0) >> 16) | (__float_as_uint(f1) & 0xFFFF0000u);
}
// XOR-swizzled X indices (conflict-free vector access)
__device__ __forceinline__ int xh_idx(int r, int k)  { return (r << 6) | (k  ^ ((r & 7) << 3)); }
__device__ __forceinline__ int xl_idx(int r, int k2) { return (r << 5) | (k2 ^ ((r & 7) << 2)); }

// branchless double tanh via e^{2p}; abs error ~2e-13
__device__ __forceinline__ double tanh_fast(double p) {
    double q = 2.0 * p;
    q = fmin(40.0, fmax(-40.0, q));
    double nf = rint(q * 1.4426950408889634074);
    double r  = fma(nf, -6.93147180369123816490e-01, q);
    r = fma(nf, -1.90821492927058770002e-10, r);
    double er =     2.755731922398589e-07;
    er = fma(er, r, 2.755731922398589e-06);
    er = fma(er, r, 2.4801587301587302e-05);
    er = fma(er, r, 1.984126984126984e-04);
    er = fma(er, r, 1.3888888888888889e-03);
    er = fma(er, r, 8.333333333333333e-03);
    er = fma(er, r, 4.1666666666666664e-02);
    er = fma(er, r, 1.6666666666666666e-01);
    er = fma(er, r, 0.5);
    er = fma(er, r, 1.0);
    er = fma(er, r, 1.0);                        // e^r
    double E = er * __longlong_as_double((long long)(1023 + (int)nf) << 52);
    return 1.0 - 2.0 / (E + 1.0);
}

__global__ void markWS_kernel(float* out) {
    int i = blockIdx.x * 256 + threadIdx.x;
    if (i < NGRAPH) out[i] = 2.0f;
}

// packed adjacency counts: adjG[g][d][s/4] byte-lane (s&3); commutative atomics
__global__ void adjscatter_kernel(const int* __restrict__ ei,
                                  unsigned* __restrict__ adjG) {
    int e = blockIdx.x * 256 + threadIdx.x;
    if (e >= E_EDGES) return;
    int s = ei[e];
    int d = ei[E_EDGES + e];
    int g = s >> 7;
    int sl = s & 127, dl = d & 127;
    atomicAdd(&adjG[((size_t)g << 12) + (dl << 5) + (sl >> 2)], 1u << ((sl & 3) << 3));
}

// ============ primary: 1024 threads = 2 graphs/block (r6 anchor + 2 cuts) ============
// r6 structure (16 waves/CU, 2 rows x 8ch / thread, one-pass phase 1) with:
//  (1) f32 lo-residual storage (no bf16 pack/unpack) — removes ~16 VALU/edge in
//      phase 2 and all packlo on stores. Accuracy strictly between r6 (bf16-lo)
//      and r3/r9 (exact f64), both measured absmax 0.0.
//  (2) degree-balanced row pairing: thread q handles rows perm[q], perm[127-q]
//      (perm = degree-descending rank sort) — equalizes phase-2 edge-loop trip
//      counts; per-row accumulation chains unchanged -> same bits.
__global__ __launch_bounds__(1024, 1) void gnn2_kernel(
    const int* __restrict__ z,
    const unsigned* __restrict__ adjG,
    const float* __restrict__ zt,
    const float* __restrict__ W0, const float* __restrict__ b0,
    const float* __restrict__ W1, const float* __restrict__ b1,
    const float* __restrict__ W2, const float* __restrict__ b2,
    const float* __restrict__ W3, const float* __restrict__ b3,
    const float* __restrict__ c1w, const float* __restrict__ c1b,
    const float* __restrict__ c2w, const float* __restrict__ c2b,
    const float* __restrict__ l1w, const float* __restrict__ l1b,
    const float* __restrict__ l2w, const float* __restrict__ l2b,
    float* __restrict__ xdump,
    float* __restrict__ out)
{
    __shared__ __align__(16) float    Xhi[2][8192];   // 65536 B (adjM overlay during setup)
    __shared__ __align__(16) float    Xlo[2][8192];   // 65536 B f32 residuals (h4s/key/head overlays)
    __shared__ unsigned char  csr[2][ECAP];           //  5888 B
    __shared__ unsigned short rp16[2][132];
    __shared__ int            aux[2][128];            // degree
    __shared__ unsigned char  perm[2][128];           // degree-descending row permutation
    __shared__ int            inv[2][30];
    __shared__ float          kd30f[2][30];
    __shared__ int            w0tot[2];
    // ~139 KB -> one 16-wave block/CU (same occupancy as r6's 106 KB)

    const int half = threadIdx.x >> 9;                // 0/1: waves 0-7 / 8-15
    const int tt   = threadIdx.x & 511;
    const int g    = (blockIdx.x << 1) | half;
    const int c0 = (tt & 7) << 3;

    float*          XH = Xhi[half];
    float*          XL = Xlo[half];
    unsigned char*  CS = csr[half];
    unsigned short* RP = rp16[half];
    int*            AX = aux[half];

    unsigned* adjM = (unsigned*)XH;   // [128][32] packed byte counts (16 KB)

    // load this graph's adjacency-count slab (coalesced)
    {
        const uint4* src = (const uint4*)(adjG + ((size_t)g << 12));
        uint4* dst = (uint4*)adjM;
        for (int i = tt; i < 1024; i += 512) dst[i] = src[i];
    }
    if (tt < 30) { inv[half][tt] = tt; kd30f[half][tt] = 0.f; }
    __syncthreads();

    // per-node in-degree
    int degv = 0;
    if (tt < 128) {
        for (int w = 0; w < 32; ++w) {
            unsigned u = adjM[(tt << 5) + w];
            degv += (int)((u & 255u) + ((u >> 8) & 255u) + ((u >> 16) & 255u) + (u >> 24));
        }
        AX[tt] = degv;
    }
    // exclusive scan (two waves per half)
    if (tt < 128) {
        int v = degv;
        for (int o = 1; o < 64; o <<= 1) {
            int u = __shfl_up(v, o, 64);
            if ((tt & 63) >= o) v += u;
        }
        if (tt == 63) w0tot[half] = v;
        RP[tt + 1] = (unsigned short)v;
    }
    __syncthreads();
    if (tt >= 64 && tt < 128) RP[tt + 1] = (unsigned short)(RP[tt + 1] + w0tot[half]);
    if (tt == 0) RP[0] = 0;
    __syncthreads();

    const int mydeg = (tt < 128) ? AX[tt] : 0;
    const double dvm = 1.0 / sqrt((double)(mydeg + 1));    // key-path dinv (t<128)

    // deterministic CSR emit (s ascending, multiplicity preserved)
    if (tt < 128) {
        unsigned pos = RP[tt];
        for (int w = 0; w < 32; ++w) {
            unsigned u = adjM[(tt << 5) + w];
            while (u) {
                int b2 = (u & 0xFFu) ? 0 : (u & 0xFF00u) ? 1 : (u & 0xFF0000u) ? 2 : 3;
                int m = (int)((u >> (b2 << 3)) & 255u);
                unsigned char sv = (unsigned char)((w << 2) + b2);
                for (int q = 0; q < m; ++q) { if (pos < ECAP) CS[pos] = sv; ++pos; }
                u &= ~(0xFFu << (b2 << 3));
            }
        }
    }
    // degree-descending rank sort -> perm (assignment only; math order per row unchanged)
    if (tt < 128) {
        int dmine = AX[tt];
        int rk = 0;
        for (int j = 0; j < 128; ++j) {
            int dj = AX[j];
            if (dj > dmine || (dj == dmine && j < tt)) ++rk;
        }
        perm[half][rk] = (unsigned char)tt;
    }
    __syncthreads();                 // adjM reads done; XH free; perm/CSR published

    const int q    = tt >> 3;
    const int rowA = perm[half][q];          // heavy row
    const int rowB = perm[half][127 - q];    // paired light row
    const double dvA = 1.0 / sqrt((double)(AX[rowA] + 1));
    const double dvB = 1.0 / sqrt((double)(AX[rowB] + 1));

    // X0 = z_table[z] (f32; lo path skipped in layer 0)
    for (int idx = tt; idx < 8192; idx += 512) {
        int n = idx >> 6, c = idx & 63;
        int zv = z[(g << 7) + n];
        zv = (zv < 0) ? 0 : ((zv >= MAXZ) ? MAXZ - 1 : zv);
        XH[xh_idx(n, c)] = zt[zv * 64 + c];
    }
    __syncthreads();

    // ---- three GCN layers ----
    for (int layer = 0; layer < 3; ++layer) {
        const float* Wg = (layer == 0) ? W0 : (layer == 1) ? W1 : W2;
        const float* bg = (layer == 0) ? b0 : (layer == 1) ? b1 : b2;
        const bool haslo = (layer != 0);

        // phase 1: acc = (X @ W)[rowA,rowB][c0..c0+7]; W from global (L1-resident)
        double accd0[8], accd1[8]; float accf0[8], accf1[8];
#pragma unroll
        for (int j = 0; j < 8; ++j) { accd0[j] = 0.0; accd1[j] = 0.0; accf0[j] = 0.f; accf1[j] = 0.f; }

        for (int k = 0; k < 64; k += 4) {
            float4 a0 = *(const float4*)&XH[xh_idx(rowA, k)];
            float4 a1 = *(const float4*)&XH[xh_idx(rowB, k)];
            float x0[4] = {a0.x, a0.y, a0.z, a0.w};
            float x1[4] = {a1.x, a1.y, a1.z, a1.w};
            float l0[4], l1[4];
            if (haslo) {
                float4 u0 = *(const float4*)&XL[xh_idx(rowA, k)];
                float4 u1 = *(const float4*)&XL[xh_idx(rowB, k)];
                l0[0] = u0.x; l0[1] = u0.y; l0[2] = u0.z; l0[3] = u0.w;
                l1[0] = u1.x; l1[1] = u1.y; l1[2] = u1.z; l1[3] = u1.w;
            }
#pragma unroll
            for (int kk = 0; kk < 4; ++kk) {
                const float* wr = Wg + ((k + kk) << 6) + c0;
                float4 wa = *(const float4*)wr;
                float4 wb = *(const float4*)(wr + 4);
                float wf[8] = {wa.x, wa.y, wa.z, wa.w, wb.x, wb.y, wb.z, wb.w};
                double xd0 = (double)x0[kk], xd1 = (double)x1[kk];
#pragma unroll
                for (int j = 0; j < 8; ++j) {
                    double wd = (double)wf[j];
                    accd0[j] = fma(xd0, wd, accd0[j]);
                    accd1[j] = fma(xd1, wd, accd1[j]);
                }
                if (haslo) {
#pragma unroll
                    for (int j = 0; j < 8; ++j) {
                        accf0[j] = fmaf(l0[kk], wf[j], accf0[j]);
                        accf1[j] = fmaf(l1[kk], wf[j], accf1[j]);
                    }
                }
            }
        }
        __syncthreads();                                   // all X reads complete

        // H = dinv * acc; store hi + f32 lo
        float hfv[2][8], rsv[2][8];
#pragma unroll
        for (int rw = 0; rw < 2; ++rw) {
            int rr = rw ? rowB : rowA;
            double dv = rw ? dvB : dvA;
#pragma unroll
            for (int j = 0; j < 8; ++j) {
                double acc = rw ? (accd1[j] + (double)accf1[j]) : (accd0[j] + (double)accf0[j]);
                double h = dv * acc;
                float hf = (float)h;
                hfv[rw][j] = hf;
                rsv[rw][j] = (float)(h - (double)hf);
            }
            int bi = xh_idx(rr, c0);
            *(float4*)&XH[bi]     = make_float4(hfv[rw][0], hfv[rw][1], hfv[rw][2], hfv[rw][3]);
            *(float4*)&XH[bi + 4] = make_float4(hfv[rw][4], hfv[rw][5], hfv[rw][6], hfv[rw][7]);
            *(float4*)&XL[bi]     = make_float4(rsv[rw][0], rsv[rw][1], rsv[rw][2], rsv[rw][3]);
            *(float4*)&XL[bi + 4] = make_float4(rsv[rw][4], rsv[rw][5], rsv[rw][6], rsv[rw][7]);
        }
        __syncthreads();                                   // H fully written

        // phase 2: agg = H[own] + sum_neighbors H[s] (deterministic per-row order)
        double ad[2][8]; float af[2][8];
#pragma unroll
        for (int rw = 0; rw < 2; ++rw)
#pragma unroll
            for (int j = 0; j < 8; ++j) { ad[rw][j] = (double)hfv[rw][j]; af[rw][j] = rsv[rw][j]; }

#pragma unroll
        for (int rw = 0; rw < 2; ++rw) {
            int rr = rw ? rowB : rowA;
            for (unsigned e = RP[rr]; e < RP[rr + 1]; ++e) {
                int s = CS[e];
                int bi = (s << 6) | (c0 ^ ((s & 7) << 3));
                float4 a  = *(const float4*)&XH[bi];
                float4 b  = *(const float4*)&XH[bi + 4];
                float4 la = *(const float4*)&XL[bi];
                float4 lb = *(const float4*)&XL[bi + 4];
                ad[rw][0] += (double)a.x; ad[rw][1] += (double)a.y;
                ad[rw][2] += (double)a.z; ad[rw][3] += (double)a.w;
                ad[rw][4] += (double)b.x; ad[rw][5] += (double)b.y;
                ad[rw][6] += (double)b.z; ad[rw][7] += (double)b.w;
                af[rw][0] += la.x; af[rw][1] += la.y;
                af[rw][2] += la.z; af[rw][3] += la.w;
                af[rw][4] += lb.x; af[rw][5] += lb.y;
                af[rw][6] += lb.z; af[rw][7] += lb.w;
            }
        }
        __syncthreads();                                   // all H reads complete

        // X = tanh(dinv*agg + b); dump layer-0/1 for head-side conv1
#pragma unroll
        for (int rw = 0; rw < 2; ++rw) {
            int rr = rw ? rowB : rowA;
            double dv = rw ? dvB : dvA;
            float vf[8], rs2[8];
#pragma unroll
            for (int j = 0; j < 8; ++j) {
                double v = tanh_fast(dv * (ad[rw][j] + (double)af[rw][j]) + (double)bg[c0 + j]);
                float vfl = (float)v;
                vf[j] = vfl;
                rs2[j] = (float)(v - (double)vfl);
            }
            int bi = xh_idx(rr, c0);
            *(float4*)&XH[bi]     = make_float4(vf[0], vf[1], vf[2], vf[3]);
            *(float4*)&XH[bi + 4] = make_float4(vf[4], vf[5], vf[6], vf[7]);
            *(float4*)&XL[bi]     = make_float4(rs2[0], rs2[1], rs2[2], rs2[3]);
            *(float4*)&XL[bi + 4] = make_float4(rs2[4], rs2[5], rs2[6], rs2[7]);

            if (layer < 2) {
                float* xd = xdump + (((size_t)g * 2 + layer) << 13) + (rr << 6) + c0;
                *(float4*)xd       = make_float4(vf[0], vf[1], vf[2], vf[3]);
                *(float4*)(xd + 4) = make_float4(vf[4], vf[5], vf[6], vf[7]);
            }
        }
        __syncthreads();
    }

    // ---- layer 4 (64->1): key path; overlays on dead XL ----
    double* h4sD  = (double*)XL;
    double* keydD = ((double*)XL) + 128;

    double sdreg = 0.0;
    if (tt < 128) {
        double sd = 0.0; float sf = 0.f;
        for (int k = 0; k < 64; k += 4) {
            float4 a = *(const float4*)&XH[xh_idx(tt, k)];
            float4 u = *(const float4*)&XL[xh_idx(tt, k)];
            float4 w = *(const float4*)&W3[k];
            sd = fma((double)a.x, (double)w.x, sd);
            sd = fma((double)a.y, (double)w.y, sd);
            sd = fma((double)a.z, (double)w.z, sd);
            sd = fma((double)a.w, (double)w.w, sd);
            sf = fmaf(u.x, w.x, sf);
            sf = fmaf(u.y, w.y, sf);
            sf = fmaf(u.z, w.z, sf);
            sf = fmaf(u.w, w.w, sf);
        }
        sdreg = sd + (double)sf;
    }
    __syncthreads();                          // XL reads done before overlay write
    if (tt < 128) h4sD[tt] = dvm * sdreg;
    __syncthreads();
    double keyreg = 0.0;
    if (tt < 128) {
        double a = h4sD[tt];
        for (unsigned e = RP[tt]; e < RP[tt + 1]; ++e) a += h4sD[CS[e]];
        keyreg = tanh_fast(dvm * a + (double)b3[0]);
        keydD[tt] = keyreg;
    }
    __syncthreads();

    // stable descending rank == stable argsort(-key)
    if (tt < 128) {
        int rk = 0;
        for (int j = 0; j < 128; ++j) {
            double kj = keydD[j];
            if (kj > keyreg || (kj == keyreg && j < tt)) ++rk;
        }
        if (rk < 30) { inv[half][rk] = tt; kd30f[half][rk] = (float)keyreg; }
    }
    __syncthreads();                         // publish inv/kd30f; keyd reads done

    // ---- head (per half, in its own XL slab past the key overlay) ----
    float* XloF = XL;
    float* h1v = XloF + 2560;   // 480
    float* ppv = XloF + 3040;   // 240
    float* flv = XloF + 3280;   // 352
    float* hmv = XloF + 3632;   // 128

    if (tt < 480) {
        int c = tt & 15, k = tt >> 4;
        int node = inv[half][k];
        // conv1 partials, bit-identical chain+tree (L0 j0..7, L1 j0..7, L2 j0..7; xor tree)
        const float* wrow = c1w + c * 193;
        const float* xg0 = xdump + ((size_t)g * 2) * 8192 + node * 64;
        const float* xg1 = xg0 + 8192;
        float s8[8];
#pragma unroll
        for (int cg = 0; cg < 8; ++cg) {
            float acc = 0.f;
            float4 xa = *(const float4*)&xg0[cg * 8];
            float4 xb = *(const float4*)&xg0[cg * 8 + 4];
            const float* w0p = wrow + cg * 8;
            acc = fmaf(xa.x, w0p[0], acc); acc = fmaf(xa.y, w0p[1], acc);
            acc = fmaf(xa.z, w0p[2], acc); acc = fmaf(xa.w, w0p[3], acc);
            acc = fmaf(xb.x, w0p[4], acc); acc = fmaf(xb.y, w0p[5], acc);
            acc = fmaf(xb.z, w0p[6], acc); acc = fmaf(xb.w, w0p[7], acc);
            float4 ya = *(const float4*)&xg1[cg * 8];
            float4 yb = *(const float4*)&xg1[cg * 8 + 4];
            const float* w1p = wrow + 64 + cg * 8;
            acc = fmaf(ya.x, w1p[0], acc); acc = fmaf(ya.y, w1p[1], acc);
            acc = fmaf(ya.z, w1p[2], acc); acc = fmaf(ya.w, w1p[3], acc);
            acc = fmaf(yb.x, w1p[4], acc); acc = fmaf(yb.y, w1p[5], acc);
            acc = fmaf(yb.z, w1p[6], acc); acc = fmaf(yb.w, w1p[7], acc);
            const float* w2p = wrow + 128 + cg * 8;
#pragma unroll
            for (int j = 0; j < 8; ++j)
                acc = fmaf(XH[xh_idx(node, cg * 8 + j)], w2p[j], acc);
            s8[cg] = acc;
        }
        float A0 = s8[0] + s8[1], A1 = s8[2] + s8[3];
        float A2 = s8[4] + s8[5], A3 = s8[6] + s8[7];
        float G = (A0 + A1) + (A2 + A3);
        float s = G + c1w[c * 193 + 192] * kd30f[half][k] + c1b[c];
        h1v[c * 30 + k] = s > 0.f ? s : 0.f;
    }
    __syncthreads();
    if (tt < 240) {
        int c = tt & 15, i = tt >> 4;
        float a = h1v[c * 30 + 2 * i], b = h1v[c * 30 + 2 * i + 1];
        ppv[c * 15 + i] = a > b ? a : b;
    }
    __syncthreads();
    if (tt < 352) {
        int o = tt / 11, j = tt % 11;
        float s = c2b[o];
        for (int i = 0; i < 16; ++i)
#pragma unroll
            for (int u = 0; u < 5; ++u)
                s = fmaf(ppv[i * 15 + j + u], c2w[o * 80 + i * 5 + u], s);
        flv[tt] = s > 0.f ? s : 0.f;
    }
    __syncthreads();
    if (tt < 128) {
        float s = l1b[tt];
        for (int i = 0; i < 352; ++i) s = fmaf(flv[i], l1w[i * 128 + tt], s);
        hmv[tt] = s > 0.f ? s : 0.f;
    }
    __syncthreads();
    if (tt < 64) {
        float v = fmaf(hmv[tt], l2w[tt], hmv[tt + 64] * l2w[tt + 64]);
#pragma unroll
        for (int o = 32; o > 0; o >>= 1) v += __shfl_down(v, o, 64);
        if (tt == 0) out[g] = v + l2b[0];
    }
}

// ============ fallback kernel: r2 fused variant (512 threads, 1 graph) ============
__global__ __launch_bounds__(512, 2) void gnn_kernel(
    const int* __restrict__ z,
    const unsigned* __restrict__ adjG,
    const float* __restrict__ zt,
    const float* __restrict__ W0, const float* __restrict__ b0,
    const float* __restrict__ W1, const float* __restrict__ b1,
    const float* __restrict__ W2, const float* __restrict__ b2,
    const float* __restrict__ W3, const float* __restrict__ b3,
    const float* __restrict__ c1w, const float* __restrict__ c1b,
    const float* __restrict__ c2w, const float* __restrict__ c2b,
    const float* __restrict__ l1w, const float* __restrict__ l1b,
    const float* __restrict__ l2w, const float* __restrict__ l2b,
    float* __restrict__ out)
{
    __shared__ __align__(16) float    Xhi[8192];
    __shared__ __align__(16) unsigned Xlo[4096];
    __shared__ unsigned char  csr[ECAP];
    __shared__ unsigned short rp16[132];
    __shared__ int            aux[128];
    __shared__ int            inv[30];
    __shared__ float          kd30f[30];
    __shared__ int            w0tot;

    const int g  = blockIdx.x;
    const int t  = threadIdx.x;
    const int r0 = t >> 3;
    const int r1 = r0 + 64;
    const int c0 = (t & 7) << 3;

    unsigned* adjM = (unsigned*)Xhi;

    {
        const uint4* src = (const uint4*)(adjG + ((size_t)g << 12));
        uint4* dst = (uint4*)adjM;
        for (int i = t; i < 1024; i += 512) dst[i] = src[i];
    }
    if (t < 30) { inv[t] = t; kd30f[t] = 0.f; }
    __syncthreads();

    int degv = 0;
    if (t < 128) {
        for (int w = 0; w < 32; ++w) {
            unsigned u = adjM[(t << 5) + w];
            degv += (int)((u & 255u) + ((u >> 8) & 255u) + ((u >> 16) & 255u) + (u >> 24));
        }
        aux[t] = degv;
    }
    if (t < 128) {
        int v = degv;
        for (int o = 1; o < 64; o <<= 1) {
            int u = __shfl_up(v, o, 64);
            if ((t & 63) >= o) v += u;
        }
        if (t == 63) w0tot = v;
        rp16[t + 1] = (unsigned short)v;
    }
    __syncthreads();
    if (t >= 64 && t < 128) rp16[t + 1] = (unsigned short)(rp16[t + 1] + w0tot);
    if (t == 0) rp16[0] = 0;
    __syncthreads();

    const int mydeg = (t < 128) ? aux[t] : 0;
    const double dv0 = 1.0 / sqrt((double)(aux[r0] + 1));
    const double dv1 = 1.0 / sqrt((double)(aux[r1] + 1));
    const double dvm = 1.0 / sqrt((double)(mydeg + 1));

    if (t < 128) {
        unsigned pos = rp16[t];
        for (int w = 0; w < 32; ++w) {
            unsigned u = adjM[(t << 5) + w];
            while (u) {
                int b2 = (u & 0xFFu) ? 0 : (u & 0xFF00u) ? 1 : (u & 0xFF0000u) ? 2 : 3;
                int m = (int)((u >> (b2 << 3)) & 255u);
                unsigned char sv = (unsigned char)((w << 2) + b2);
                for (int q = 0; q < m; ++q) { if (pos < ECAP) csr[pos] = sv; ++pos; }
                u &= ~(0xFFu << (b2 << 3));
            }
        }
    }
    __syncthreads();

    for (int idx = t; idx < 8192; idx += 512) {
        int n = idx >> 6, c = idx & 63;
        int zv = z[(g << 7) + n];
        zv = (zv < 0) ? 0 : ((zv >= MAXZ) ? MAXZ - 1 : zv);
        Xhi[xh_idx(n, c)] = zt[zv * 64 + c];
    }
    __syncthreads();

    float g1p[2][16];
#pragma unroll
    for (int rw = 0; rw < 2; ++rw)
#pragma unroll
        for (int c = 0; c < 16; ++c) g1p[rw][c] = 0.f;

    for (int layer = 0; layer < 3; ++layer) {
        const float* Wg = (layer == 0) ? W0 : (layer == 1) ? W1 : W2;
        const float* bg = (layer == 0) ? b0 : (layer == 1) ? b1 : b2;
        const bool haslo = (layer != 0);

        double accd0[8], accd1[8]; float accf0[8], accf1[8];
#pragma unroll
        for (int j = 0; j < 8; ++j) { accd0[j] = 0.0; accd1[j] = 0.0; accf0[j] = 0.f; accf1[j] = 0.f; }

        for (int k = 0; k < 64; k += 4) {
            float4 a0 = *(const float4*)&Xhi[xh_idx(r0, k)];
            float4 a1 = *(const float4*)&Xhi[xh_idx(r1, k)];
            float x0[4] = {a0.x, a0.y, a0.z, a0.w};
            float x1[4] = {a1.x, a1.y, a1.z, a1.w};
            float l0[4], l1[4];
            if (haslo) {
                uint2 u0 = *(const uint2*)&Xlo[xl_idx(r0, k >> 1)];
                uint2 u1 = *(const uint2*)&Xlo[xl_idx(r1, k >> 1)];
                l0[0] = bfu_lo(u0.x); l0[1] = bfu_hi(u0.x); l0[2] = bfu_lo(u0.y); l0[3] = bfu_hi(u0.y);
                l1[0] = bfu_lo(u1.x); l1[1] = bfu_hi(u1.x); l1[2] = bfu_lo(u1.y); l1[3] = bfu_hi(u1.y);
            }
#pragma unroll
            for (int kk = 0; kk < 4; ++kk) {
                const float* wr = Wg + ((k + kk) << 6) + c0;
                float4 wa = *(const float4*)wr;
                float4 wb = *(const float4*)(wr + 4);
                float wf[8] = {wa.x, wa.y, wa.z, wa.w, wb.x, wb.y, wb.z, wb.w};
                double xd0 = (double)x0[kk], xd1 = (double)x1[kk];
#pragma unroll
                for (int j = 0; j < 8; ++j) {
                    double wd = (double)wf[j];
                    accd0[j] = fma(xd0, wd, accd0[j]);
                    accd1[j] = fma(xd1, wd, accd1[j]);
                }
                if (haslo) {
#pragma unroll
                    for (int j = 0; j < 8; ++j) {
                        accf0[j] = fmaf(l0[kk], wf[j], accf0[j]);
                        accf1[j] = fmaf(l1[kk], wf[j], accf1[j]);
                    }
                }
            }
        }
        __syncthreads();

        float hfv[2][8], rsv[2][8];
#pragma unroll
        for (int rw = 0; rw < 2; ++rw) {
            int rr = rw ? r1 : r0;
            double dv = rw ? dv1 : dv0;
#pragma unroll
            for (int j = 0; j < 8; ++j) {
                double acc = rw ? (accd1[j] + (double)accf1[j]) : (accd0[j] + (double)accf0[j]);
                double h = dv * acc;
                float hf = (float)h;
                hfv[rw][j] = hf;
                rsv[rw][j] = (float)(h - (double)hf);
            }
            int bi = xh_idx(rr, c0);
            *(float4*)&Xhi[bi]     = make_float4(hfv[rw][0], hfv[rw][1], hfv[rw][2], hfv[rw][3]);
            *(float4*)&Xhi[bi + 4] = make_float4(hfv[rw][4], hfv[rw][5], hfv[rw][6], hfv[rw][7]);
            uint4 lv;
            lv.x = packlo(rsv[rw][0], rsv[rw][1]);
            lv.y = packlo(rsv[rw][2], rsv[rw][3]);
            lv.z = packlo(rsv[rw][4], rsv[rw][5]);
            lv.w = packlo(rsv[rw][6], rsv[rw][7]);
            *(uint4*)&Xlo[xl_idx(rr, c0 >> 1)] = lv;
        }
        __syncthreads();

        double ad[2][8]; float af[2][8];
#pragma unroll
        for (int rw = 0; rw < 2; ++rw)
#pragma unroll
            for (int j = 0; j < 8; ++j) { ad[rw][j] = (double)hfv[rw][j]; af[rw][j] = rsv[rw][j]; }

#pragma unroll
        for (int rw = 0; rw < 2; ++rw) {
            int rr = rw ? r1 : r0;
            for (unsigned e = rp16[rr]; e < rp16[rr + 1]; ++e) {
                int s = csr[e];
                int bi = (s << 6) | (c0 ^ ((s & 7) << 3));
                float4 a = *(const float4*)&Xhi[bi];
                float4 b = *(const float4*)&Xhi[bi + 4];
                uint4 lu = *(const uint4*)&Xlo[(s << 5) | ((c0 >> 1) ^ ((s & 7) << 2))];
                ad[rw][0] += (double)a.x; ad[rw][1] += (double)a.y;
                ad[rw][2] += (double)a.z; ad[rw][3] += (double)a.w;
                ad[rw][4] += (double)b.x; ad[rw][5] += (double)b.y;
                ad[rw][6] += (double)b.z; ad[rw][7] += (double)b.w;
                af[rw][0] += bfu_lo(lu.x); af[rw][1] += bfu_hi(lu.x);
                af[rw][2] += bfu_lo(lu.y); af[rw][3] += bfu_hi(lu.y);
                af[rw][4] += bfu_lo(lu.z); af[rw][5] += bfu_hi(lu.z);
                af[rw][6] += bfu_lo(lu.w); af[rw][7] += bfu_hi(lu.w);
            }
        }
        __syncthreads();

#pragma unroll
        for (int rw = 0; rw < 2; ++rw) {
            int rr = rw ? r1 : r0;
            double dv = rw ? dv1 : dv0;
            float vf[8], rs[8];
#pragma unroll
            for (int j = 0; j < 8; ++j) {
                double v = tanh_fast(dv * (ad[rw][j] + (double)af[rw][j]) + (double)bg[c0 + j]);
                float vfl = (float)v;
                vf[j] = vfl;
                rs[j] = (float)(v - (double)vfl);
            }
            int bi = xh_idx(rr, c0);
            *(float4*)&Xhi[bi]     = make_float4(vf[0], vf[1], vf[2], vf[3]);
            *(float4*)&Xhi[bi + 4] = make_float4(vf[4], vf[5], vf[6], vf[7]);
            uint4 lv;
            lv.x = packlo(rs[0], rs[1]);
            lv.y = packlo(rs[2], rs[3]);
            lv.z = packlo(rs[4], rs[5]);
            lv.w = packlo(rs[6], rs[7]);
            *(uint4*)&Xlo[xl_idx(rr, c0 >> 1)] = lv;

            const float* w1base = c1w + layer * 64 + c0;
            for (int c = 0; c < 16; ++c) {
                const float* wr = w1base + c * 193;
#pragma unroll
                for (int j = 0; j < 8; ++j)
                    g1p[rw][c] = fmaf(vf[j], wr[j], g1p[rw][c]);
            }
        }
        __syncthreads();
    }

    double* h4sD  = (double*)Xlo;
    double* keydD = ((double*)Xlo) + 128;

    double sdreg = 0.0;
    if (t < 128) {
        double sd = 0.0; float sf = 0.f;
        for (int k = 0; k < 64; k += 4) {
            float4 a = *(const float4*)&Xhi[xh_idx(t, k)];
            uint2  u = *(const uint2*)&Xlo[xl_idx(t, k >> 1)];
            float4 w = *(const float4*)&W3[k];
            sd = fma((double)a.x, (double)w.x, sd);
            sd = fma((double)a.y, (double)w.y, sd);
            sd = fma((double)a.z, (double)w.z, sd);
            sd = fma((double)a.w, (double)w.w, sd);
            sf = fmaf(bfu_lo(u.x), w.x, sf);
            sf = fmaf(bfu_hi(u.x), w.y, sf);
            sf = fmaf(bfu_lo(u.y), w.z, sf);
            sf = fmaf(bfu_hi(u.y), w.w, sf);
        }
        sdreg = sd + (double)sf;
    }
    __syncthreads();
    if (t < 128) h4sD[t] = dvm * sdreg;
    __syncthreads();
    double keyreg = 0.0;
    if (t < 128) {
        double a = h4sD[t];
        for (unsigned e = rp16[t]; e < rp16[t + 1]; ++e) a += h4sD[csr[e]];
        keyreg = tanh_fast(dvm * a + (double)b3[0]);
        keydD[t] = keyreg;
    }
    __syncthreads();

    if (t < 128) {
        int rk = 0;
        for (int j = 0; j < 128; ++j) {
            double kj = keydD[j];
            if (kj > keyreg || (kj == keyreg && j < t)) ++rk;
        }
        if (rk < 30) { inv[rk] = t; kd30f[rk] = (float)keyreg; }
    }

#pragma unroll
    for (int m = 1; m <= 4; m <<= 1) {
#pragma unroll
        for (int rw = 0; rw < 2; ++rw)
#pragma unroll
            for (int c = 0; c < 16; ++c)
                g1p[rw][c] += __shfl_xor(g1p[rw][c], m, 64);
    }
    __syncthreads();
    float* XloF = (float*)Xlo;
    float* G1   = XloF + 512;
    if ((t & 7) == 0) {
#pragma unroll
        for (int c = 0; c < 16; c += 4) {
            *(float4*)&G1[r0 * 16 + c] = make_float4(g1p[0][c], g1p[0][c + 1], g1p[0][c + 2], g1p[0][c + 3]);
            *(float4*)&G1[r1 * 16 + c] = make_float4(g1p[1][c], g1p[1][c + 1], g1p[1][c + 2], g1p[1][c + 3]);
        }
    }
    __syncthreads();

    float* h1v = XloF + 2560;
    float* ppv = XloF + 3040;
    float* flv = XloF + 3280;
    float* hmv = XloF + 3632;

    if (t < 480) {
        int c = t & 15, k = t >> 4;
        int node = inv[k];
        float s = G1[node * 16 + c] + c1w[c * 193 + 192] * kd30f[k] + c1b[c];
        h1v[c * 30 + k] = s > 0.f ? s : 0.f;
    }
    __syncthreads();
    if (t < 240) {
        int c = t & 15, i = t >> 4;
        float a = h1v[c * 30 + 2 * i], b = h1v[c * 30 + 2 * i + 1];
        ppv[c * 15 + i] = a > b ? a : b;
    }
    __syncthreads();
    if (t < 352) {
        int o = t / 11, j = t % 11;
        float s = c2b[o];
        for (int i = 0; i < 16; ++i)
#pragma unroll
            for (int u = 0; u < 5; ++u)
                s = fmaf(ppv[i * 15 + j + u], c2w[o * 80 + i * 5 + u], s);
        flv[t] = s > 0.f ? s : 0.f;
    }
    __syncthreads();
    if (t < 128) {
        float s = l1b[t];
        for (int i = 0; i < 352; ++i) s = fmaf(flv[i], l1w[i * 128 + t], s);
        hmv[t] = s > 0.f ? s : 0.f;
    }
    __syncthreads();
    if (t < 64) {
        float v = fmaf(hmv[t], l2w[t], hmv[t + 64] * l2w[t + 64]);
#pragma unroll
        for (int o = 32; o > 0; o >>= 1) v += __shfl_down(v, o, 64);
        if (t == 0) out[g] = v + l2b[0];
    }
}

// ---------------- launch ----------------

extern "C" void kernel_launch(void* const* d_in, const int* in_sizes, int n_in,
                              void* d_out, int out_size, void* d_ws, size_t ws_size,
                              hipStream_t stream) {
    const int*   z   = (const int*)d_in[0];
    const int*   ei  = (const int*)d_in[1];
    const float* zt  = (const float*)d_in[3];
    const float* W0  = (const float*)d_in[4];
    const float* b0  = (const float*)d_in[5];
    const float* W1  = (const float*)d_in[6];
    const float* b1  = (const float*)d_in[7];
    const float* W2  = (const float*)d_in[8];
    const float* b2  = (const float*)d_in[9];
    const float* W3  = (const float*)d_in[10];
    const float* b3  = (const float*)d_in[11];
    const float* c1w = (const float*)d_in[12];
    const float* c1b = (const float*)d_in[13];
    const float* c2w = (const float*)d_in[14];
    const float* c2b = (const float*)d_in[15];
    const float* l1w = (const float*)d_in[16];
    const float* l1b = (const float*)d_in[17];
    const float* l2w = (const float*)d_in[18];
    const float* l2b = (const float*)d_in[19];
    float* out = (float*)d_out;

    const size_t ADJ_B = (size_t)NGRAPH * 4096 * 4;            // 16.78 MB
    const size_t XD_B  = (size_t)NGRAPH * 2 * 8192 * 4;        // 67.11 MB (x dumps, layers 0-1)
    if (ws_size < ADJ_B) {
        markWS_kernel<<<4, 256, 0, stream>>>(out);
        return;
    }

    unsigned* adjG = (unsigned*)d_ws;

    hipMemsetAsync(adjG, 0, ADJ_B, stream);
    adjscatter_kernel<<<(E_EDGES + 255) / 256, 256, 0, stream>>>(ei, adjG);

    if (ws_size >= ADJ_B + XD_B) {
        float* xdump = (float*)((char*)d_ws + ADJ_B);
        gnn2_kernel<<<NGRAPH / 2, 1024, 0, stream>>>(z, adjG, zt,
                                                     W0, b0, W1, b1, W2, b2, W3, b3,
                                                     c1w, c1b, c2w, c2b, l1w, l1b, l2w, l2b,
                                                     xdump, out);
    } else {
        gnn_kernel<<<NGRAPH, 512, 0, stream>>>(z, adjG, zt,
                                               W0, b0, W1, b1, W2, b2, W3, b3,
                                               c1w, c1b, c2w, c2b, l1w, l1b, l2w, l2b,
                                               out);
    }
}

// Round 12
// 570.483 us; speedup vs baseline: 1.3563x; 1.0132x over previous
//
#include <hip/hip_runtime.h>

#define NGRAPH  1024
#define E_EDGES 2097152
#define ECAP    2944
#define MAXZ    1000

__device__ __forceinline__ float bfu_lo(unsigned u) { return __uint_as_float(u << 16); }
__device__ __forceinline__ float bfu_hi(unsigned u) { return __uint_as_float(u & 0xFFFF0000u); }
__device__ __forceinline__ unsigned packlo(float f0, float f1) {
    return (__float_as_uint(f0) >> 16) | (__float_as_uint(f1) & 0xFFFF0000u);
}
// XOR-swizzled indices: f32 X tile [128][64] (hi or lo plane)
__device__ __forceinline__ int xh_idx(int r, int k)  { return (r << 6) | (k  ^ ((r & 7) << 3)); }
__device__ __forceinline__ int xl_idx(int r, int k2) { return (r << 5) | (k2 ^ ((r & 7) << 2)); }
// XOR swizzle for f64 H tile [128][64] (r3/r9-validated)
__device__ __forceinline__ int xd_idx(int r, int c) {
    return (r << 6) | (c ^ ((r & 7) << 1) ^ ((c & 48) >> 3));
}

// branchless double tanh via e^{2p}; abs error ~2e-13
__device__ __forceinline__ double tanh_fast(double p) {
    double q = 2.0 * p;
    q = fmin(40.0, fmax(-40.0, q));
    double nf = rint(q * 1.4426950408889634074);
    double r  = fma(nf, -6.93147180369123816490e-01, q);
    r = fma(nf, -1.90821492927058770002e-10, r);
    double er =     2.755731922398589e-07;
    er = fma(er, r, 2.755731922398589e-06);
    er = fma(er, r, 2.4801587301587302e-05);
    er = fma(er, r, 1.984126984126984e-04);
    er = fma(er, r, 1.3888888888888889e-03);
    er = fma(er, r, 8.333333333333333e-03);
    er = fma(er, r, 4.1666666666666664e-02);
    er = fma(er, r, 1.6666666666666666e-01);
    er = fma(er, r, 0.5);
    er = fma(er, r, 1.0);
    er = fma(er, r, 1.0);                        // e^r
    double E = er * __longlong_as_double((long long)(1023 + (int)nf) << 52);
    return 1.0 - 2.0 / (E + 1.0);
}

__global__ void markWS_kernel(float* out) {
    int i = blockIdx.x * 256 + threadIdx.x;
    if (i < NGRAPH) out[i] = 2.0f;
}

// packed adjacency counts: adjG[g][d][s/4] byte-lane (s&3); commutative atomics
__global__ void adjscatter_kernel(const int* __restrict__ ei,
                                  unsigned* __restrict__ adjG) {
    int e = blockIdx.x * 256 + threadIdx.x;
    if (e >= E_EDGES) return;
    int s = ei[e];
    int d = ei[E_EDGES + e];
    int g = s >> 7;
    int sl = s & 127, dl = d & 127;
    atomicAdd(&adjG[((size_t)g << 12) + (dl << 5) + (sl >> 2)], 1u << ((sl & 3) << 3));
}

// ============ primary: 1024 threads = 2 graphs/block ============
// r11 anchor (440us) with two fixes:
//  (1) phase 1 back on NATURAL rows (r0=tt>>3, r0+64): xor-swizzle is conflict-free
//      only when a wave's 8 row-groups have distinct row&7 — perm broke that
//      (conflicts 2.0e7->3.3e7 in r11). Phase 2 keeps degree-balanced perm rows,
//      initializing from an LDS reload of own-H (bits = stored bits).
//  (2) H stored native f64 in a unified 64KB/graph buffer (double view of the same
//      memory holding X as f32 hi+lo planes). Same bytes/row, but phase 2 loses the
//      8 f32 shadow adds/edge and H-store loses the hi/lo split. f64 aggregation =
//      r3/r9-validated numerics (absmax 0.0).
__global__ __launch_bounds__(1024, 1) void gnn2_kernel(
    const int* __restrict__ z,
    const unsigned* __restrict__ adjG,
    const float* __restrict__ zt,
    const float* __restrict__ W0, const float* __restrict__ b0,
    const float* __restrict__ W1, const float* __restrict__ b1,
    const float* __restrict__ W2, const float* __restrict__ b2,
    const float* __restrict__ W3, const float* __restrict__ b3,
    const float* __restrict__ c1w, const float* __restrict__ c1b,
    const float* __restrict__ c2w, const float* __restrict__ c2b,
    const float* __restrict__ l1w, const float* __restrict__ l1b,
    const float* __restrict__ l2w, const float* __restrict__ l2b,
    float* __restrict__ xdump,
    float* __restrict__ out)
{
    __shared__ __align__(16) double   Xd[2][8192];    // 131072 B: X = f32 hi(32K)+lo(32K); H = f64(64K)
    __shared__ unsigned char  csr[2][ECAP];           //   5888 B
    __shared__ unsigned short rp16[2][132];
    __shared__ int            aux[2][128];            // degree
    __shared__ unsigned char  perm[2][128];           // degree-descending row permutation
    __shared__ int            inv[2][30];
    __shared__ float          kd30f[2][30];
    __shared__ int            w0tot[2];
    // ~139 KB -> one 16-wave block/CU

    const int half = threadIdx.x >> 9;                // 0/1: waves 0-7 / 8-15
    const int tt   = threadIdx.x & 511;
    const int g    = (blockIdx.x << 1) | half;
    const int c0   = (tt & 7) << 3;

    double*         HD = Xd[half];
    float*          XH = (float*)Xd[half];            // 8192 floats (hi plane)
    float*          XL = XH + 8192;                   // 8192 floats (lo plane)
    unsigned char*  CS = csr[half];
    unsigned short* RP = rp16[half];
    int*            AX = aux[half];

    unsigned* adjM = (unsigned*)XH;   // [128][32] packed byte counts (16 KB)

    // load this graph's adjacency-count slab (coalesced)
    {
        const uint4* src = (const uint4*)(adjG + ((size_t)g << 12));
        uint4* dst = (uint4*)adjM;
        for (int i = tt; i < 1024; i += 512) dst[i] = src[i];
    }
    if (tt < 30) { inv[half][tt] = tt; kd30f[half][tt] = 0.f; }
    __syncthreads();

    // per-node in-degree
    int degv = 0;
    if (tt < 128) {
        for (int w = 0; w < 32; ++w) {
            unsigned u = adjM[(tt << 5) + w];
            degv += (int)((u & 255u) + ((u >> 8) & 255u) + ((u >> 16) & 255u) + (u >> 24));
        }
        AX[tt] = degv;
    }
    // exclusive scan (two waves per half)
    if (tt < 128) {
        int v = degv;
        for (int o = 1; o < 64; o <<= 1) {
            int u = __shfl_up(v, o, 64);
            if ((tt & 63) >= o) v += u;
        }
        if (tt == 63) w0tot[half] = v;
        RP[tt + 1] = (unsigned short)v;
    }
    __syncthreads();
    if (tt >= 64 && tt < 128) RP[tt + 1] = (unsigned short)(RP[tt + 1] + w0tot[half]);
    if (tt == 0) RP[0] = 0;
    __syncthreads();

    const int mydeg = (tt < 128) ? AX[tt] : 0;
    const double dvm = 1.0 / sqrt((double)(mydeg + 1));    // key-path dinv (t<128)

    // deterministic CSR emit (s ascending, multiplicity preserved)
    if (tt < 128) {
        unsigned pos = RP[tt];
        for (int w = 0; w < 32; ++w) {
            unsigned u = adjM[(tt << 5) + w];
            while (u) {
                int b2 = (u & 0xFFu) ? 0 : (u & 0xFF00u) ? 1 : (u & 0xFF0000u) ? 2 : 3;
                int m = (int)((u >> (b2 << 3)) & 255u);
                unsigned char sv = (unsigned char)((w << 2) + b2);
                for (int q = 0; q < m; ++q) { if (pos < ECAP) CS[pos] = sv; ++pos; }
                u &= ~(0xFFu << (b2 << 3));
            }
        }
    }
    // degree-descending rank sort -> perm (phase-2 assignment only)
    if (tt < 128) {
        int dmine = AX[tt];
        int rk = 0;
        for (int j = 0; j < 128; ++j) {
            int dj = AX[j];
            if (dj > dmine || (dj == dmine && j < tt)) ++rk;
        }
        perm[half][rk] = (unsigned char)tt;
    }
    __syncthreads();                 // adjM reads done; Xd free; perm/CSR published

    // natural rows (phase 1) and balanced perm rows (phase 2)
    const int r0 = tt >> 3;
    const int r1 = r0 + 64;
    const double dv0 = 1.0 / sqrt((double)(AX[r0] + 1));
    const double dv1 = 1.0 / sqrt((double)(AX[r1] + 1));
    const int q    = tt >> 3;
    const int rowA = perm[half][q];
    const int rowB = perm[half][127 - q];
    const double dvA = 1.0 / sqrt((double)(AX[rowA] + 1));
    const double dvB = 1.0 / sqrt((double)(AX[rowB] + 1));
    const int cS = (c0 & 48) >> 3;           // constant part of xd swizzle for this thread

    // X0 = z_table[z] (f32 hi; lo plane unused in layer 0)
    for (int idx = tt; idx < 8192; idx += 512) {
        int n = idx >> 6, c = idx & 63;
        int zv = z[(g << 7) + n];
        zv = (zv < 0) ? 0 : ((zv >= MAXZ) ? MAXZ - 1 : zv);
        XH[xh_idx(n, c)] = zt[zv * 64 + c];
    }
    __syncthreads();

    // ---- three GCN layers ----
    for (int layer = 0; layer < 3; ++layer) {
        const float* Wg = (layer == 0) ? W0 : (layer == 1) ? W1 : W2;
        const float* bg = (layer == 0) ? b0 : (layer == 1) ? b1 : b2;
        const bool haslo = (layer != 0);

        // phase 1 (natural rows): acc = (X @ W)[r0,r1][c0..c0+7]
        double accd0[8], accd1[8]; float accf0[8], accf1[8];
#pragma unroll
        for (int j = 0; j < 8; ++j) { accd0[j] = 0.0; accd1[j] = 0.0; accf0[j] = 0.f; accf1[j] = 0.f; }

        for (int k = 0; k < 64; k += 4) {
            float4 a0 = *(const float4*)&XH[xh_idx(r0, k)];
            float4 a1 = *(const float4*)&XH[xh_idx(r1, k)];
            float x0[4] = {a0.x, a0.y, a0.z, a0.w};
            float x1[4] = {a1.x, a1.y, a1.z, a1.w};
            float l0[4], l1[4];
            if (haslo) {
                float4 u0 = *(const float4*)&XL[xh_idx(r0, k)];
                float4 u1 = *(const float4*)&XL[xh_idx(r1, k)];
                l0[0] = u0.x; l0[1] = u0.y; l0[2] = u0.z; l0[3] = u0.w;
                l1[0] = u1.x; l1[1] = u1.y; l1[2] = u1.z; l1[3] = u1.w;
            }
#pragma unroll
            for (int kk = 0; kk < 4; ++kk) {
                const float* wr = Wg + ((k + kk) << 6) + c0;
                float4 wa = *(const float4*)wr;
                float4 wb = *(const float4*)(wr + 4);
                float wf[8] = {wa.x, wa.y, wa.z, wa.w, wb.x, wb.y, wb.z, wb.w};
                double xd0 = (double)x0[kk], xd1 = (double)x1[kk];
#pragma unroll
                for (int j = 0; j < 8; ++j) {
                    double wd = (double)wf[j];
                    accd0[j] = fma(xd0, wd, accd0[j]);
                    accd1[j] = fma(xd1, wd, accd1[j]);
                }
                if (haslo) {
#pragma unroll
                    for (int j = 0; j < 8; ++j) {
                        accf0[j] = fmaf(l0[kk], wf[j], accf0[j]);
                        accf1[j] = fmaf(l1[kk], wf[j], accf1[j]);
                    }
                }
            }
        }
        __syncthreads();                                   // all X reads complete

        // H = dinv * acc; store native f64 (overwrites X planes)
        {
            int bi = xd_idx(r0, c0);
            *(double2*)&HD[bi]     = make_double2(dv0 * (accd0[0] + (double)accf0[0]),
                                                  dv0 * (accd0[1] + (double)accf0[1]));
            *(double2*)&HD[bi ^ 2] = make_double2(dv0 * (accd0[2] + (double)accf0[2]),
                                                  dv0 * (accd0[3] + (double)accf0[3]));
            *(double2*)&HD[bi ^ 4] = make_double2(dv0 * (accd0[4] + (double)accf0[4]),
                                                  dv0 * (accd0[5] + (double)accf0[5]));
            *(double2*)&HD[bi ^ 6] = make_double2(dv0 * (accd0[6] + (double)accf0[6]),
                                                  dv0 * (accd0[7] + (double)accf0[7]));
            int bj = xd_idx(r1, c0);
            *(double2*)&HD[bj]     = make_double2(dv1 * (accd1[0] + (double)accf1[0]),
                                                  dv1 * (accd1[1] + (double)accf1[1]));
            *(double2*)&HD[bj ^ 2] = make_double2(dv1 * (accd1[2] + (double)accf1[2]),
                                                  dv1 * (accd1[3] + (double)accf1[3]));
            *(double2*)&HD[bj ^ 4] = make_double2(dv1 * (accd1[4] + (double)accf1[4]),
                                                  dv1 * (accd1[5] + (double)accf1[5]));
            *(double2*)&HD[bj ^ 6] = make_double2(dv1 * (accd1[6] + (double)accf1[6]),
                                                  dv1 * (accd1[7] + (double)accf1[7]));
        }
        __syncthreads();                                   // H fully written

        // phase 2 (perm rows, reload-init): agg = H[own] + sum_neighbors H[s]
        float vfs[2][8], rss[2][8];
#pragma unroll
        for (int rw = 0; rw < 2; ++rw) {
            int rr = rw ? rowB : rowA;
            double dv = rw ? dvB : dvA;
            int bio = xd_idx(rr, c0);
            double2 p0 = *(const double2*)&HD[bio];
            double2 p1 = *(const double2*)&HD[bio ^ 2];
            double2 p2 = *(const double2*)&HD[bio ^ 4];
            double2 p3 = *(const double2*)&HD[bio ^ 6];
            double ad[8];
            ad[0] = p0.x; ad[1] = p0.y; ad[2] = p1.x; ad[3] = p1.y;
            ad[4] = p2.x; ad[5] = p2.y; ad[6] = p3.x; ad[7] = p3.y;

            for (unsigned e = RP[rr]; e < RP[rr + 1]; ++e) {
                int s = CS[e];
                int bs = (s << 6) | ((c0 ^ cS) ^ ((s & 7) << 1));
                double2 q0 = *(const double2*)&HD[bs];
                double2 q1 = *(const double2*)&HD[bs ^ 2];
                double2 q2 = *(const double2*)&HD[bs ^ 4];
                double2 q3 = *(const double2*)&HD[bs ^ 6];
                ad[0] += q0.x; ad[1] += q0.y;
                ad[2] += q1.x; ad[3] += q1.y;
                ad[4] += q2.x; ad[5] += q2.y;
                ad[6] += q3.x; ad[7] += q3.y;
            }
            // tanh pre-barrier; stores deferred
#pragma unroll
            for (int j = 0; j < 8; ++j) {
                double v = tanh_fast(dv * ad[j] + (double)bg[c0 + j]);
                float vfl = (float)v;
                vfs[rw][j] = vfl;
                rss[rw][j] = (float)(v - (double)vfl);
            }
        }
        __syncthreads();                                   // all H reads complete

        // store X = tanh outputs (f32 hi + f32 lo planes); dump layer-0/1 for head
#pragma unroll
        for (int rw = 0; rw < 2; ++rw) {
            int rr = rw ? rowB : rowA;
            int bi = xh_idx(rr, c0);
            *(float4*)&XH[bi]     = make_float4(vfs[rw][0], vfs[rw][1], vfs[rw][2], vfs[rw][3]);
            *(float4*)&XH[bi + 4] = make_float4(vfs[rw][4], vfs[rw][5], vfs[rw][6], vfs[rw][7]);
            *(float4*)&XL[bi]     = make_float4(rss[rw][0], rss[rw][1], rss[rw][2], rss[rw][3]);
            *(float4*)&XL[bi + 4] = make_float4(rss[rw][4], rss[rw][5], rss[rw][6], rss[rw][7]);

            if (layer < 2) {
                float* xd = xdump + (((size_t)g * 2 + layer) << 13) + (rr << 6) + c0;
                *(float4*)xd       = make_float4(vfs[rw][0], vfs[rw][1], vfs[rw][2], vfs[rw][3]);
                *(float4*)(xd + 4) = make_float4(vfs[rw][4], vfs[rw][5], vfs[rw][6], vfs[rw][7]);
            }
        }
        __syncthreads();
    }

    // ---- layer 4 (64->1): key path; overlays on XL plane ----
    double* h4sD  = (double*)XL;
    double* keydD = ((double*)XL) + 128;

    double sdreg = 0.0;
    if (tt < 128) {
        double sd = 0.0; float sf = 0.f;
        for (int k = 0; k < 64; k += 4) {
            float4 a = *(const float4*)&XH[xh_idx(tt, k)];
            float4 u = *(const float4*)&XL[xh_idx(tt, k)];
            float4 w = *(const float4*)&W3[k];
            sd = fma((double)a.x, (double)w.x, sd);
            sd = fma((double)a.y, (double)w.y, sd);
            sd = fma((double)a.z, (double)w.z, sd);
            sd = fma((double)a.w, (double)w.w, sd);
            sf = fmaf(u.x, w.x, sf);
            sf = fmaf(u.y, w.y, sf);
            sf = fmaf(u.z, w.z, sf);
            sf = fmaf(u.w, w.w, sf);
        }
        sdreg = sd + (double)sf;
    }
    __syncthreads();                          // XL reads done before overlay write
    if (tt < 128) h4sD[tt] = dvm * sdreg;
    __syncthreads();
    double keyreg = 0.0;
    if (tt < 128) {
        double a = h4sD[tt];
        for (unsigned e = RP[tt]; e < RP[tt + 1]; ++e) a += h4sD[CS[e]];
        keyreg = tanh_fast(dvm * a + (double)b3[0]);
        keydD[tt] = keyreg;
    }
    __syncthreads();

    // stable descending rank == stable argsort(-key)
    if (tt < 128) {
        int rk = 0;
        for (int j = 0; j < 128; ++j) {
            double kj = keydD[j];
            if (kj > keyreg || (kj == keyreg && j < tt)) ++rk;
        }
        if (rk < 30) { inv[half][rk] = tt; kd30f[half][rk] = (float)keyreg; }
    }
    __syncthreads();                         // publish inv/kd30f; keyd reads done

    // ---- head (per half, in XL plane past the key overlay) ----
    float* XloF = XL;
    float* h1v = XloF + 2560;   // 480
    float* ppv = XloF + 3040;   // 240
    float* flv = XloF + 3280;   // 352
    float* hmv = XloF + 3632;   // 128

    if (tt < 480) {
        int c = tt & 15, k = tt >> 4;
        int node = inv[half][k];
        // conv1 partials, bit-identical chain+tree (L0 j0..7, L1 j0..7, L2 j0..7; xor tree)
        const float* wrow = c1w + c * 193;
        const float* xg0 = xdump + ((size_t)g * 2) * 8192 + node * 64;
        const float* xg1 = xg0 + 8192;
        float s8[8];
#pragma unroll
        for (int cg = 0; cg < 8; ++cg) {
            float acc = 0.f;
            float4 xa = *(const float4*)&xg0[cg * 8];
            float4 xb = *(const float4*)&xg0[cg * 8 + 4];
            const float* w0p = wrow + cg * 8;
            acc = fmaf(xa.x, w0p[0], acc); acc = fmaf(xa.y, w0p[1], acc);
            acc = fmaf(xa.z, w0p[2], acc); acc = fmaf(xa.w, w0p[3], acc);
            acc = fmaf(xb.x, w0p[4], acc); acc = fmaf(xb.y, w0p[5], acc);
            acc = fmaf(xb.z, w0p[6], acc); acc = fmaf(xb.w, w0p[7], acc);
            float4 ya = *(const float4*)&xg1[cg * 8];
            float4 yb = *(const float4*)&xg1[cg * 8 + 4];
            const float* w1p = wrow + 64 + cg * 8;
            acc = fmaf(ya.x, w1p[0], acc); acc = fmaf(ya.y, w1p[1], acc);
            acc = fmaf(ya.z, w1p[2], acc); acc = fmaf(ya.w, w1p[3], acc);
            acc = fmaf(yb.x, w1p[4], acc); acc = fmaf(yb.y, w1p[5], acc);
            acc = fmaf(yb.z, w1p[6], acc); acc = fmaf(yb.w, w1p[7], acc);
            const float* w2p = wrow + 128 + cg * 8;
#pragma unroll
            for (int j = 0; j < 8; ++j)
                acc = fmaf(XH[xh_idx(node, cg * 8 + j)], w2p[j], acc);
            s8[cg] = acc;
        }
        float A0 = s8[0] + s8[1], A1 = s8[2] + s8[3];
        float A2 = s8[4] + s8[5], A3 = s8[6] + s8[7];
        float G = (A0 + A1) + (A2 + A3);
        float s = G + c1w[c * 193 + 192] * kd30f[half][k] + c1b[c];
        h1v[c * 30 + k] = s > 0.f ? s : 0.f;
    }
    __syncthreads();
    if (tt < 240) {
        int c = tt & 15, i = tt >> 4;
        float a = h1v[c * 30 + 2 * i], b = h1v[c * 30 + 2 * i + 1];
        ppv[c * 15 + i] = a > b ? a : b;
    }
    __syncthreads();
    if (tt < 352) {
        int o = tt / 11, j = tt % 11;
        float s = c2b[o];
        for (int i = 0; i < 16; ++i)
#pragma unroll
            for (int u = 0; u < 5; ++u)
                s = fmaf(ppv[i * 15 + j + u], c2w[o * 80 + i * 5 + u], s);
        flv[tt] = s > 0.f ? s : 0.f;
    }
    __syncthreads();
    if (tt < 128) {
        float s = l1b[tt];
        for (int i = 0; i < 352; ++i) s = fmaf(flv[i], l1w[i * 128 + tt], s);
        hmv[tt] = s > 0.f ? s : 0.f;
    }
    __syncthreads();
    if (tt < 64) {
        float v = fmaf(hmv[tt], l2w[tt], hmv[tt + 64] * l2w[tt + 64]);
#pragma unroll
        for (int o = 32; o > 0; o >>= 1) v += __shfl_down(v, o, 64);
        if (tt == 0) out[g] = v + l2b[0];
    }
}

// ============ fallback kernel: r2 fused variant (512 threads, 1 graph) ============
__global__ __launch_bounds__(512, 2) void gnn_kernel(
    const int* __restrict__ z,
    const unsigned* __restrict__ adjG,
    const float* __restrict__ zt,
    const float* __restrict__ W0, const float* __restrict__ b0,
    const float* __restrict__ W1, const float* __restrict__ b1,
    const float* __restrict__ W2, const float* __restrict__ b2,
    const float* __restrict__ W3, const float* __restrict__ b3,
    const float* __restrict__ c1w, const float* __restrict__ c1b,
    const float* __restrict__ c2w, const float* __restrict__ c2b,
    const float* __restrict__ l1w, const float* __restrict__ l1b,
    const float* __restrict__ l2w, const float* __restrict__ l2b,
    float* __restrict__ out)
{
    __shared__ __align__(16) float    Xhi[8192];
    __shared__ __align__(16) unsigned Xlo[4096];
    __shared__ unsigned char  csr[ECAP];
    __shared__ unsigned short rp16[132];
    __shared__ int            aux[128];
    __shared__ int            inv[30];
    __shared__ float          kd30f[30];
    __shared__ int            w0tot;

    const int g  = blockIdx.x;
    const int t  = threadIdx.x;
    const int r0 = t >> 3;
    const int r1 = r0 + 64;
    const int c0 = (t & 7) << 3;

    unsigned* adjM = (unsigned*)Xhi;

    {
        const uint4* src = (const uint4*)(adjG + ((size_t)g << 12));
        uint4* dst = (uint4*)adjM;
        for (int i = t; i < 1024; i += 512) dst[i] = src[i];
    }
    if (t < 30) { inv[t] = t; kd30f[t] = 0.f; }
    __syncthreads();

    int degv = 0;
    if (t < 128) {
        for (int w = 0; w < 32; ++w) {
            unsigned u = adjM[(t << 5) + w];
            degv += (int)((u & 255u) + ((u >> 8) & 255u) + ((u >> 16) & 255u) + (u >> 24));
        }
        aux[t] = degv;
    }
    if (t < 128) {
        int v = degv;
        for (int o = 1; o < 64; o <<= 1) {
            int u = __shfl_up(v, o, 64);
            if ((t & 63) >= o) v += u;
        }
        if (t == 63) w0tot = v;
        rp16[t + 1] = (unsigned short)v;
    }
    __syncthreads();
    if (t >= 64 && t < 128) rp16[t + 1] = (unsigned short)(rp16[t + 1] + w0tot);
    if (t == 0) rp16[0] = 0;
    __syncthreads();

    const int mydeg = (t < 128) ? aux[t] : 0;
    const double dv0 = 1.0 / sqrt((double)(aux[r0] + 1));
    const double dv1 = 1.0 / sqrt((double)(aux[r1] + 1));
    const double dvm = 1.0 / sqrt((double)(mydeg + 1));

    if (t < 128) {
        unsigned pos = rp16[t];
        for (int w = 0; w < 32; ++w) {
            unsigned u = adjM[(t << 5) + w];
            while (u) {
                int b2 = (u & 0xFFu) ? 0 : (u & 0xFF00u) ? 1 : (u & 0xFF0000u) ? 2 : 3;
                int m = (int)((u >> (b2 << 3)) & 255u);
                unsigned char sv = (unsigned char)((w << 2) + b2);
                for (int q = 0; q < m; ++q) { if (pos < ECAP) csr[pos] = sv; ++pos; }
                u &= ~(0xFFu << (b2 << 3));
            }
        }
    }
    __syncthreads();

    for (int idx = t; idx < 8192; idx += 512) {
        int n = idx >> 6, c = idx & 63;
        int zv = z[(g << 7) + n];
        zv = (zv < 0) ? 0 : ((zv >= MAXZ) ? MAXZ - 1 : zv);
        Xhi[xh_idx(n, c)] = zt[zv * 64 + c];
    }
    __syncthreads();

    float g1p[2][16];
#pragma unroll
    for (int rw = 0; rw < 2; ++rw)
#pragma unroll
        for (int c = 0; c < 16; ++c) g1p[rw][c] = 0.f;

    for (int layer = 0; layer < 3; ++layer) {
        const float* Wg = (layer == 0) ? W0 : (layer == 1) ? W1 : W2;
        const float* bg = (layer == 0) ? b0 : (layer == 1) ? b1 : b2;
        const bool haslo = (layer != 0);

        double accd0[8], accd1[8]; float accf0[8], accf1[8];
#pragma unroll
        for (int j = 0; j < 8; ++j) { accd0[j] = 0.0; accd1[j] = 0.0; accf0[j] = 0.f; accf1[j] = 0.f; }

        for (int k = 0; k < 64; k += 4) {
            float4 a0 = *(const float4*)&Xhi[xh_idx(r0, k)];
            float4 a1 = *(const float4*)&Xhi[xh_idx(r1, k)];
            float x0[4] = {a0.x, a0.y, a0.z, a0.w};
            float x1[4] = {a1.x, a1.y, a1.z, a1.w};
            float l0[4], l1[4];
            if (haslo) {
                uint2 u0 = *(const uint2*)&Xlo[xl_idx(r0, k >> 1)];
                uint2 u1 = *(const uint2*)&Xlo[xl_idx(r1, k >> 1)];
                l0[0] = bfu_lo(u0.x); l0[1] = bfu_hi(u0.x); l0[2] = bfu_lo(u0.y); l0[3] = bfu_hi(u0.y);
                l1[0] = bfu_lo(u1.x); l1[1] = bfu_hi(u1.x); l1[2] = bfu_lo(u1.y); l1[3] = bfu_hi(u1.y);
            }
#pragma unroll
            for (int kk = 0; kk < 4; ++kk) {
                const float* wr = Wg + ((k + kk) << 6) + c0;
                float4 wa = *(const float4*)wr;
                float4 wb = *(const float4*)(wr + 4);
                float wf[8] = {wa.x, wa.y, wa.z, wa.w, wb.x, wb.y, wb.z, wb.w};
                double xd0 = (double)x0[kk], xd1 = (double)x1[kk];
#pragma unroll
                for (int j = 0; j < 8; ++j) {
                    double wd = (double)wf[j];
                    accd0[j] = fma(xd0, wd, accd0[j]);
                    accd1[j] = fma(xd1, wd, accd1[j]);
                }
                if (haslo) {
#pragma unroll
                    for (int j = 0; j < 8; ++j) {
                        accf0[j] = fmaf(l0[kk], wf[j], accf0[j]);
                        accf1[j] = fmaf(l1[kk], wf[j], accf1[j]);
                    }
                }
            }
        }
        __syncthreads();

        float hfv[2][8], rsv[2][8];
#pragma unroll
        for (int rw = 0; rw < 2; ++rw) {
            int rr = rw ? r1 : r0;
            double dv = rw ? dv1 : dv0;
#pragma unroll
            for (int j = 0; j < 8; ++j) {
                double acc = rw ? (accd1[j] + (double)accf1[j]) : (accd0[j] + (double)accf0[j]);
                double h = dv * acc;
                float hf = (float)h;
                hfv[rw][j] = hf;
                rsv[rw][j] = (float)(h - (double)hf);
            }
            int bi = xh_idx(rr, c0);
            *(float4*)&Xhi[bi]     = make_float4(hfv[rw][0], hfv[rw][1], hfv[rw][2], hfv[rw][3]);
            *(float4*)&Xhi[bi + 4] = make_float4(hfv[rw][4], hfv[rw][5], hfv[rw][6], hfv[rw][7]);
            uint4 lv;
            lv.x = packlo(rsv[rw][0], rsv[rw][1]);
            lv.y = packlo(rsv[rw][2], rsv[rw][3]);
            lv.z = packlo(rsv[rw][4], rsv[rw][5]);
            lv.w = packlo(rsv[rw][6], rsv[rw][7]);
            *(uint4*)&Xlo[xl_idx(rr, c0 >> 1)] = lv;
        }
        __syncthreads();

        double ad[2][8]; float af[2][8];
#pragma unroll
        for (int rw = 0; rw < 2; ++rw)
#pragma unroll
            for (int j = 0; j < 8; ++j) { ad[rw][j] = (double)hfv[rw][j]; af[rw][j] = rsv[rw][j]; }

#pragma unroll
        for (int rw = 0; rw < 2; ++rw) {
            int rr = rw ? r1 : r0;
            for (unsigned e = rp16[rr]; e < rp16[rr + 1]; ++e) {
                int s = csr[e];
                int bi = (s << 6) | (c0 ^ ((s & 7) << 3));
                float4 a = *(const float4*)&Xhi[bi];
                float4 b = *(const float4*)&Xhi[bi + 4];
                uint4 lu = *(const uint4*)&Xlo[(s << 5) | ((c0 >> 1) ^ ((s & 7) << 2))];
                ad[rw][0] += (double)a.x; ad[rw][1] += (double)a.y;
                ad[rw][2] += (double)a.z; ad[rw][3] += (double)a.w;
                ad[rw][4] += (double)b.x; ad[rw][5] += (double)b.y;
                ad[rw][6] += (double)b.z; ad[rw][7] += (double)b.w;
                af[rw][0] += bfu_lo(lu.x); af[rw][1] += bfu_hi(lu.x);
                af[rw][2] += bfu_lo(lu.y); af[rw][3] += bfu_hi(lu.y);
                af[rw][4] += bfu_lo(lu.z); af[rw][5] += bfu_hi(lu.z);
                af[rw][6] += bfu_lo(lu.w); af[rw][7] += bfu_hi(lu.w);
            }
        }
        __syncthreads();

#pragma unroll
        for (int rw = 0; rw < 2; ++rw) {
            int rr = rw ? r1 : r0;
            double dv = rw ? dv1 : dv0;
            float vf[8], rs[8];
#pragma unroll
            for (int j = 0; j < 8; ++j) {
                double v = tanh_fast(dv * (ad[rw][j] + (double)af[rw][j]) + (double)bg[c0 + j]);
                float vfl = (float)v;
                vf[j] = vfl;
                rs[j] = (float)(v - (double)vfl);
            }
            int bi = xh_idx(rr, c0);
            *(float4*)&Xhi[bi]     = make_float4(vf[0], vf[1], vf[2], vf[3]);
            *(float4*)&Xhi[bi + 4] = make_float4(vf[4], vf[5], vf[6], vf[7]);
            uint4 lv;
            lv.x = packlo(rs[0], rs[1]);
            lv.y = packlo(rs[2], rs[3]);
            lv.z = packlo(rs[4], rs[5]);
            lv.w = packlo(rs[6], rs[7]);
            *(uint4*)&Xlo[xl_idx(rr, c0 >> 1)] = lv;

            const float* w1base = c1w + layer * 64 + c0;
            for (int c = 0; c < 16; ++c) {
                const float* wr = w1base + c * 193;
#pragma unroll
                for (int j = 0; j < 8; ++j)
                    g1p[rw][c] = fmaf(vf[j], wr[j], g1p[rw][c]);
            }
        }
        __syncthreads();
    }

    double* h4sD  = (double*)Xlo;
    double* keydD = ((double*)Xlo) + 128;

    double sdreg = 0.0;
    if (t < 128) {
        double sd = 0.0; float sf = 0.f;
        for (int k = 0; k < 64; k += 4) {
            float4 a = *(const float4*)&Xhi[xh_idx(t, k)];
            uint2  u = *(const uint2*)&Xlo[xl_idx(t, k >> 1)];
            float4 w = *(const float4*)&W3[k];
            sd = fma((double)a.x, (double)w.x, sd);
            sd = fma((double)a.y, (double)w.y, sd);
            sd = fma((double)a.z, (double)w.z, sd);
            sd = fma((double)a.w, (double)w.w, sd);
            sf = fmaf(bfu_lo(u.x), w.x, sf);
            sf = fmaf(bfu_hi(u.x), w.y, sf);
            sf = fmaf(bfu_lo(u.y), w.z, sf);
            sf = fmaf(bfu_hi(u.y), w.w, sf);
        }
        sdreg = sd + (double)sf;
    }
    __syncthreads();
    if (t < 128) h4sD[t] = dvm * sdreg;
    __syncthreads();
    double keyreg = 0.0;
    if (t < 128) {
        double a = h4sD[t];
        for (unsigned e = rp16[t]; e < rp16[t + 1]; ++e) a += h4sD[csr[e]];
        keyreg = tanh_fast(dvm * a + (double)b3[0]);
        keydD[t] = keyreg;
    }
    __syncthreads();

    if (t < 128) {
        int rk = 0;
        for (int j = 0; j < 128; ++j) {
            double kj = keydD[j];
            if (kj > keyreg || (kj == keyreg && j < t)) ++rk;
        }
        if (rk < 30) { inv[rk] = t; kd30f[rk] = (float)keyreg; }
    }

#pragma unroll
    for (int m = 1; m <= 4; m <<= 1) {
#pragma unroll
        for (int rw = 0; rw < 2; ++rw)
#pragma unroll
            for (int c = 0; c < 16; ++c)
                g1p[rw][c] += __shfl_xor(g1p[rw][c], m, 64);
    }
    __syncthreads();
    float* XloF = (float*)Xlo;
    float* G1   = XloF + 512;
    if ((t & 7) == 0) {
#pragma unroll
        for (int c = 0; c < 16; c += 4) {
            *(float4*)&G1[r0 * 16 + c] = make_float4(g1p[0][c], g1p[0][c + 1], g1p[0][c + 2], g1p[0][c + 3]);
            *(float4*)&G1[r1 * 16 + c] = make_float4(g1p[1][c], g1p[1][c + 1], g1p[1][c + 2], g1p[1][c + 3]);
        }
    }
    __syncthreads();

    float* h1v = XloF + 2560;
    float* ppv = XloF + 3040;
    float* flv = XloF + 3280;
    float* hmv = XloF + 3632;

    if (t < 480) {
        int c = t & 15, k = t >> 4;
        int node = inv[k];
        float s = G1[node * 16 + c] + c1w[c * 193 + 192] * kd30f[k] + c1b[c];
        h1v[c * 30 + k] = s > 0.f ? s : 0.f;
    }
    __syncthreads();
    if (t < 240) {
        int c = t & 15, i = t >> 4;
        float a = h1v[c * 30 + 2 * i], b = h1v[c * 30 + 2 * i + 1];
        ppv[c * 15 + i] = a > b ? a : b;
    }
    __syncthreads();
    if (t < 352) {
        int o = t / 11, j = t % 11;
        float s = c2b[o];
        for (int i = 0; i < 16; ++i)
#pragma unroll
            for (int u = 0; u < 5; ++u)
                s = fmaf(ppv[i * 15 + j + u], c2w[o * 80 + i * 5 + u], s);
        flv[t] = s > 0.f ? s : 0.f;
    }
    __syncthreads();
    if (t < 128) {
        float s = l1b[t];
        for (int i = 0; i < 352; ++i) s = fmaf(flv[i], l1w[i * 128 + t], s);
        hmv[t] = s > 0.f ? s : 0.f;
    }
    __syncthreads();
    if (t < 64) {
        float v = fmaf(hmv[t], l2w[t], hmv[t + 64] * l2w[t + 64]);
#pragma unroll
        for (int o = 32; o > 0; o >>= 1) v += __shfl_down(v, o, 64);
        if (t == 0) out[g] = v + l2b[0];
    }
}

// ---------------- launch ----------------

extern "C" void kernel_launch(void* const* d_in, const int* in_sizes, int n_in,
                              void* d_out, int out_size, void* d_ws, size_t ws_size,
                              hipStream_t stream) {
    const int*   z   = (const int*)d_in[0];
    const int*   ei  = (const int*)d_in[1];
    const float* zt  = (const float*)d_in[3];
    const float* W0  = (const float*)d_in[4];
    const float* b0  = (const float*)d_in[5];
    const float* W1  = (const float*)d_in[6];
    const float* b1  = (const float*)d_in[7];
    const float* W2  = (const float*)d_in[8];
    const float* b2  = (const float*)d_in[9];
    const float* W3  = (const float*)d_in[10];
    const float* b3  = (const float*)d_in[11];
    const float* c1w = (const float*)d_in[12];
    const float* c1b = (const float*)d_in[13];
    const float* c2w = (const float*)d_in[14];
    const float* c2b = (const float*)d_in[15];
    const float* l1w = (const float*)d_in[16];
    const float* l1b = (const float*)d_in[17];
    const float* l2w = (const float*)d_in[18];
    const float* l2b = (const float*)d_in[19];
    float* out = (float*)d_out;

    const size_t ADJ_B = (size_t)NGRAPH * 4096 * 4;            // 16.78 MB
    const size_t XD_B  = (size_t)NGRAPH * 2 * 8192 * 4;        // 67.11 MB (x dumps, layers 0-1)
    if (ws_size < ADJ_B) {
        markWS_kernel<<<4, 256, 0, stream>>>(out);
        return;
    }

    unsigned* adjG = (unsigned*)d_ws;

    hipMemsetAsync(adjG, 0, ADJ_B, stream);
    adjscatter_kernel<<<(E_EDGES + 255) / 256, 256, 0, stream>>>(ei, adjG);

    if (ws_size >= ADJ_B + XD_B) {
        float* xdump = (float*)((char*)d_ws + ADJ_B);
        gnn2_kernel<<<NGRAPH / 2, 1024, 0, stream>>>(z, adjG, zt,
                                                     W0, b0, W1, b1, W2, b2, W3, b3,
                                                     c1w, c1b, c2w, c2b, l1w, l1b, l2w, l2b,
                                                     xdump, out);
    } else {
        gnn_kernel<<<NGRAPH, 512, 0, stream>>>(z, adjG, zt,
                                               W0, b0, W1, b1, W2, b2, W3, b3,
                                               c1w, c1b, c2w, c2b, l1w, l1b, l2w, l2b,
                                               out);
    }
}

// Round 13
// 561.371 us; speedup vs baseline: 1.3783x; 1.0162x over previous
//
#include <hip/hip_runtime.h>

#define NGRAPH  1024
#define E_EDGES 2097152
#define ECAP    2944
#define MAXZ    1000

__device__ __forceinline__ float bfu_lo(unsigned u) { return __uint_as_float(u << 16); }
__device__ __forceinline__ float bfu_hi(unsigned u) { return __uint_as_float(u & 0xFFFF0000u); }
__device__ __forceinline__ unsigned packlo(float f0, float f1) {
    return (__float_as_uint(f0) >> 16) | (__float_as_uint(f1) & 0xFFFF0000u);
}
// XOR-swizzled indices: f32 X tile [128][64] (hi or lo plane)
__device__ __forceinline__ int xh_idx(int r, int k)  { return (r << 6) | (k  ^ ((r & 7) << 3)); }
__device__ __forceinline__ int xl_idx(int r, int k2) { return (r << 5) | (k2 ^ ((r & 7) << 2)); }
// XOR swizzle for f64 H tile [128][64] (r3/r9-validated)
__device__ __forceinline__ int xd_idx(int r, int c) {
    return (r << 6) | (c ^ ((r & 7) << 1) ^ ((c & 48) >> 3));
}

// branchless double tanh via e^{2p}; abs error ~2e-13
__device__ __forceinline__ double tanh_fast(double p) {
    double q = 2.0 * p;
    q = fmin(40.0, fmax(-40.0, q));
    double nf = rint(q * 1.4426950408889634074);
    double r  = fma(nf, -6.93147180369123816490e-01, q);
    r = fma(nf, -1.90821492927058770002e-10, r);
    double er =     2.755731922398589e-07;
    er = fma(er, r, 2.755731922398589e-06);
    er = fma(er, r, 2.4801587301587302e-05);
    er = fma(er, r, 1.984126984126984e-04);
    er = fma(er, r, 1.3888888888888889e-03);
    er = fma(er, r, 8.333333333333333e-03);
    er = fma(er, r, 4.1666666666666664e-02);
    er = fma(er, r, 1.6666666666666666e-01);
    er = fma(er, r, 0.5);
    er = fma(er, r, 1.0);
    er = fma(er, r, 1.0);                        // e^r
    double E = er * __longlong_as_double((long long)(1023 + (int)nf) << 52);
    return 1.0 - 2.0 / (E + 1.0);
}

__global__ void markWS_kernel(float* out) {
    int i = blockIdx.x * 256 + threadIdx.x;
    if (i < NGRAPH) out[i] = 2.0f;
}

// packed adjacency counts: adjG[g][d][s/4] byte-lane (s&3); commutative atomics
__global__ void adjscatter_kernel(const int* __restrict__ ei,
                                  unsigned* __restrict__ adjG) {
    int e = blockIdx.x * 256 + threadIdx.x;
    if (e >= E_EDGES) return;
    int s = ei[e];
    int d = ei[E_EDGES + e];
    int g = s >> 7;
    int sl = s & 127, dl = d & 127;
    atomicAdd(&adjG[((size_t)g << 12) + (dl << 5) + (sl >> 2)], 1u << ((sl & 3) << 3));
}

// ============ primary: 512 threads = ONE graph/block (r12 math, decoupled barriers) ============
// r12 yoked two independent graphs to one __syncthreads ladder (16 waves drain at
// every barrier). This splits them: 1 graph / 512-thread block, launch_bounds(512,4)
// -> VGPR capped 64 (empirical: r1), LDS ~69.6KB -> 2 blocks/CU = same 16 waves/CU,
// but co-resident graphs now slip phases freely (phase-1 VALU overlaps phase-2
// latency across blocks). Per-row math identical to r12 -> same bits.
__global__ __launch_bounds__(512, 4) void gnn1_kernel(
    const int* __restrict__ z,
    const unsigned* __restrict__ adjG,
    const float* __restrict__ zt,
    const float* __restrict__ W0, const float* __restrict__ b0,
    const float* __restrict__ W1, const float* __restrict__ b1,
    const float* __restrict__ W2, const float* __restrict__ b2,
    const float* __restrict__ W3, const float* __restrict__ b3,
    const float* __restrict__ c1w, const float* __restrict__ c1b,
    const float* __restrict__ c2w, const float* __restrict__ c2b,
    const float* __restrict__ l1w, const float* __restrict__ l1b,
    const float* __restrict__ l2w, const float* __restrict__ l2b,
    float* __restrict__ xdump,
    float* __restrict__ out)
{
    __shared__ __align__(16) double   Xd[8192];       // 65536 B: X = f32 hi(32K)+lo(32K); H = f64(64K)
    __shared__ unsigned char  csr[ECAP];              //  2944 B
    __shared__ unsigned short rp16[132];
    __shared__ int            aux[128];               // degree
    __shared__ unsigned char  perm[128];              // degree-descending row permutation
    __shared__ int            inv[30];
    __shared__ float          kd30f[30];
    __shared__ int            w0tot;
    // ~69.6 KB/block -> 2 blocks/CU (16 waves) with independent barriers

    const int tt = threadIdx.x;
    const int g  = blockIdx.x;
    const int c0 = (tt & 7) << 3;

    double* HD = Xd;
    float*  XH = (float*)Xd;            // 8192 floats (hi plane)
    float*  XL = XH + 8192;             // 8192 floats (lo plane)

    unsigned* adjM = (unsigned*)XH;     // [128][32] packed byte counts (16 KB)

    // load this graph's adjacency-count slab (coalesced)
    {
        const uint4* src = (const uint4*)(adjG + ((size_t)g << 12));
        uint4* dst = (uint4*)adjM;
        for (int i = tt; i < 1024; i += 512) dst[i] = src[i];
    }
    if (tt < 30) { inv[tt] = tt; kd30f[tt] = 0.f; }
    __syncthreads();

    // per-node in-degree
    int degv = 0;
    if (tt < 128) {
        for (int w = 0; w < 32; ++w) {
            unsigned u = adjM[(tt << 5) + w];
            degv += (int)((u & 255u) + ((u >> 8) & 255u) + ((u >> 16) & 255u) + (u >> 24));
        }
        aux[tt] = degv;
    }
    // exclusive scan (two waves)
    if (tt < 128) {
        int v = degv;
        for (int o = 1; o < 64; o <<= 1) {
            int u = __shfl_up(v, o, 64);
            if ((tt & 63) >= o) v += u;
        }
        if (tt == 63) w0tot = v;
        rp16[tt + 1] = (unsigned short)v;
    }
    __syncthreads();
    if (tt >= 64 && tt < 128) rp16[tt + 1] = (unsigned short)(rp16[tt + 1] + w0tot);
    if (tt == 0) rp16[0] = 0;
    __syncthreads();

    const int mydeg = (tt < 128) ? aux[tt] : 0;
    const double dvm = 1.0 / sqrt((double)(mydeg + 1));    // key-path dinv (tt<128)

    // deterministic CSR emit (s ascending, multiplicity preserved)
    if (tt < 128) {
        unsigned pos = rp16[tt];
        for (int w = 0; w < 32; ++w) {
            unsigned u = adjM[(tt << 5) + w];
            while (u) {
                int b2 = (u & 0xFFu) ? 0 : (u & 0xFF00u) ? 1 : (u & 0xFF0000u) ? 2 : 3;
                int m = (int)((u >> (b2 << 3)) & 255u);
                unsigned char sv = (unsigned char)((w << 2) + b2);
                for (int q = 0; q < m; ++q) { if (pos < ECAP) csr[pos] = sv; ++pos; }
                u &= ~(0xFFu << (b2 << 3));
            }
        }
    }
    // degree-descending rank sort -> perm (phase-2 assignment only)
    if (tt < 128) {
        int dmine = aux[tt];
        int rk = 0;
        for (int j = 0; j < 128; ++j) {
            int dj = aux[j];
            if (dj > dmine || (dj == dmine && j < tt)) ++rk;
        }
        perm[rk] = (unsigned char)tt;
    }
    __syncthreads();                 // adjM reads done; Xd free; perm/CSR published

    // natural rows (phase 1) and balanced perm rows (phase 2)
    const int r0 = tt >> 3;
    const int r1 = r0 + 64;
    const double dv0 = 1.0 / sqrt((double)(aux[r0] + 1));
    const double dv1 = 1.0 / sqrt((double)(aux[r1] + 1));
    const int q    = tt >> 3;
    const int rowA = perm[q];
    const int rowB = perm[127 - q];
    const double dvA = 1.0 / sqrt((double)(aux[rowA] + 1));
    const double dvB = 1.0 / sqrt((double)(aux[rowB] + 1));
    const int cS = (c0 & 48) >> 3;           // constant part of xd swizzle for this thread

    // X0 = z_table[z] (f32 hi; lo plane unused in layer 0)
    for (int idx = tt; idx < 8192; idx += 512) {
        int n = idx >> 6, c = idx & 63;
        int zv = z[(g << 7) + n];
        zv = (zv < 0) ? 0 : ((zv >= MAXZ) ? MAXZ - 1 : zv);
        XH[xh_idx(n, c)] = zt[zv * 64 + c];
    }
    __syncthreads();

    // ---- three GCN layers ----
    for (int layer = 0; layer < 3; ++layer) {
        const float* Wg = (layer == 0) ? W0 : (layer == 1) ? W1 : W2;
        const float* bg = (layer == 0) ? b0 : (layer == 1) ? b1 : b2;
        const bool haslo = (layer != 0);

        // phase 1 (natural rows): acc = (X @ W)[r0,r1][c0..c0+7]
        double accd0[8], accd1[8]; float accf0[8], accf1[8];
#pragma unroll
        for (int j = 0; j < 8; ++j) { accd0[j] = 0.0; accd1[j] = 0.0; accf0[j] = 0.f; accf1[j] = 0.f; }

        for (int k = 0; k < 64; k += 4) {
            float4 a0 = *(const float4*)&XH[xh_idx(r0, k)];
            float4 a1 = *(const float4*)&XH[xh_idx(r1, k)];
            float x0[4] = {a0.x, a0.y, a0.z, a0.w};
            float x1[4] = {a1.x, a1.y, a1.z, a1.w};
            float l0[4], l1[4];
            if (haslo) {
                float4 u0 = *(const float4*)&XL[xh_idx(r0, k)];
                float4 u1 = *(const float4*)&XL[xh_idx(r1, k)];
                l0[0] = u0.x; l0[1] = u0.y; l0[2] = u0.z; l0[3] = u0.w;
                l1[0] = u1.x; l1[1] = u1.y; l1[2] = u1.z; l1[3] = u1.w;
            }
#pragma unroll
            for (int kk = 0; kk < 4; ++kk) {
                const float* wr = Wg + ((k + kk) << 6) + c0;
                float4 wa = *(const float4*)wr;
                float4 wb = *(const float4*)(wr + 4);
                float wf[8] = {wa.x, wa.y, wa.z, wa.w, wb.x, wb.y, wb.z, wb.w};
                double xd0 = (double)x0[kk], xd1 = (double)x1[kk];
#pragma unroll
                for (int j = 0; j < 8; ++j) {
                    double wd = (double)wf[j];
                    accd0[j] = fma(xd0, wd, accd0[j]);
                    accd1[j] = fma(xd1, wd, accd1[j]);
                }
                if (haslo) {
#pragma unroll
                    for (int j = 0; j < 8; ++j) {
                        accf0[j] = fmaf(l0[kk], wf[j], accf0[j]);
                        accf1[j] = fmaf(l1[kk], wf[j], accf1[j]);
                    }
                }
            }
        }
        __syncthreads();                                   // all X reads complete

        // H = dinv * acc; store native f64 (overwrites X planes)
        {
            int bi = xd_idx(r0, c0);
            *(double2*)&HD[bi]     = make_double2(dv0 * (accd0[0] + (double)accf0[0]),
                                                  dv0 * (accd0[1] + (double)accf0[1]));
            *(double2*)&HD[bi ^ 2] = make_double2(dv0 * (accd0[2] + (double)accf0[2]),
                                                  dv0 * (accd0[3] + (double)accf0[3]));
            *(double2*)&HD[bi ^ 4] = make_double2(dv0 * (accd0[4] + (double)accf0[4]),
                                                  dv0 * (accd0[5] + (double)accf0[5]));
            *(double2*)&HD[bi ^ 6] = make_double2(dv0 * (accd0[6] + (double)accf0[6]),
                                                  dv0 * (accd0[7] + (double)accf0[7]));
            int bj = xd_idx(r1, c0);
            *(double2*)&HD[bj]     = make_double2(dv1 * (accd1[0] + (double)accf1[0]),
                                                  dv1 * (accd1[1] + (double)accf1[1]));
            *(double2*)&HD[bj ^ 2] = make_double2(dv1 * (accd1[2] + (double)accf1[2]),
                                                  dv1 * (accd1[3] + (double)accf1[3]));
            *(double2*)&HD[bj ^ 4] = make_double2(dv1 * (accd1[4] + (double)accf1[4]),
                                                  dv1 * (accd1[5] + (double)accf1[5]));
            *(double2*)&HD[bj ^ 6] = make_double2(dv1 * (accd1[6] + (double)accf1[6]),
                                                  dv1 * (accd1[7] + (double)accf1[7]));
        }
        __syncthreads();                                   // H fully written

        // phase 2 (perm rows, reload-init): agg = H[own] + sum_neighbors H[s]
        float vfs[2][8], rss[2][8];
#pragma unroll
        for (int rw = 0; rw < 2; ++rw) {
            int rr = rw ? rowB : rowA;
            double dv = rw ? dvB : dvA;
            int bio = xd_idx(rr, c0);
            double2 p0 = *(const double2*)&HD[bio];
            double2 p1 = *(const double2*)&HD[bio ^ 2];
            double2 p2 = *(const double2*)&HD[bio ^ 4];
            double2 p3 = *(const double2*)&HD[bio ^ 6];
            double ad[8];
            ad[0] = p0.x; ad[1] = p0.y; ad[2] = p1.x; ad[3] = p1.y;
            ad[4] = p2.x; ad[5] = p2.y; ad[6] = p3.x; ad[7] = p3.y;

            for (unsigned e = rp16[rr]; e < rp16[rr + 1]; ++e) {
                int s = csr[e];
                int bs = (s << 6) | ((c0 ^ cS) ^ ((s & 7) << 1));
                double2 q0 = *(const double2*)&HD[bs];
                double2 q1 = *(const double2*)&HD[bs ^ 2];
                double2 q2 = *(const double2*)&HD[bs ^ 4];
                double2 q3 = *(const double2*)&HD[bs ^ 6];
                ad[0] += q0.x; ad[1] += q0.y;
                ad[2] += q1.x; ad[3] += q1.y;
                ad[4] += q2.x; ad[5] += q2.y;
                ad[6] += q3.x; ad[7] += q3.y;
            }
            // tanh pre-barrier; stores deferred
#pragma unroll
            for (int j = 0; j < 8; ++j) {
                double v = tanh_fast(dv * ad[j] + (double)bg[c0 + j]);
                float vfl = (float)v;
                vfs[rw][j] = vfl;
                rss[rw][j] = (float)(v - (double)vfl);
            }
        }
        __syncthreads();                                   // all H reads complete

        // store X = tanh outputs (f32 hi + f32 lo planes); dump layer-0/1 for head
#pragma unroll
        for (int rw = 0; rw < 2; ++rw) {
            int rr = rw ? rowB : rowA;
            int bi = xh_idx(rr, c0);
            *(float4*)&XH[bi]     = make_float4(vfs[rw][0], vfs[rw][1], vfs[rw][2], vfs[rw][3]);
            *(float4*)&XH[bi + 4] = make_float4(vfs[rw][4], vfs[rw][5], vfs[rw][6], vfs[rw][7]);
            *(float4*)&XL[bi]     = make_float4(rss[rw][0], rss[rw][1], rss[rw][2], rss[rw][3]);
            *(float4*)&XL[bi + 4] = make_float4(rss[rw][4], rss[rw][5], rss[rw][6], rss[rw][7]);

            if (layer < 2) {
                float* xd = xdump + (((size_t)g * 2 + layer) << 13) + (rr << 6) + c0;
                *(float4*)xd       = make_float4(vfs[rw][0], vfs[rw][1], vfs[rw][2], vfs[rw][3]);
                *(float4*)(xd + 4) = make_float4(vfs[rw][4], vfs[rw][5], vfs[rw][6], vfs[rw][7]);
            }
        }
        __syncthreads();
    }

    // ---- layer 4 (64->1): key path; overlays on XL plane ----
    double* h4sD  = (double*)XL;
    double* keydD = ((double*)XL) + 128;

    double sdreg = 0.0;
    if (tt < 128) {
        double sd = 0.0; float sf = 0.f;
        for (int k = 0; k < 64; k += 4) {
            float4 a = *(const float4*)&XH[xh_idx(tt, k)];
            float4 u = *(const float4*)&XL[xh_idx(tt, k)];
            float4 w = *(const float4*)&W3[k];
            sd = fma((double)a.x, (double)w.x, sd);
            sd = fma((double)a.y, (double)w.y, sd);
            sd = fma((double)a.z, (double)w.z, sd);
            sd = fma((double)a.w, (double)w.w, sd);
            sf = fmaf(u.x, w.x, sf);
            sf = fmaf(u.y, w.y, sf);
            sf = fmaf(u.z, w.z, sf);
            sf = fmaf(u.w, w.w, sf);
        }
        sdreg = sd + (double)sf;
    }
    __syncthreads();                          // XL reads done before overlay write
    if (tt < 128) h4sD[tt] = dvm * sdreg;
    __syncthreads();
    double keyreg = 0.0;
    if (tt < 128) {
        double a = h4sD[tt];
        for (unsigned e = rp16[tt]; e < rp16[tt + 1]; ++e) a += h4sD[csr[e]];
        keyreg = tanh_fast(dvm * a + (double)b3[0]);
        keydD[tt] = keyreg;
    }
    __syncthreads();

    // stable descending rank == stable argsort(-key)
    if (tt < 128) {
        int rk = 0;
        for (int j = 0; j < 128; ++j) {
            double kj = keydD[j];
            if (kj > keyreg || (kj == keyreg && j < tt)) ++rk;
        }
        if (rk < 30) { inv[rk] = tt; kd30f[rk] = (float)keyreg; }
    }
    __syncthreads();                         // publish inv/kd30f; keyd reads done

    // ---- head (in XL plane past the key overlay) ----
    float* XloF = XL;
    float* h1v = XloF + 2560;   // 480
    float* ppv = XloF + 3040;   // 240
    float* flv = XloF + 3280;   // 352
    float* hmv = XloF + 3632;   // 128

    if (tt < 480) {
        int c = tt & 15, k = tt >> 4;
        int node = inv[k];
        // conv1 partials, bit-identical chain+tree (L0 j0..7, L1 j0..7, L2 j0..7; xor tree)
        const float* wrow = c1w + c * 193;
        const float* xg0 = xdump + ((size_t)g * 2) * 8192 + node * 64;
        const float* xg1 = xg0 + 8192;
        float s8[8];
#pragma unroll
        for (int cg = 0; cg < 8; ++cg) {
            float acc = 0.f;
            float4 xa = *(const float4*)&xg0[cg * 8];
            float4 xb = *(const float4*)&xg0[cg * 8 + 4];
            const float* w0p = wrow + cg * 8;
            acc = fmaf(xa.x, w0p[0], acc); acc = fmaf(xa.y, w0p[1], acc);
            acc = fmaf(xa.z, w0p[2], acc); acc = fmaf(xa.w, w0p[3], acc);
            acc = fmaf(xb.x, w0p[4], acc); acc = fmaf(xb.y, w0p[5], acc);
            acc = fmaf(xb.z, w0p[6], acc); acc = fmaf(xb.w, w0p[7], acc);
            float4 ya = *(const float4*)&xg1[cg * 8];
            float4 yb = *(const float4*)&xg1[cg * 8 + 4];
            const float* w1p = wrow + 64 + cg * 8;
            acc = fmaf(ya.x, w1p[0], acc); acc = fmaf(ya.y, w1p[1], acc);
            acc = fmaf(ya.z, w1p[2], acc); acc = fmaf(ya.w, w1p[3], acc);
            acc = fmaf(yb.x, w1p[4], acc); acc = fmaf(yb.y, w1p[5], acc);
            acc = fmaf(yb.z, w1p[6], acc); acc = fmaf(yb.w, w1p[7], acc);
            const float* w2p = wrow + 128 + cg * 8;
#pragma unroll
            for (int j = 0; j < 8; ++j)
                acc = fmaf(XH[xh_idx(node, cg * 8 + j)], w2p[j], acc);
            s8[cg] = acc;
        }
        float A0 = s8[0] + s8[1], A1 = s8[2] + s8[3];
        float A2 = s8[4] + s8[5], A3 = s8[6] + s8[7];
        float G = (A0 + A1) + (A2 + A3);
        float s = G + c1w[c * 193 + 192] * kd30f[k] + c1b[c];
        h1v[c * 30 + k] = s > 0.f ? s : 0.f;
    }
    __syncthreads();
    if (tt < 240) {
        int c = tt & 15, i = tt >> 4;
        float a = h1v[c * 30 + 2 * i], b = h1v[c * 30 + 2 * i + 1];
        ppv[c * 15 + i] = a > b ? a : b;
    }
    __syncthreads();
    if (tt < 352) {
        int o = tt / 11, j = tt % 11;
        float s = c2b[o];
        for (int i = 0; i < 16; ++i)
#pragma unroll
            for (int u = 0; u < 5; ++u)
                s = fmaf(ppv[i * 15 + j + u], c2w[o * 80 + i * 5 + u], s);
        flv[tt] = s > 0.f ? s : 0.f;
    }
    __syncthreads();
    if (tt < 128) {
        float s = l1b[tt];
        for (int i = 0; i < 352; ++i) s = fmaf(flv[i], l1w[i * 128 + tt], s);
        hmv[tt] = s > 0.f ? s : 0.f;
    }
    __syncthreads();
    if (tt < 64) {
        float v = fmaf(hmv[tt], l2w[tt], hmv[tt + 64] * l2w[tt + 64]);
#pragma unroll
        for (int o = 32; o > 0; o >>= 1) v += __shfl_down(v, o, 64);
        if (tt == 0) out[g] = v + l2b[0];
    }
}

// ============ fallback kernel: r2 fused variant (512 threads, 1 graph) ============
__global__ __launch_bounds__(512, 2) void gnn_kernel(
    const int* __restrict__ z,
    const unsigned* __restrict__ adjG,
    const float* __restrict__ zt,
    const float* __restrict__ W0, const float* __restrict__ b0,
    const float* __restrict__ W1, const float* __restrict__ b1,
    const float* __restrict__ W2, const float* __restrict__ b2,
    const float* __restrict__ W3, const float* __restrict__ b3,
    const float* __restrict__ c1w, const float* __restrict__ c1b,
    const float* __restrict__ c2w, const float* __restrict__ c2b,
    const float* __restrict__ l1w, const float* __restrict__ l1b,
    const float* __restrict__ l2w, const float* __restrict__ l2b,
    float* __restrict__ out)
{
    __shared__ __align__(16) float    Xhi[8192];
    __shared__ __align__(16) unsigned Xlo[4096];
    __shared__ unsigned char  csr[ECAP];
    __shared__ unsigned short rp16[132];
    __shared__ int            aux[128];
    __shared__ int            inv[30];
    __shared__ float          kd30f[30];
    __shared__ int            w0tot;

    const int g  = blockIdx.x;
    const int t  = threadIdx.x;
    const int r0 = t >> 3;
    const int r1 = r0 + 64;
    const int c0 = (t & 7) << 3;

    unsigned* adjM = (unsigned*)Xhi;

    {
        const uint4* src = (const uint4*)(adjG + ((size_t)g << 12));
        uint4* dst = (uint4*)adjM;
        for (int i = t; i < 1024; i += 512) dst[i] = src[i];
    }
    if (t < 30) { inv[t] = t; kd30f[t] = 0.f; }
    __syncthreads();

    int degv = 0;
    if (t < 128) {
        for (int w = 0; w < 32; ++w) {
            unsigned u = adjM[(t << 5) + w];
            degv += (int)((u & 255u) + ((u >> 8) & 255u) + ((u >> 16) & 255u) + (u >> 24));
        }
        aux[t] = degv;
    }
    if (t < 128) {
        int v = degv;
        for (int o = 1; o < 64; o <<= 1) {
            int u = __shfl_up(v, o, 64);
            if ((t & 63) >= o) v += u;
        }
        if (t == 63) w0tot = v;
        rp16[t + 1] = (unsigned short)v;
    }
    __syncthreads();
    if (t >= 64 && t < 128) rp16[t + 1] = (unsigned short)(rp16[t + 1] + w0tot);
    if (t == 0) rp16[0] = 0;
    __syncthreads();

    const int mydeg = (t < 128) ? aux[t] : 0;
    const double dv0 = 1.0 / sqrt((double)(aux[r0] + 1));
    const double dv1 = 1.0 / sqrt((double)(aux[r1] + 1));
    const double dvm = 1.0 / sqrt((double)(mydeg + 1));

    if (t < 128) {
        unsigned pos = rp16[t];
        for (int w = 0; w < 32; ++w) {
            unsigned u = adjM[(t << 5) + w];
            while (u) {
                int b2 = (u & 0xFFu) ? 0 : (u & 0xFF00u) ? 1 : (u & 0xFF0000u) ? 2 : 3;
                int m = (int)((u >> (b2 << 3)) & 255u);
                unsigned char sv = (unsigned char)((w << 2) + b2);
                for (int q = 0; q < m; ++q) { if (pos < ECAP) csr[pos] = sv; ++pos; }
                u &= ~(0xFFu << (b2 << 3));
            }
        }
    }
    __syncthreads();

    for (int idx = t; idx < 8192; idx += 512) {
        int n = idx >> 6, c = idx & 63;
        int zv = z[(g << 7) + n];
        zv = (zv < 0) ? 0 : ((zv >= MAXZ) ? MAXZ - 1 : zv);
        Xhi[xh_idx(n, c)] = zt[zv * 64 + c];
    }
    __syncthreads();

    float g1p[2][16];
#pragma unroll
    for (int rw = 0; rw < 2; ++rw)
#pragma unroll
        for (int c = 0; c < 16; ++c) g1p[rw][c] = 0.f;

    for (int layer = 0; layer < 3; ++layer) {
        const float* Wg = (layer == 0) ? W0 : (layer == 1) ? W1 : W2;
        const float* bg = (layer == 0) ? b0 : (layer == 1) ? b1 : b2;
        const bool haslo = (layer != 0);

        double accd0[8], accd1[8]; float accf0[8], accf1[8];
#pragma unroll
        for (int j = 0; j < 8; ++j) { accd0[j] = 0.0; accd1[j] = 0.0; accf0[j] = 0.f; accf1[j] = 0.f; }

        for (int k = 0; k < 64; k += 4) {
            float4 a0 = *(const float4*)&Xhi[xh_idx(r0, k)];
            float4 a1 = *(const float4*)&Xhi[xh_idx(r1, k)];
            float x0[4] = {a0.x, a0.y, a0.z, a0.w};
            float x1[4] = {a1.x, a1.y, a1.z, a1.w};
            float l0[4], l1[4];
            if (haslo) {
                uint2 u0 = *(const uint2*)&Xlo[xl_idx(r0, k >> 1)];
                uint2 u1 = *(const uint2*)&Xlo[xl_idx(r1, k >> 1)];
                l0[0] = bfu_lo(u0.x); l0[1] = bfu_hi(u0.x); l0[2] = bfu_lo(u0.y); l0[3] = bfu_hi(u0.y);
                l1[0] = bfu_lo(u1.x); l1[1] = bfu_hi(u1.x); l1[2] = bfu_lo(u1.y); l1[3] = bfu_hi(u1.y);
            }
#pragma unroll
            for (int kk = 0; kk < 4; ++kk) {
                const float* wr = Wg + ((k + kk) << 6) + c0;
                float4 wa = *(const float4*)wr;
                float4 wb = *(const float4*)(wr + 4);
                float wf[8] = {wa.x, wa.y, wa.z, wa.w, wb.x, wb.y, wb.z, wb.w};
                double xd0 = (double)x0[kk], xd1 = (double)x1[kk];
#pragma unroll
                for (int j = 0; j < 8; ++j) {
                    double wd = (double)wf[j];
                    accd0[j] = fma(xd0, wd, accd0[j]);
                    accd1[j] = fma(xd1, wd, accd1[j]);
                }
                if (haslo) {
#pragma unroll
                    for (int j = 0; j < 8; ++j) {
                        accf0[j] = fmaf(l0[kk], wf[j], accf0[j]);
                        accf1[j] = fmaf(l1[kk], wf[j], accf1[j]);
                    }
                }
            }
        }
        __syncthreads();

        float hfv[2][8], rsv[2][8];
#pragma unroll
        for (int rw = 0; rw < 2; ++rw) {
            int rr = rw ? r1 : r0;
            double dv = rw ? dv1 : dv0;
#pragma unroll
            for (int j = 0; j < 8; ++j) {
                double acc = rw ? (accd1[j] + (double)accf1[j]) : (accd0[j] + (double)accf0[j]);
                double h = dv * acc;
                float hf = (float)h;
                hfv[rw][j] = hf;
                rsv[rw][j] = (float)(h - (double)hf);
            }
            int bi = xh_idx(rr, c0);
            *(float4*)&Xhi[bi]     = make_float4(hfv[rw][0], hfv[rw][1], hfv[rw][2], hfv[rw][3]);
            *(float4*)&Xhi[bi + 4] = make_float4(hfv[rw][4], hfv[rw][5], hfv[rw][6], hfv[rw][7]);
            uint4 lv;
            lv.x = packlo(rsv[rw][0], rsv[rw][1]);
            lv.y = packlo(rsv[rw][2], rsv[rw][3]);
            lv.z = packlo(rsv[rw][4], rsv[rw][5]);
            lv.w = packlo(rsv[rw][6], rsv[rw][7]);
            *(uint4*)&Xlo[xl_idx(rr, c0 >> 1)] = lv;
        }
        __syncthreads();

        double ad[2][8]; float af[2][8];
#pragma unroll
        for (int rw = 0; rw < 2; ++rw)
#pragma unroll
            for (int j = 0; j < 8; ++j) { ad[rw][j] = (double)hfv[rw][j]; af[rw][j] = rsv[rw][j]; }

#pragma unroll
        for (int rw = 0; rw < 2; ++rw) {
            int rr = rw ? r1 : r0;
            for (unsigned e = rp16[rr]; e < rp16[rr + 1]; ++e) {
                int s = csr[e];
                int bi = (s << 6) | (c0 ^ ((s & 7) << 3));
                float4 a = *(const float4*)&Xhi[bi];
                float4 b = *(const float4*)&Xhi[bi + 4];
                uint4 lu = *(const uint4*)&Xlo[(s << 5) | ((c0 >> 1) ^ ((s & 7) << 2))];
                ad[rw][0] += (double)a.x; ad[rw][1] += (double)a.y;
                ad[rw][2] += (double)a.z; ad[rw][3] += (double)a.w;
                ad[rw][4] += (double)b.x; ad[rw][5] += (double)b.y;
                ad[rw][6] += (double)b.z; ad[rw][7] += (double)b.w;
                af[rw][0] += bfu_lo(lu.x); af[rw][1] += bfu_hi(lu.x);
                af[rw][2] += bfu_lo(lu.y); af[rw][3] += bfu_hi(lu.y);
                af[rw][4] += bfu_lo(lu.z); af[rw][5] += bfu_hi(lu.z);
                af[rw][6] += bfu_lo(lu.w); af[rw][7] += bfu_hi(lu.w);
            }
        }
        __syncthreads();

#pragma unroll
        for (int rw = 0; rw < 2; ++rw) {
            int rr = rw ? r1 : r0;
            double dv = rw ? dv1 : dv0;
            float vf[8], rs[8];
#pragma unroll
            for (int j = 0; j < 8; ++j) {
                double v = tanh_fast(dv * (ad[rw][j] + (double)af[rw][j]) + (double)bg[c0 + j]);
                float vfl = (float)v;
                vf[j] = vfl;
                rs[j] = (float)(v - (double)vfl);
            }
            int bi = xh_idx(rr, c0);
            *(float4*)&Xhi[bi]     = make_float4(vf[0], vf[1], vf[2], vf[3]);
            *(float4*)&Xhi[bi + 4] = make_float4(vf[4], vf[5], vf[6], vf[7]);
            uint4 lv;
            lv.x = packlo(rs[0], rs[1]);
            lv.y = packlo(rs[2], rs[3]);
            lv.z = packlo(rs[4], rs[5]);
            lv.w = packlo(rs[6], rs[7]);
            *(uint4*)&Xlo[xl_idx(rr, c0 >> 1)] = lv;

            const float* w1base = c1w + layer * 64 + c0;
            for (int c = 0; c < 16; ++c) {
                const float* wr = w1base + c * 193;
#pragma unroll
                for (int j = 0; j < 8; ++j)
                    g1p[rw][c] = fmaf(vf[j], wr[j], g1p[rw][c]);
            }
        }
        __syncthreads();
    }

    double* h4sD  = (double*)Xlo;
    double* keydD = ((double*)Xlo) + 128;

    double sdreg = 0.0;
    if (t < 128) {
        double sd = 0.0; float sf = 0.f;
        for (int k = 0; k < 64; k += 4) {
            float4 a = *(const float4*)&Xhi[xh_idx(t, k)];
            uint2  u = *(const uint2*)&Xlo[xl_idx(t, k >> 1)];
            float4 w = *(const float4*)&W3[k];
            sd = fma((double)a.x, (double)w.x, sd);
            sd = fma((double)a.y, (double)w.y, sd);
            sd = fma((double)a.z, (double)w.z, sd);
            sd = fma((double)a.w, (double)w.w, sd);
            sf = fmaf(bfu_lo(u.x), w.x, sf);
            sf = fmaf(bfu_hi(u.x), w.y, sf);
            sf = fmaf(bfu_lo(u.y), w.z, sf);
            sf = fmaf(bfu_hi(u.y), w.w, sf);
        }
        sdreg = sd + (double)sf;
    }
    __syncthreads();
    if (t < 128) h4sD[t] = dvm * sdreg;
    __syncthreads();
    double keyreg = 0.0;
    if (t < 128) {
        double a = h4sD[t];
        for (unsigned e = rp16[t]; e < rp16[t + 1]; ++e) a += h4sD[csr[e]];
        keyreg = tanh_fast(dvm * a + (double)b3[0]);
        keydD[t] = keyreg;
    }
    __syncthreads();

    if (t < 128) {
        int rk = 0;
        for (int j = 0; j < 128; ++j) {
            double kj = keydD[j];
            if (kj > keyreg || (kj == keyreg && j < t)) ++rk;
        }
        if (rk < 30) { inv[rk] = t; kd30f[rk] = (float)keyreg; }
    }

#pragma unroll
    for (int m = 1; m <= 4; m <<= 1) {
#pragma unroll
        for (int rw = 0; rw < 2; ++rw)
#pragma unroll
            for (int c = 0; c < 16; ++c)
                g1p[rw][c] += __shfl_xor(g1p[rw][c], m, 64);
    }
    __syncthreads();
    float* XloF = (float*)Xlo;
    float* G1   = XloF + 512;
    if ((t & 7) == 0) {
#pragma unroll
        for (int c = 0; c < 16; c += 4) {
            *(float4*)&G1[r0 * 16 + c] = make_float4(g1p[0][c], g1p[0][c + 1], g1p[0][c + 2], g1p[0][c + 3]);
            *(float4*)&G1[r1 * 16 + c] = make_float4(g1p[1][c], g1p[1][c + 1], g1p[1][c + 2], g1p[1][c + 3]);
        }
    }
    __syncthreads();

    float* h1v = XloF + 2560;
    float* ppv = XloF + 3040;
    float* flv = XloF + 3280;
    float* hmv = XloF + 3632;

    if (t < 480) {
        int c = t & 15, k = t >> 4;
        int node = inv[k];
        float s = G1[node * 16 + c] + c1w[c * 193 + 192] * kd30f[k] + c1b[c];
        h1v[c * 30 + k] = s > 0.f ? s : 0.f;
    }
    __syncthreads();
    if (t < 240) {
        int c = t & 15, i = t >> 4;
        float a = h1v[c * 30 + 2 * i], b = h1v[c * 30 + 2 * i + 1];
        ppv[c * 15 + i] = a > b ? a : b;
    }
    __syncthreads();
    if (t < 352) {
        int o = t / 11, j = t % 11;
        float s = c2b[o];
        for (int i = 0; i < 16; ++i)
#pragma unroll
            for (int u = 0; u < 5; ++u)
                s = fmaf(ppv[i * 15 + j + u], c2w[o * 80 + i * 5 + u], s);
        flv[t] = s > 0.f ? s : 0.f;
    }
    __syncthreads();
    if (t < 128) {
        float s = l1b[t];
        for (int i = 0; i < 352; ++i) s = fmaf(flv[i], l1w[i * 128 + t], s);
        hmv[t] = s > 0.f ? s : 0.f;
    }
    __syncthreads();
    if (t < 64) {
        float v = fmaf(hmv[t], l2w[t], hmv[t + 64] * l2w[t + 64]);
#pragma unroll
        for (int o = 32; o > 0; o >>= 1) v += __shfl_down(v, o, 64);
        if (t == 0) out[g] = v + l2b[0];
    }
}

// ---------------- launch ----------------

extern "C" void kernel_launch(void* const* d_in, const int* in_sizes, int n_in,
                              void* d_out, int out_size, void* d_ws, size_t ws_size,
                              hipStream_t stream) {
    const int*   z   = (const int*)d_in[0];
    const int*   ei  = (const int*)d_in[1];
    const float* zt  = (const float*)d_in[3];
    const float* W0  = (const float*)d_in[4];
    const float* b0  = (const float*)d_in[5];
    const float* W1  = (const float*)d_in[6];
    const float* b1  = (const float*)d_in[7];
    const float* W2  = (const float*)d_in[8];
    const float* b2  = (const float*)d_in[9];
    const float* W3  = (const float*)d_in[10];
    const float* b3  = (const float*)d_in[11];
    const float* c1w = (const float*)d_in[12];
    const float* c1b = (const float*)d_in[13];
    const float* c2w = (const float*)d_in[14];
    const float* c2b = (const float*)d_in[15];
    const float* l1w = (const float*)d_in[16];
    const float* l1b = (const float*)d_in[17];
    const float* l2w = (const float*)d_in[18];
    const float* l2b = (const float*)d_in[19];
    float* out = (float*)d_out;

    const size_t ADJ_B = (size_t)NGRAPH * 4096 * 4;            // 16.78 MB
    const size_t XD_B  = (size_t)NGRAPH * 2 * 8192 * 4;        // 67.11 MB (x dumps, layers 0-1)
    if (ws_size < ADJ_B) {
        markWS_kernel<<<4, 256, 0, stream>>>(out);
        return;
    }

    unsigned* adjG = (unsigned*)d_ws;

    hipMemsetAsync(adjG, 0, ADJ_B, stream);
    adjscatter_kernel<<<(E_EDGES + 255) / 256, 256, 0, stream>>>(ei, adjG);

    if (ws_size >= ADJ_B + XD_B) {
        float* xdump = (float*)((char*)d_ws + ADJ_B);
        gnn1_kernel<<<NGRAPH, 512, 0, stream>>>(z, adjG, zt,
                                                W0, b0, W1, b1, W2, b2, W3, b3,
                                                c1w, c1b, c2w, c2b, l1w, l1b, l2w, l2b,
                                                xdump, out);
    } else {
        gnn_kernel<<<NGRAPH, 512, 0, stream>>>(z, adjG, zt,
                                               W0, b0, W1, b1, W2, b2, W3, b3,
                                               c1w, c1b, c2w, c2b, l1w, l1b, l2w, l2b,
                                               out);
    }
}

// Round 14
// 517.046 us; speedup vs baseline: 1.4964x; 1.0857x over previous
//
#include <hip/hip_runtime.h>

#define NGRAPH  1024
#define E_EDGES 2097152
#define ECAP    2944
#define MAXZ    1000

__device__ __forceinline__ float bfu_lo(unsigned u) { return __uint_as_float(u << 16); }
__device__ __forceinline__ float bfu_hi(unsigned u) { return __uint_as_float(u & 0xFFFF0000u); }
__device__ __forceinline__ unsigned packlo(float f0, float f1) {
    return (__float_as_uint(f0) >> 16) | (__float_as_uint(f1) & 0xFFFF0000u);
}
// XOR-swizzled indices: f32 tile [128][64] (fallback kernel)
__device__ __forceinline__ int xh_idx(int r, int k)  { return (r << 6) | (k  ^ ((r & 7) << 3)); }
__device__ __forceinline__ int xl_idx(int r, int k2) { return (r << 5) | (k2 ^ ((r & 7) << 2)); }
// XOR swizzle for f64 X/H tile [128][64] (r3/r9-validated)
__device__ __forceinline__ int xd_idx(int r, int c) {
    return (r << 6) | (c ^ ((r & 7) << 1) ^ ((c & 48) >> 3));
}

// branchless double tanh via e^{2p}; abs error ~2e-13
__device__ __forceinline__ double tanh_fast(double p) {
    double q = 2.0 * p;
    q = fmin(40.0, fmax(-40.0, q));
    double nf = rint(q * 1.4426950408889634074);
    double r  = fma(nf, -6.93147180369123816490e-01, q);
    r = fma(nf, -1.90821492927058770002e-10, r);
    double er =     2.755731922398589e-07;
    er = fma(er, r, 2.755731922398589e-06);
    er = fma(er, r, 2.4801587301587302e-05);
    er = fma(er, r, 1.984126984126984e-04);
    er = fma(er, r, 1.3888888888888889e-03);
    er = fma(er, r, 8.333333333333333e-03);
    er = fma(er, r, 4.1666666666666664e-02);
    er = fma(er, r, 1.6666666666666666e-01);
    er = fma(er, r, 0.5);
    er = fma(er, r, 1.0);
    er = fma(er, r, 1.0);                        // e^r
    double E = er * __longlong_as_double((long long)(1023 + (int)nf) << 52);
    return 1.0 - 2.0 / (E + 1.0);
}

__global__ void markWS_kernel(float* out) {
    int i = blockIdx.x * 256 + threadIdx.x;
    if (i < NGRAPH) out[i] = 2.0f;
}

// packed adjacency counts: adjG[g][d][s/4] byte-lane (s&3); commutative atomics
__global__ void adjscatter_kernel(const int* __restrict__ ei,
                                  unsigned* __restrict__ adjG) {
    int e = blockIdx.x * 256 + threadIdx.x;
    if (e >= E_EDGES) return;
    int s = ei[e];
    int d = ei[E_EDGES + e];
    int g = s >> 7;
    int sl = s & 127, dl = d & 127;
    atomicAdd(&adjG[((size_t)g << 12) + (dl << 5) + (sl >> 2)], 1u << ((sl & 3) << 3));
}

// ============ primary: 512 threads = ONE graph/block, full-f64 X/H ============
// r13 structure (2 blocks/CU, decoupled barriers, degree-balanced phase 2) with the
// hi/lo split eliminated: X AND H native f64 in one 64KB LDS buffer (same bytes as
// the two f32 planes; same b128 load count). Phase 1 loses the 16 f32 shadow FMA +
// 2 x-cvts per kk (~40% of its VALU stream) and 16 live VGPRs. W stays f32 in
// global (f64 W thrashed L1 in r9). Numerics = r3/r9 (absmax 0.0 precedent).
// Key/head overlays move to dedicated LDS (~+7KB -> ~74.7KB/block, still 2/CU).
__global__ __launch_bounds__(512, 4) void gnn1_kernel(
    const int* __restrict__ z,
    const unsigned* __restrict__ adjG,
    const float* __restrict__ zt,
    const float* __restrict__ W0, const float* __restrict__ b0,
    const float* __restrict__ W1, const float* __restrict__ b1,
    const float* __restrict__ W2, const float* __restrict__ b2,
    const float* __restrict__ W3, const float* __restrict__ b3,
    const float* __restrict__ c1w, const float* __restrict__ c1b,
    const float* __restrict__ c2w, const float* __restrict__ c2b,
    const float* __restrict__ l1w, const float* __restrict__ l1b,
    const float* __restrict__ l2w, const float* __restrict__ l2b,
    float* __restrict__ xdump,
    float* __restrict__ out)
{
    __shared__ __align__(16) double   Xd[8192];       // 65536 B f64 X/H (adjM overlay at setup)
    __shared__ __align__(16) double   h4sD[128];      //  1024 B
    __shared__ __align__(16) double   keydD[128];     //  1024 B
    __shared__ __align__(16) float    hscr[1200];     //  4800 B head scratch
    __shared__ unsigned char  csr[ECAP];              //  2944 B
    __shared__ unsigned short rp16[132];
    __shared__ int            aux[128];               // degree
    __shared__ unsigned char  perm[128];              // degree-descending row permutation
    __shared__ int            inv[30];
    __shared__ float          kd30f[30];
    __shared__ int            w0tot;
    // ~74.7 KB/block -> 2 blocks/CU (16 waves) with independent barriers

    const int tt = threadIdx.x;
    const int g  = blockIdx.x;
    const int c0 = (tt & 7) << 3;

    double* XD = Xd;
    unsigned* adjM = (unsigned*)Xd;     // [128][32] packed byte counts (16 KB)

    // load this graph's adjacency-count slab (coalesced)
    {
        const uint4* src = (const uint4*)(adjG + ((size_t)g << 12));
        uint4* dst = (uint4*)adjM;
        for (int i = tt; i < 1024; i += 512) dst[i] = src[i];
    }
    if (tt < 30) { inv[tt] = tt; kd30f[tt] = 0.f; }
    __syncthreads();

    // per-node in-degree
    int degv = 0;
    if (tt < 128) {
        for (int w = 0; w < 32; ++w) {
            unsigned u = adjM[(tt << 5) + w];
            degv += (int)((u & 255u) + ((u >> 8) & 255u) + ((u >> 16) & 255u) + (u >> 24));
        }
        aux[tt] = degv;
    }
    // exclusive scan (two waves)
    if (tt < 128) {
        int v = degv;
        for (int o = 1; o < 64; o <<= 1) {
            int u = __shfl_up(v, o, 64);
            if ((tt & 63) >= o) v += u;
        }
        if (tt == 63) w0tot = v;
        rp16[tt + 1] = (unsigned short)v;
    }
    __syncthreads();
    if (tt >= 64 && tt < 128) rp16[tt + 1] = (unsigned short)(rp16[tt + 1] + w0tot);
    if (tt == 0) rp16[0] = 0;
    __syncthreads();

    const int mydeg = (tt < 128) ? aux[tt] : 0;
    const double dvm = 1.0 / sqrt((double)(mydeg + 1));    // key-path dinv (tt<128)

    // deterministic CSR emit (s ascending, multiplicity preserved)
    if (tt < 128) {
        unsigned pos = rp16[tt];
        for (int w = 0; w < 32; ++w) {
            unsigned u = adjM[(tt << 5) + w];
            while (u) {
                int b2 = (u & 0xFFu) ? 0 : (u & 0xFF00u) ? 1 : (u & 0xFF0000u) ? 2 : 3;
                int m = (int)((u >> (b2 << 3)) & 255u);
                unsigned char sv = (unsigned char)((w << 2) + b2);
                for (int q = 0; q < m; ++q) { if (pos < ECAP) csr[pos] = sv; ++pos; }
                u &= ~(0xFFu << (b2 << 3));
            }
        }
    }
    // degree-descending rank sort -> perm (phase-2 assignment only)
    if (tt < 128) {
        int dmine = aux[tt];
        int rk = 0;
        for (int j = 0; j < 128; ++j) {
            int dj = aux[j];
            if (dj > dmine || (dj == dmine && j < tt)) ++rk;
        }
        perm[rk] = (unsigned char)tt;
    }
    __syncthreads();                 // adjM reads done; Xd free; perm/CSR published

    // natural rows (phase 1) and balanced perm rows (phase 2)
    const int r0 = tt >> 3;
    const int r1 = r0 + 64;
    const double dv0 = 1.0 / sqrt((double)(aux[r0] + 1));
    const double dv1 = 1.0 / sqrt((double)(aux[r1] + 1));
    const int q    = tt >> 3;
    const int rowA = perm[q];
    const int rowB = perm[127 - q];
    const double dvA = 1.0 / sqrt((double)(aux[rowA] + 1));
    const double dvB = 1.0 / sqrt((double)(aux[rowB] + 1));
    const int cS = (c0 & 48) >> 3;           // constant part of xd swizzle for this thread

    // X0 = (double)z_table[z] — exact
    for (int idx = tt; idx < 8192; idx += 512) {
        int n = idx >> 6, c = idx & 63;
        int zv = z[(g << 7) + n];
        zv = (zv < 0) ? 0 : ((zv >= MAXZ) ? MAXZ - 1 : zv);
        XD[xd_idx(n, c)] = (double)zt[zv * 64 + c];
    }
    __syncthreads();

    // ---- three GCN layers ----
    for (int layer = 0; layer < 3; ++layer) {
        const float* Wg = (layer == 0) ? W0 : (layer == 1) ? W1 : W2;
        const float* bg = (layer == 0) ? b0 : (layer == 1) ? b1 : b2;

        // phase 1 (natural rows): acc = (X @ W)[r0,r1][c0..c0+7]; X f64, W f32->f64
        double acc0[8], acc1[8];
#pragma unroll
        for (int j = 0; j < 8; ++j) { acc0[j] = 0.0; acc1[j] = 0.0; }

        for (int k = 0; k < 64; k += 4) {
            int b0i = (r0 << 6) | (k ^ ((r0 & 7) << 1) ^ ((k & 48) >> 3));
            int b1i = b0i + 4096;                        // r1 = r0+64, same swizzle bits
            double2 xa = *(const double2*)&XD[b0i];
            double2 xb = *(const double2*)&XD[b0i ^ 2];
            double2 ya = *(const double2*)&XD[b1i];
            double2 yb = *(const double2*)&XD[b1i ^ 2];
            double x0[4] = {xa.x, xa.y, xb.x, xb.y};
            double x1[4] = {ya.x, ya.y, yb.x, yb.y};
#pragma unroll
            for (int kk = 0; kk < 4; ++kk) {
                const float* wr = Wg + ((k + kk) << 6) + c0;
                float4 wa = *(const float4*)wr;
                float4 wb = *(const float4*)(wr + 4);
                float wf[8] = {wa.x, wa.y, wa.z, wa.w, wb.x, wb.y, wb.z, wb.w};
#pragma unroll
                for (int j = 0; j < 8; ++j) {
                    double wd = (double)wf[j];
                    acc0[j] = fma(x0[kk], wd, acc0[j]);
                    acc1[j] = fma(x1[kk], wd, acc1[j]);
                }
            }
        }
        __syncthreads();                                   // all X reads complete

        // H = dinv * acc; store native f64 (overwrites X)
        {
            int bi = xd_idx(r0, c0);
            *(double2*)&XD[bi]     = make_double2(dv0 * acc0[0], dv0 * acc0[1]);
            *(double2*)&XD[bi ^ 2] = make_double2(dv0 * acc0[2], dv0 * acc0[3]);
            *(double2*)&XD[bi ^ 4] = make_double2(dv0 * acc0[4], dv0 * acc0[5]);
            *(double2*)&XD[bi ^ 6] = make_double2(dv0 * acc0[6], dv0 * acc0[7]);
            int bj = xd_idx(r1, c0);
            *(double2*)&XD[bj]     = make_double2(dv1 * acc1[0], dv1 * acc1[1]);
            *(double2*)&XD[bj ^ 2] = make_double2(dv1 * acc1[2], dv1 * acc1[3]);
            *(double2*)&XD[bj ^ 4] = make_double2(dv1 * acc1[4], dv1 * acc1[5]);
            *(double2*)&XD[bj ^ 6] = make_double2(dv1 * acc1[6], dv1 * acc1[7]);
        }
        __syncthreads();                                   // H fully written

        // phase 2 (perm rows): agg = H[own] + sum_neighbors H[s]; tanh pre-barrier
        double tv[2][8];
#pragma unroll
        for (int rw = 0; rw < 2; ++rw) {
            int rr = rw ? rowB : rowA;
            double dv = rw ? dvB : dvA;
            int bio = xd_idx(rr, c0);
            double2 p0 = *(const double2*)&XD[bio];
            double2 p1 = *(const double2*)&XD[bio ^ 2];
            double2 p2 = *(const double2*)&XD[bio ^ 4];
            double2 p3 = *(const double2*)&XD[bio ^ 6];
            double ad[8];
            ad[0] = p0.x; ad[1] = p0.y; ad[2] = p1.x; ad[3] = p1.y;
            ad[4] = p2.x; ad[5] = p2.y; ad[6] = p3.x; ad[7] = p3.y;

            for (unsigned e = rp16[rr]; e < rp16[rr + 1]; ++e) {
                int s = csr[e];
                int bs = (s << 6) | ((c0 ^ cS) ^ ((s & 7) << 1));
                double2 q0 = *(const double2*)&XD[bs];
                double2 q1 = *(const double2*)&XD[bs ^ 2];
                double2 q2 = *(const double2*)&XD[bs ^ 4];
                double2 q3 = *(const double2*)&XD[bs ^ 6];
                ad[0] += q0.x; ad[1] += q0.y;
                ad[2] += q1.x; ad[3] += q1.y;
                ad[4] += q2.x; ad[5] += q2.y;
                ad[6] += q3.x; ad[7] += q3.y;
            }
#pragma unroll
            for (int j = 0; j < 8; ++j)
                tv[rw][j] = tanh_fast(dv * ad[j] + (double)bg[c0 + j]);
        }
        __syncthreads();                                   // all H reads complete

        // store X = tanh outputs (f64); dump layer-0/1 f32 casts for head-side conv1
#pragma unroll
        for (int rw = 0; rw < 2; ++rw) {
            int rr = rw ? rowB : rowA;
            int bi = xd_idx(rr, c0);
            *(double2*)&XD[bi]     = make_double2(tv[rw][0], tv[rw][1]);
            *(double2*)&XD[bi ^ 2] = make_double2(tv[rw][2], tv[rw][3]);
            *(double2*)&XD[bi ^ 4] = make_double2(tv[rw][4], tv[rw][5]);
            *(double2*)&XD[bi ^ 6] = make_double2(tv[rw][6], tv[rw][7]);

            if (layer < 2) {
                float* xd = xdump + (((size_t)g * 2 + layer) << 13) + (rr << 6) + c0;
                *(float4*)xd       = make_float4((float)tv[rw][0], (float)tv[rw][1],
                                                 (float)tv[rw][2], (float)tv[rw][3]);
                *(float4*)(xd + 4) = make_float4((float)tv[rw][4], (float)tv[rw][5],
                                                 (float)tv[rw][6], (float)tv[rw][7]);
            }
        }
        __syncthreads();
    }

    // ---- layer 4 (64->1): key path (f64 X; r9-validated chain) ----
    double sdreg = 0.0;
    if (tt < 128) {
        double sd = 0.0;
        for (int k = 0; k < 64; k += 2) {
            int bi = (tt << 6) | (k ^ ((tt & 7) << 1) ^ ((k & 48) >> 3));
            double2 a = *(const double2*)&XD[bi];
            sd = fma(a.x, (double)W3[k], sd);
            sd = fma(a.y, (double)W3[k + 1], sd);
        }
        sdreg = sd;
    }
    if (tt < 128) h4sD[tt] = dvm * sdreg;
    __syncthreads();
    double keyreg = 0.0;
    if (tt < 128) {
        double a = h4sD[tt];
        for (unsigned e = rp16[tt]; e < rp16[tt + 1]; ++e) a += h4sD[csr[e]];
        keyreg = tanh_fast(dvm * a + (double)b3[0]);
        keydD[tt] = keyreg;
    }
    __syncthreads();

    // stable descending rank == stable argsort(-key)
    if (tt < 128) {
        int rk = 0;
        for (int j = 0; j < 128; ++j) {
            double kj = keydD[j];
            if (kj > keyreg || (kj == keyreg && j < tt)) ++rk;
        }
        if (rk < 30) { inv[rk] = tt; kd30f[rk] = (float)keyreg; }
    }
    __syncthreads();                         // publish inv/kd30f

    // ---- head (dedicated scratch; X f64 intact for layer-2 term) ----
    float* h1v = hscr;          // 480
    float* ppv = hscr + 480;    // 240
    float* flv = hscr + 720;    // 352
    float* hmv = hscr + 1072;   // 128

    if (tt < 480) {
        int c = tt & 15, k = tt >> 4;
        int node = inv[k];
        // conv1 partials, bit-identical chain+tree (L0 j0..7, L1 j0..7, L2 j0..7; xor tree)
        const float* wrow = c1w + c * 193;
        const float* xg0 = xdump + ((size_t)g * 2) * 8192 + node * 64;
        const float* xg1 = xg0 + 8192;
        float s8[8];
#pragma unroll
        for (int cg = 0; cg < 8; ++cg) {
            float acc = 0.f;
            float4 xa = *(const float4*)&xg0[cg * 8];
            float4 xb = *(const float4*)&xg0[cg * 8 + 4];
            const float* w0p = wrow + cg * 8;
            acc = fmaf(xa.x, w0p[0], acc); acc = fmaf(xa.y, w0p[1], acc);
            acc = fmaf(xa.z, w0p[2], acc); acc = fmaf(xa.w, w0p[3], acc);
            acc = fmaf(xb.x, w0p[4], acc); acc = fmaf(xb.y, w0p[5], acc);
            acc = fmaf(xb.z, w0p[6], acc); acc = fmaf(xb.w, w0p[7], acc);
            float4 ya = *(const float4*)&xg1[cg * 8];
            float4 yb = *(const float4*)&xg1[cg * 8 + 4];
            const float* w1p = wrow + 64 + cg * 8;
            acc = fmaf(ya.x, w1p[0], acc); acc = fmaf(ya.y, w1p[1], acc);
            acc = fmaf(ya.z, w1p[2], acc); acc = fmaf(ya.w, w1p[3], acc);
            acc = fmaf(yb.x, w1p[4], acc); acc = fmaf(yb.y, w1p[5], acc);
            acc = fmaf(yb.z, w1p[6], acc); acc = fmaf(yb.w, w1p[7], acc);
            const float* w2p = wrow + 128 + cg * 8;
#pragma unroll
            for (int j = 0; j < 8; ++j)
                acc = fmaf((float)XD[xd_idx(node, cg * 8 + j)], w2p[j], acc);
            s8[cg] = acc;
        }
        float A0 = s8[0] + s8[1], A1 = s8[2] + s8[3];
        float A2 = s8[4] + s8[5], A3 = s8[6] + s8[7];
        float G = (A0 + A1) + (A2 + A3);
        float s = G + c1w[c * 193 + 192] * kd30f[k] + c1b[c];
        h1v[c * 30 + k] = s > 0.f ? s : 0.f;
    }
    __syncthreads();
    if (tt < 240) {
        int c = tt & 15, i = tt >> 4;
        float a = h1v[c * 30 + 2 * i], b = h1v[c * 30 + 2 * i + 1];
        ppv[c * 15 + i] = a > b ? a : b;
    }
    __syncthreads();
    if (tt < 352) {
        int o = tt / 11, j = tt % 11;
        float s = c2b[o];
        for (int i = 0; i < 16; ++i)
#pragma unroll
            for (int u = 0; u < 5; ++u)
                s = fmaf(ppv[i * 15 + j + u], c2w[o * 80 + i * 5 + u], s);
        flv[tt] = s > 0.f ? s : 0.f;
    }
    __syncthreads();
    if (tt < 128) {
        float s = l1b[tt];
        for (int i = 0; i < 352; ++i) s = fmaf(flv[i], l1w[i * 128 + tt], s);
        hmv[tt] = s > 0.f ? s : 0.f;
    }
    __syncthreads();
    if (tt < 64) {
        float v = fmaf(hmv[tt], l2w[tt], hmv[tt + 64] * l2w[tt + 64]);
#pragma unroll
        for (int o = 32; o > 0; o >>= 1) v += __shfl_down(v, o, 64);
        if (tt == 0) out[g] = v + l2b[0];
    }
}

// ============ fallback kernel: r2 fused variant (512 threads, 1 graph) ============
__global__ __launch_bounds__(512, 2) void gnn_kernel(
    const int* __restrict__ z,
    const unsigned* __restrict__ adjG,
    const float* __restrict__ zt,
    const float* __restrict__ W0, const float* __restrict__ b0,
    const float* __restrict__ W1, const float* __restrict__ b1,
    const float* __restrict__ W2, const float* __restrict__ b2,
    const float* __restrict__ W3, const float* __restrict__ b3,
    const float* __restrict__ c1w, const float* __restrict__ c1b,
    const float* __restrict__ c2w, const float* __restrict__ c2b,
    const float* __restrict__ l1w, const float* __restrict__ l1b,
    const float* __restrict__ l2w, const float* __restrict__ l2b,
    float* __restrict__ out)
{
    __shared__ __align__(16) float    Xhi[8192];
    __shared__ __align__(16) unsigned Xlo[4096];
    __shared__ unsigned char  csr[ECAP];
    __shared__ unsigned short rp16[132];
    __shared__ int            aux[128];
    __shared__ int            inv[30];
    __shared__ float          kd30f[30];
    __shared__ int            w0tot;

    const int g  = blockIdx.x;
    const int t  = threadIdx.x;
    const int r0 = t >> 3;
    const int r1 = r0 + 64;
    const int c0 = (t & 7) << 3;

    unsigned* adjM = (unsigned*)Xhi;

    {
        const uint4* src = (const uint4*)(adjG + ((size_t)g << 12));
        uint4* dst = (uint4*)adjM;
        for (int i = t; i < 1024; i += 512) dst[i] = src[i];
    }
    if (t < 30) { inv[t] = t; kd30f[t] = 0.f; }
    __syncthreads();

    int degv = 0;
    if (t < 128) {
        for (int w = 0; w < 32; ++w) {
            unsigned u = adjM[(t << 5) + w];
            degv += (int)((u & 255u) + ((u >> 8) & 255u) + ((u >> 16) & 255u) + (u >> 24));
        }
        aux[t] = degv;
    }
    if (t < 128) {
        int v = degv;
        for (int o = 1; o < 64; o <<= 1) {
            int u = __shfl_up(v, o, 64);
            if ((t & 63) >= o) v += u;
        }
        if (t == 63) w0tot = v;
        rp16[t + 1] = (unsigned short)v;
    }
    __syncthreads();
    if (t >= 64 && t < 128) rp16[t + 1] = (unsigned short)(rp16[t + 1] + w0tot);
    if (t == 0) rp16[0] = 0;
    __syncthreads();

    const int mydeg = (t < 128) ? aux[t] : 0;
    const double dv0 = 1.0 / sqrt((double)(aux[r0] + 1));
    const double dv1 = 1.0 / sqrt((double)(aux[r1] + 1));
    const double dvm = 1.0 / sqrt((double)(mydeg + 1));

    if (t < 128) {
        unsigned pos = rp16[t];
        for (int w = 0; w < 32; ++w) {
            unsigned u = adjM[(t << 5) + w];
            while (u) {
                int b2 = (u & 0xFFu) ? 0 : (u & 0xFF00u) ? 1 : (u & 0xFF0000u) ? 2 : 3;
                int m = (int)((u >> (b2 << 3)) & 255u);
                unsigned char sv = (unsigned char)((w << 2) + b2);
                for (int q = 0; q < m; ++q) { if (pos < ECAP) csr[pos] = sv; ++pos; }
                u &= ~(0xFFu << (b2 << 3));
            }
        }
    }
    __syncthreads();

    for (int idx = t; idx < 8192; idx += 512) {
        int n = idx >> 6, c = idx & 63;
        int zv = z[(g << 7) + n];
        zv = (zv < 0) ? 0 : ((zv >= MAXZ) ? MAXZ - 1 : zv);
        Xhi[xh_idx(n, c)] = zt[zv * 64 + c];
    }
    __syncthreads();

    float g1p[2][16];
#pragma unroll
    for (int rw = 0; rw < 2; ++rw)
#pragma unroll
        for (int c = 0; c < 16; ++c) g1p[rw][c] = 0.f;

    for (int layer = 0; layer < 3; ++layer) {
        const float* Wg = (layer == 0) ? W0 : (layer == 1) ? W1 : W2;
        const float* bg = (layer == 0) ? b0 : (layer == 1) ? b1 : b2;
        const bool haslo = (layer != 0);

        double accd0[8], accd1[8]; float accf0[8], accf1[8];
#pragma unroll
        for (int j = 0; j < 8; ++j) { accd0[j] = 0.0; accd1[j] = 0.0; accf0[j] = 0.f; accf1[j] = 0.f; }

        for (int k = 0; k < 64; k += 4) {
            float4 a0 = *(const float4*)&Xhi[xh_idx(r0, k)];
            float4 a1 = *(const float4*)&Xhi[xh_idx(r1, k)];
            float x0[4] = {a0.x, a0.y, a0.z, a0.w};
            float x1[4] = {a1.x, a1.y, a1.z, a1.w};
            float l0[4], l1[4];
            if (haslo) {
                uint2 u0 = *(const uint2*)&Xlo[xl_idx(r0, k >> 1)];
                uint2 u1 = *(const uint2*)&Xlo[xl_idx(r1, k >> 1)];
                l0[0] = bfu_lo(u0.x); l0[1] = bfu_hi(u0.x); l0[2] = bfu_lo(u0.y); l0[3] = bfu_hi(u0.y);
                l1[0] = bfu_lo(u1.x); l1[1] = bfu_hi(u1.x); l1[2] = bfu_lo(u1.y); l1[3] = bfu_hi(u1.y);
            }
#pragma unroll
            for (int kk = 0; kk < 4; ++kk) {
                const float* wr = Wg + ((k + kk) << 6) + c0;
                float4 wa = *(const float4*)wr;
                float4 wb = *(const float4*)(wr + 4);
                float wf[8] = {wa.x, wa.y, wa.z, wa.w, wb.x, wb.y, wb.z, wb.w};
                double xd0 = (double)x0[kk], xd1 = (double)x1[kk];
#pragma unroll
                for (int j = 0; j < 8; ++j) {
                    double wd = (double)wf[j];
                    accd0[j] = fma(xd0, wd, accd0[j]);
                    accd1[j] = fma(xd1, wd, accd1[j]);
                }
                if (haslo) {
#pragma unroll
                    for (int j = 0; j < 8; ++j) {
                        accf0[j] = fmaf(l0[kk], wf[j], accf0[j]);
                        accf1[j] = fmaf(l1[kk], wf[j], accf1[j]);
                    }
                }
            }
        }
        __syncthreads();

        float hfv[2][8], rsv[2][8];
#pragma unroll
        for (int rw = 0; rw < 2; ++rw) {
            int rr = rw ? r1 : r0;
            double dv = rw ? dv1 : dv0;
#pragma unroll
            for (int j = 0; j < 8; ++j) {
                double acc = rw ? (accd1[j] + (double)accf1[j]) : (accd0[j] + (double)accf0[j]);
                double h = dv * acc;
                float hf = (float)h;
                hfv[rw][j] = hf;
                rsv[rw][j] = (float)(h - (double)hf);
            }
            int bi = xh_idx(rr, c0);
            *(float4*)&Xhi[bi]     = make_float4(hfv[rw][0], hfv[rw][1], hfv[rw][2], hfv[rw][3]);
            *(float4*)&Xhi[bi + 4] = make_float4(hfv[rw][4], hfv[rw][5], hfv[rw][6], hfv[rw][7]);
            uint4 lv;
            lv.x = packlo(rsv[rw][0], rsv[rw][1]);
            lv.y = packlo(rsv[rw][2], rsv[rw][3]);
            lv.z = packlo(rsv[rw][4], rsv[rw][5]);
            lv.w = packlo(rsv[rw][6], rsv[rw][7]);
            *(uint4*)&Xlo[xl_idx(rr, c0 >> 1)] = lv;
        }
        __syncthreads();

        double ad[2][8]; float af[2][8];
#pragma unroll
        for (int rw = 0; rw < 2; ++rw)
#pragma unroll
            for (int j = 0; j < 8; ++j) { ad[rw][j] = (double)hfv[rw][j]; af[rw][j] = rsv[rw][j]; }

#pragma unroll
        for (int rw = 0; rw < 2; ++rw) {
            int rr = rw ? r1 : r0;
            for (unsigned e = rp16[rr]; e < rp16[rr + 1]; ++e) {
                int s = csr[e];
                int bi = (s << 6) | (c0 ^ ((s & 7) << 3));
                float4 a = *(const float4*)&Xhi[bi];
                float4 b = *(const float4*)&Xhi[bi + 4];
                uint4 lu = *(const uint4*)&Xlo[(s << 5) | ((c0 >> 1) ^ ((s & 7) << 2))];
                ad[rw][0] += (double)a.x; ad[rw][1] += (double)a.y;
                ad[rw][2] += (double)a.z; ad[rw][3] += (double)a.w;
                ad[rw][4] += (double)b.x; ad[rw][5] += (double)b.y;
                ad[rw][6] += (double)b.z; ad[rw][7] += (double)b.w;
                af[rw][0] += bfu_lo(lu.x); af[rw][1] += bfu_hi(lu.x);
                af[rw][2] += bfu_lo(lu.y); af[rw][3] += bfu_hi(lu.y);
                af[rw][4] += bfu_lo(lu.z); af[rw][5] += bfu_hi(lu.z);
                af[rw][6] += bfu_lo(lu.w); af[rw][7] += bfu_hi(lu.w);
            }
        }
        __syncthreads();

#pragma unroll
        for (int rw = 0; rw < 2; ++rw) {
            int rr = rw ? r1 : r0;
            double dv = rw ? dv1 : dv0;
            float vf[8], rs[8];
#pragma unroll
            for (int j = 0; j < 8; ++j) {
                double v = tanh_fast(dv * (ad[rw][j] + (double)af[rw][j]) + (double)bg[c0 + j]);
                float vfl = (float)v;
                vf[j] = vfl;
                rs[j] = (float)(v - (double)vfl);
            }
            int bi = xh_idx(rr, c0);
            *(float4*)&Xhi[bi]     = make_float4(vf[0], vf[1], vf[2], vf[3]);
            *(float4*)&Xhi[bi + 4] = make_float4(vf[4], vf[5], vf[6], vf[7]);
            uint4 lv;
            lv.x = packlo(rs[0], rs[1]);
            lv.y = packlo(rs[2], rs[3]);
            lv.z = packlo(rs[4], rs[5]);
            lv.w = packlo(rs[6], rs[7]);
            *(uint4*)&Xlo[xl_idx(rr, c0 >> 1)] = lv;

            const float* w1base = c1w + layer * 64 + c0;
            for (int c = 0; c < 16; ++c) {
                const float* wr = w1base + c * 193;
#pragma unroll
                for (int j = 0; j < 8; ++j)
                    g1p[rw][c] = fmaf(vf[j], wr[j], g1p[rw][c]);
            }
        }
        __syncthreads();
    }

    double* h4sD  = (double*)Xlo;
    double* keydD = ((double*)Xlo) + 128;

    double sdreg = 0.0;
    if (t < 128) {
        double sd = 0.0; float sf = 0.f;
        for (int k = 0; k < 64; k += 4) {
            float4 a = *(const float4*)&Xhi[xh_idx(t, k)];
            uint2  u = *(const uint2*)&Xlo[xl_idx(t, k >> 1)];
            float4 w = *(const float4*)&W3[k];
            sd = fma((double)a.x, (double)w.x, sd);
            sd = fma((double)a.y, (double)w.y, sd);
            sd = fma((double)a.z, (double)w.z, sd);
            sd = fma((double)a.w, (double)w.w, sd);
            sf = fmaf(bfu_lo(u.x), w.x, sf);
            sf = fmaf(bfu_hi(u.x), w.y, sf);
            sf = fmaf(bfu_lo(u.y), w.z, sf);
            sf = fmaf(bfu_hi(u.y), w.w, sf);
        }
        sdreg = sd + (double)sf;
    }
    __syncthreads();
    if (t < 128) h4sD[t] = dvm * sdreg;
    __syncthreads();
    double keyreg = 0.0;
    if (t < 128) {
        double a = h4sD[t];
        for (unsigned e = rp16[t]; e < rp16[t + 1]; ++e) a += h4sD[csr[e]];
        keyreg = tanh_fast(dvm * a + (double)b3[0]);
        keydD[t] = keyreg;
    }
    __syncthreads();

    if (t < 128) {
        int rk = 0;
        for (int j = 0; j < 128; ++j) {
            double kj = keydD[j];
            if (kj > keyreg || (kj == keyreg && j < t)) ++rk;
        }
        if (rk < 30) { inv[rk] = t; kd30f[rk] = (float)keyreg; }
    }

#pragma unroll
    for (int m = 1; m <= 4; m <<= 1) {
#pragma unroll
        for (int rw = 0; rw < 2; ++rw)
#pragma unroll
            for (int c = 0; c < 16; ++c)
                g1p[rw][c] += __shfl_xor(g1p[rw][c], m, 64);
    }
    __syncthreads();
    float* XloF = (float*)Xlo;
    float* G1   = XloF + 512;
    if ((t & 7) == 0) {
#pragma unroll
        for (int c = 0; c < 16; c += 4) {
            *(float4*)&G1[r0 * 16 + c] = make_float4(g1p[0][c], g1p[0][c + 1], g1p[0][c + 2], g1p[0][c + 3]);
            *(float4*)&G1[r1 * 16 + c] = make_float4(g1p[1][c], g1p[1][c + 1], g1p[1][c + 2], g1p[1][c + 3]);
        }
    }
    __syncthreads();

    float* h1v = XloF + 2560;
    float* ppv = XloF + 3040;
    float* flv = XloF + 3280;
    float* hmv = XloF + 3632;

    if (t < 480) {
        int c = t & 15, k = t >> 4;
        int node = inv[k];
        float s = G1[node * 16 + c] + c1w[c * 193 + 192] * kd30f[k] + c1b[c];
        h1v[c * 30 + k] = s > 0.f ? s : 0.f;
    }
    __syncthreads();
    if (t < 240) {
        int c = t & 15, i = t >> 4;
        float a = h1v[c * 30 + 2 * i], b = h1v[c * 30 + 2 * i + 1];
        ppv[c * 15 + i] = a > b ? a : b;
    }
    __syncthreads();
    if (t < 352) {
        int o = t / 11, j = t % 11;
        float s = c2b[o];
        for (int i = 0; i < 16; ++i)
#pragma unroll
            for (int u = 0; u < 5; ++u)
                s = fmaf(ppv[i * 15 + j + u], c2w[o * 80 + i * 5 + u], s);
        flv[t] = s > 0.f ? s : 0.f;
    }
    __syncthreads();
    if (t < 128) {
        float s = l1b[t];
        for (int i = 0; i < 352; ++i) s = fmaf(flv[i], l1w[i * 128 + t], s);
        hmv[t] = s > 0.f ? s : 0.f;
    }
    __syncthreads();
    if (t < 64) {
        float v = fmaf(hmv[t], l2w[t], hmv[t + 64] * l2w[t + 64]);
#pragma unroll
        for (int o = 32; o > 0; o >>= 1) v += __shfl_down(v, o, 64);
        if (t == 0) out[g] = v + l2b[0];
    }
}

// ---------------- launch ----------------

extern "C" void kernel_launch(void* const* d_in, const int* in_sizes, int n_in,
                              void* d_out, int out_size, void* d_ws, size_t ws_size,
                              hipStream_t stream) {
    const int*   z   = (const int*)d_in[0];
    const int*   ei  = (const int*)d_in[1];
    const float* zt  = (const float*)d_in[3];
    const float* W0  = (const float*)d_in[4];
    const float* b0  = (const float*)d_in[5];
    const float* W1  = (const float*)d_in[6];
    const float* b1  = (const float*)d_in[7];
    const float* W2  = (const float*)d_in[8];
    const float* b2  = (const float*)d_in[9];
    const float* W3  = (const float*)d_in[10];
    const float* b3  = (const float*)d_in[11];
    const float* c1w = (const float*)d_in[12];
    const float* c1b = (const float*)d_in[13];
    const float* c2w = (const float*)d_in[14];
    const float* c2b = (const float*)d_in[15];
    const float* l1w = (const float*)d_in[16];
    const float* l1b = (const float*)d_in[17];
    const float* l2w = (const float*)d_in[18];
    const float* l2b = (const float*)d_in[19];
    float* out = (float*)d_out;

    const size_t ADJ_B = (size_t)NGRAPH * 4096 * 4;            // 16.78 MB
    const size_t XD_B  = (size_t)NGRAPH * 2 * 8192 * 4;        // 67.11 MB (x dumps, layers 0-1)
    if (ws_size < ADJ_B) {
        markWS_kernel<<<4, 256, 0, stream>>>(out);
        return;
    }

    unsigned* adjG = (unsigned*)d_ws;

    hipMemsetAsync(adjG, 0, ADJ_B, stream);
    adjscatter_kernel<<<(E_EDGES + 255) / 256, 256, 0, stream>>>(ei, adjG);

    if (ws_size >= ADJ_B + XD_B) {
        float* xdump = (float*)((char*)d_ws + ADJ_B);
        gnn1_kernel<<<NGRAPH, 512, 0, stream>>>(z, adjG, zt,
                                                W0, b0, W1, b1, W2, b2, W3, b3,
                                                c1w, c1b, c2w, c2b, l1w, l1b, l2w, l2b,
                                                xdump, out);
    } else {
        gnn_kernel<<<NGRAPH, 512, 0, stream>>>(z, adjG, zt,
                                               W0, b0, W1, b1, W2, b2, W3, b3,
                                               c1w, c1b, c2w, c2b, l1w, l1b, l2w, l2b,
                                               out);
    }
}